// Round 3
// baseline (320.586 us; speedup 1.0000x reference)
//
#include <hip/hip_runtime.h>
#include <hip/hip_bf16.h>
#include <stdint.h>

#define HID   2048
#define SLEN  2048
#define NB    2
#define NHEADS 32
#define NKVH   8
#define HDIM   64
#define KVW    512   // NKVH*HDIM

typedef __bf16 bf16_t;
typedef __bf16 bf16x2 __attribute__((ext_vector_type(2)));
typedef __bf16 bf16x4 __attribute__((ext_vector_type(4)));
typedef __bf16 bf16x8 __attribute__((ext_vector_type(8)));
typedef float  f32x4  __attribute__((ext_vector_type(4)));

__device__ __forceinline__ f32x4 mfma16(bf16x8 a, bf16x8 b, f32x4 c) {
  return __builtin_amdgcn_mfma_f32_16x16x32_bf16(a, b, c, 0, 0, 0);
}

__device__ __forceinline__ void gl2lds16(const bf16_t* g, bf16_t* l) {
  __builtin_amdgcn_global_load_lds(
      (const __attribute__((address_space(1))) void*)g,
      (__attribute__((address_space(3))) void*)l,
      16, 0, 0);
}

__device__ __forceinline__ float fast_exp2(float x) {
#if __has_builtin(__builtin_amdgcn_exp2f)
  return __builtin_amdgcn_exp2f(x);
#else
  return __expf(x * 0.69314718f);
#endif
}

__device__ __forceinline__ bf16x8 ld8(const bf16_t* p) {
  return *(const bf16x8*)p;
}
__device__ __forceinline__ bf16x8 ld8(const float* p) {
  f32x4 a = *(const f32x4*)p;
  f32x4 b = *(const f32x4*)(p + 4);
  bf16x8 r;
  r[0] = (bf16_t)a[0]; r[1] = (bf16_t)a[1]; r[2] = (bf16_t)a[2]; r[3] = (bf16_t)a[3];
  r[4] = (bf16_t)b[0]; r[5] = (bf16_t)b[1]; r[6] = (bf16_t)b[2]; r[7] = (bf16_t)b[3];
  return r;
}

__device__ __forceinline__ uint32_t pack2(float a, float b) {
  bf16x2 t; t[0] = (bf16_t)a; t[1] = (bf16_t)b;
  return __builtin_bit_cast(uint32_t, t);
}

__device__ __forceinline__ void st_c(bf16_t* p, float v) { *p = (bf16_t)v; }
__device__ __forceinline__ void st_c(float*  p, float v) { *p = v; }

// ---------------- fp32 -> bf16 convert pass + bias concat -------------------
__global__ __launch_bounds__(256) void cvt_kernel(
    const float* __restrict__ x,  const float* __restrict__ wq,
    const float* __restrict__ wk, const float* __restrict__ wv,
    const float* __restrict__ wo,
    const float* __restrict__ bq, const float* __restrict__ bk,
    const float* __restrict__ bv,
    bf16_t* xb, bf16_t* wqb, bf16_t* wkb, bf16_t* wvb, bf16_t* wob,
    float* bcat)
{
  if (blockIdx.y >= 5) {   // float->float bias concat
    const float* fs; float* fd; size_t n;
    if (blockIdx.y == 5)      { fs = bq; fd = bcat;        n = HID; }
    else if (blockIdx.y == 6) { fs = bk; fd = bcat + HID;  n = KVW; }
    else                      { fs = bv; fd = bcat + HID + KVW; n = KVW; }
    const size_t stride4 = (size_t)gridDim.x * 256 * 4;
    for (size_t i = ((size_t)blockIdx.x * 256 + threadIdx.x) * 4; i < n; i += stride4)
      *(f32x4*)(fd + i) = *(const f32x4*)(fs + i);
    return;
  }
  const float* s; bf16_t* d; size_t n;
  switch (blockIdx.y) {
    case 0:  s = x;  d = xb;  n = (size_t)NB * SLEN * HID; break;
    case 1:  s = wq; d = wqb; n = (size_t)HID * HID; break;
    case 2:  s = wk; d = wkb; n = (size_t)KVW * HID; break;
    case 3:  s = wv; d = wvb; n = (size_t)KVW * HID; break;
    default: s = wo; d = wob; n = (size_t)HID * HID; break;
  }
  const size_t stride = (size_t)gridDim.x * 256 * 8;
  for (size_t i = ((size_t)blockIdx.x * 256 + threadIdx.x) * 8; i < n; i += stride)
    *(bf16x8*)(d + i) = ld8(s + i);
}

// ====================== 256x256 8-phase GEMM (T2+T3+T4+T5) ==================
__device__ __forceinline__ bf16x8 ldfrag(const bf16_t* __restrict__ Lh, int r, int g) {
  return *(const bf16x8*)(Lh + r * 64 + ((g ^ (r & 7)) << 3));
}

template <int Q>
__device__ __forceinline__ void mfma_quad(const bf16x8 (&af)[2][2],
                                          const bf16x8 (&bfr)[4][2],
                                          f32x4 (&acc)[8][4]) {
#pragma unroll
  for (int ks = 0; ks < 2; ++ks)
#pragma unroll
    for (int i = 0; i < 2; ++i)
#pragma unroll
      for (int ni = 0; ni < 4; ++ni)
        acc[2 * Q + i][ni] = mfma16(af[i][ks], bfr[ni][ks], acc[2 * Q + i][ni]);
}

__device__ __forceinline__ void phase_barrier() {
  __builtin_amdgcn_s_barrier();
  asm volatile("" ::: "memory");
}

__device__ __forceinline__ void gemm256_core(
    const bf16_t* __restrict__ Ag,
    const bf16_t* __restrict__ Bg,
    bf16_t* __restrict__ lds, f32x4 (&acc)[8][4])
{
  const int tid  = threadIdx.x;
  const int lane = tid & 63;
  const int w    = tid >> 6;
  const int fr   = lane & 15;
  const int quad = lane >> 4;
  const int wr   = w >> 2;
  const int wc   = w & 3;
  const int rbB  = (wc & 1) * 64;

  bf16_t* A0 = lds;
  bf16_t* B0 = lds + 16384;
  bf16_t* A1 = lds + 32768;
  bf16_t* B1 = lds + 49152;
  const bf16_t* Ar0 = A0 + wr * 8192;
  const bf16_t* Br0 = B0 + (wc >> 1) * 8192;
  const bf16_t* Ar1 = A1 + wr * 8192;
  const bf16_t* Br1 = B1 + (wc >> 1) * 8192;

  const f32x4 z4 = {0.f, 0.f, 0.f, 0.f};
#pragma unroll
  for (int i = 0; i < 8; ++i)
#pragma unroll
    for (int j = 0; j < 4; ++j) acc[i][j] = z4;

  auto STAGE = [&](const bf16_t* __restrict__ Gp, bf16_t* __restrict__ Lh) {
#pragma unroll
    for (int j = 0; j < 2; ++j) {
      const int s = j * 512 + tid;
      const int r = s >> 3;
      const int g = (s & 7) ^ (r & 7);
      gl2lds16(Gp + (size_t)r * HID + g * 8, Lh + s * 8);
    }
  };

  STAGE(Bg,                  B0);
  STAGE(Bg + 128 * HID,      B0 + 8192);
  STAGE(Ag,                  A0);
  STAGE(Ag + 128 * HID,      A0 + 8192);
  STAGE(Bg + 64,             B1);
  STAGE(Bg + 128 * HID + 64, B1 + 8192);
  asm volatile("s_waitcnt vmcnt(4)" ::: "memory");
  phase_barrier();

  bf16x8 bfr[4][2], af[2][2];

#pragma unroll 1
  for (int it = 0; it < 16; ++it) {
    const bool more = (it < 15);
    const size_t k1 = (size_t)(2 * it + 1) * 64;
    const size_t k2 = (size_t)(2 * it + 2) * 64;
    const size_t k3 = (size_t)(2 * it + 3) * 64;

#pragma unroll
    for (int ni = 0; ni < 4; ++ni)
#pragma unroll
      for (int ks = 0; ks < 2; ++ks)
        bfr[ni][ks] = ldfrag(Br0, rbB + ni * 16 + fr, ks * 4 + quad);
#pragma unroll
    for (int i = 0; i < 2; ++i)
#pragma unroll
      for (int ks = 0; ks < 2; ++ks)
        af[i][ks] = ldfrag(Ar0, i * 16 + fr, ks * 4 + quad);
    STAGE(Ag + k1, A1);
    phase_barrier();
    asm volatile("s_waitcnt lgkmcnt(0)" ::: "memory");
    __builtin_amdgcn_s_setprio(1);
    mfma_quad<0>(af, bfr, acc);
    __builtin_amdgcn_s_setprio(0);
    phase_barrier();

#pragma unroll
    for (int i = 0; i < 2; ++i)
#pragma unroll
      for (int ks = 0; ks < 2; ++ks)
        af[i][ks] = ldfrag(Ar0, 32 + i * 16 + fr, ks * 4 + quad);
    STAGE(Ag + 128 * HID + k1, A1 + 8192);
    phase_barrier();
    asm volatile("s_waitcnt lgkmcnt(0)" ::: "memory");
    __builtin_amdgcn_s_setprio(1);
    mfma_quad<1>(af, bfr, acc);
    __builtin_amdgcn_s_setprio(0);
    phase_barrier();

#pragma unroll
    for (int i = 0; i < 2; ++i)
#pragma unroll
      for (int ks = 0; ks < 2; ++ks)
        af[i][ks] = ldfrag(Ar0, 64 + i * 16 + fr, ks * 4 + quad);
    if (more) STAGE(Bg + k2, B0);
    phase_barrier();
    asm volatile("s_waitcnt lgkmcnt(0)" ::: "memory");
    __builtin_amdgcn_s_setprio(1);
    mfma_quad<2>(af, bfr, acc);
    __builtin_amdgcn_s_setprio(0);
    phase_barrier();

#pragma unroll
    for (int i = 0; i < 2; ++i)
#pragma unroll
      for (int ks = 0; ks < 2; ++ks)
        af[i][ks] = ldfrag(Ar0, 96 + i * 16 + fr, ks * 4 + quad);
    if (more) STAGE(Bg + 128 * HID + k2, B0 + 8192);
    phase_barrier();
    asm volatile("s_waitcnt lgkmcnt(0)" ::: "memory");
    __builtin_amdgcn_s_setprio(1);
    mfma_quad<3>(af, bfr, acc);
    __builtin_amdgcn_s_setprio(0);
    if (more) { asm volatile("s_waitcnt vmcnt(4)" ::: "memory"); }
    else      { asm volatile("s_waitcnt vmcnt(0)" ::: "memory"); }
    phase_barrier();

#pragma unroll
    for (int ni = 0; ni < 4; ++ni)
#pragma unroll
      for (int ks = 0; ks < 2; ++ks)
        bfr[ni][ks] = ldfrag(Br1, rbB + ni * 16 + fr, ks * 4 + quad);
#pragma unroll
    for (int i = 0; i < 2; ++i)
#pragma unroll
      for (int ks = 0; ks < 2; ++ks)
        af[i][ks] = ldfrag(Ar1, i * 16 + fr, ks * 4 + quad);
    if (more) STAGE(Ag + k2, A0);
    phase_barrier();
    asm volatile("s_waitcnt lgkmcnt(0)" ::: "memory");
    __builtin_amdgcn_s_setprio(1);
    mfma_quad<0>(af, bfr, acc);
    __builtin_amdgcn_s_setprio(0);
    phase_barrier();

#pragma unroll
    for (int i = 0; i < 2; ++i)
#pragma unroll
      for (int ks = 0; ks < 2; ++ks)
        af[i][ks] = ldfrag(Ar1, 32 + i * 16 + fr, ks * 4 + quad);
    if (more) STAGE(Ag + 128 * HID + k2, A0 + 8192);
    phase_barrier();
    asm volatile("s_waitcnt lgkmcnt(0)" ::: "memory");
    __builtin_amdgcn_s_setprio(1);
    mfma_quad<1>(af, bfr, acc);
    __builtin_amdgcn_s_setprio(0);
    phase_barrier();

#pragma unroll
    for (int i = 0; i < 2; ++i)
#pragma unroll
      for (int ks = 0; ks < 2; ++ks)
        af[i][ks] = ldfrag(Ar1, 64 + i * 16 + fr, ks * 4 + quad);
    if (more) STAGE(Bg + k3, B1);
    phase_barrier();
    asm volatile("s_waitcnt lgkmcnt(0)" ::: "memory");
    __builtin_amdgcn_s_setprio(1);
    mfma_quad<2>(af, bfr, acc);
    __builtin_amdgcn_s_setprio(0);
    phase_barrier();

#pragma unroll
    for (int i = 0; i < 2; ++i)
#pragma unroll
      for (int ks = 0; ks < 2; ++ks)
        af[i][ks] = ldfrag(Ar1, 96 + i * 16 + fr, ks * 4 + quad);
    if (more) STAGE(Bg + 128 * HID + k3, B1 + 8192);
    phase_barrier();
    asm volatile("s_waitcnt lgkmcnt(0)" ::: "memory");
    __builtin_amdgcn_s_setprio(1);
    mfma_quad<3>(af, bfr, acc);
    __builtin_amdgcn_s_setprio(0);
    if (more) { asm volatile("s_waitcnt vmcnt(4)" ::: "memory"); }
    phase_barrier();
  }
}

__global__ __launch_bounds__(512, 2) void qkv8_kernel(
    const bf16_t* __restrict__ xb, const bf16_t* __restrict__ Wcat,
    const float* __restrict__ bcat,
    bf16_t* __restrict__ Qb, bf16_t* __restrict__ Kb, bf16_t* __restrict__ VbT)
{
  __shared__ __align__(16) bf16_t lds[65536];
  const int cb = blockIdx.x;   // 0..11
  const int mb = blockIdx.y;   // 0..15
  f32x4 acc[8][4];
  gemm256_core(xb + (size_t)mb * 256 * HID, Wcat + (size_t)cb * 256 * HID, lds, acc);

  const int tid = threadIdx.x, lane = tid & 63, w = tid >> 6;
  const int fr = lane & 15, quad = lane >> 4, wr = w >> 2, wc = w & 3;
#pragma unroll
  for (int ni = 0; ni < 4; ++ni) {
    const int gcol = cb * 256 + wc * 64 + ni * 16 + fr;
    const float bz = bcat[gcol];
#pragma unroll
    for (int mi = 0; mi < 8; ++mi) {
      const int grow = mb * 256 + wr * 128 + mi * 16 + quad * 4;
      if (cb < 8) {
#pragma unroll
        for (int r = 0; r < 4; ++r)
          Qb[(size_t)(grow + r) * HID + gcol] = (bf16_t)(acc[mi][ni][r] + bz);
      } else if (cb < 10) {
        const int kc = gcol - 2048;
#pragma unroll
        for (int r = 0; r < 4; ++r)
          Kb[(size_t)(grow + r) * KVW + kc] = (bf16_t)(acc[mi][ni][r] + bz);
      } else {
        const int vc = gcol - 2560;
        const int b = grow >> 11, s = grow & 2047;
        bf16x4 pk;
#pragma unroll
        for (int r = 0; r < 4; ++r) pk[r] = (bf16_t)(acc[mi][ni][r] + bz);
        *(bf16x4*)&VbT[((size_t)(b * NKVH + (vc >> 6)) * HDIM + (vc & 63)) * SLEN + s] = pk;
      }
    }
  }
}

__global__ __launch_bounds__(512, 2) void oproj8_kernel(
    const bf16_t* __restrict__ A, const bf16_t* __restrict__ Wob,
    const float* __restrict__ bo, float* __restrict__ out)
{
  __shared__ __align__(16) bf16_t lds[65536];
  const int cb = blockIdx.x;
  const int mb = blockIdx.y;
  f32x4 acc[8][4];
  gemm256_core(A + (size_t)mb * 256 * HID, Wob + (size_t)cb * 256 * HID, lds, acc);

  const int tid = threadIdx.x, lane = tid & 63, w = tid >> 6;
  const int fr = lane & 15, quad = lane >> 4, wr = w >> 2, wc = w & 3;
#pragma unroll
  for (int ni = 0; ni < 4; ++ni) {
    const int gcol = cb * 256 + wc * 64 + ni * 16 + fr;
    const float bz = bo[gcol];
#pragma unroll
    for (int mi = 0; mi < 8; ++mi) {
      const int grow = mb * 256 + wr * 128 + mi * 16 + quad * 4;
#pragma unroll
      for (int r = 0; r < 4; ++r)
        out[(size_t)(grow + r) * HID + gcol] = acc[mi][ni][r] + bz;
    }
  }
}

// ---------------- Path B (fallback): fp32-source GEMM -----------------------
template <typename AT, typename CT>
__device__ __forceinline__ void gemm128_tile(
    const AT* __restrict__ Ap, int lda,
    const float* __restrict__ Wp, int ldw,
    const float* __restrict__ biasp,
    CT* __restrict__ Cp, int ldc,
    int K)
{
  __shared__ __align__(16) bf16_t Al[128 * 32];
  __shared__ __align__(16) bf16_t Bl[128 * 32];

  const int tid  = threadIdx.x;
  const int lane = tid & 63;
  const int w    = tid >> 6;
  const int fr   = lane & 15;
  const int quad = lane >> 4;
  const int wm   = (w >> 1) * 64;
  const int wn   = (w & 1) * 64;

  const f32x4 z4 = {0.f, 0.f, 0.f, 0.f};
  f32x4 acc[4][4];
  for (int i = 0; i < 4; ++i)
    for (int j = 0; j < 4; ++j) acc[i][j] = z4;

  const int c0    = w * 2;
  const int srow0 = lane >> 2;
  const int skc   = (lane & 3) * 8;

  for (int k0 = 0; k0 < K; k0 += 32) {
    bf16x8 av[2], bv[2];
    for (int t = 0; t < 2; ++t) {
      const int r = (c0 + t) * 16 + srow0;
      av[t] = ld8(Ap + (size_t)r * lda + k0 + skc);
      bv[t] = ld8(Wp + (size_t)r * ldw + k0 + skc);
    }
    for (int t = 0; t < 2; ++t) {
      const int c = c0 + t;
      *(bf16x8*)&Al[c * 512 + lane * 8] = av[t];
      *(bf16x8*)&Bl[c * 512 + lane * 8] = bv[t];
    }
    __syncthreads();
    bf16x8 af[4], bfr[4];
    for (int mi = 0; mi < 4; ++mi)
      af[mi] = *(const bf16x8*)&Al[(wm + mi * 16 + fr) * 32 + quad * 8];
    for (int ni = 0; ni < 4; ++ni)
      bfr[ni] = *(const bf16x8*)&Bl[(wn + ni * 16 + fr) * 32 + quad * 8];
    for (int mi = 0; mi < 4; ++mi)
      for (int ni = 0; ni < 4; ++ni)
        acc[mi][ni] = mfma16(af[mi], bfr[ni], acc[mi][ni]);
    __syncthreads();
  }

  for (int ni = 0; ni < 4; ++ni) {
    const int col = wn + ni * 16 + fr;
    const float bz = biasp[col];
    for (int mi = 0; mi < 4; ++mi) {
      const int r0 = wm + mi * 16 + quad * 4;
      for (int r = 0; r < 4; ++r)
        st_c(Cp + (size_t)(r0 + r) * ldc + col, acc[mi][ni][r] + bz);
    }
  }
}

__global__ __launch_bounds__(256) void qkv_kernel(
    const float* __restrict__ x,
    const float* __restrict__ Wq, const float* __restrict__ bq,
    const float* __restrict__ Wk, const float* __restrict__ bk,
    const float* __restrict__ Wv, const float* __restrict__ bv,
    bf16_t* Qb, bf16_t* Kb, bf16_t* Vb)
{
  const int nb = blockIdx.x;
  const int mb = blockIdx.y;
  const float* W; const float* bias; bf16_t* C; int ldc;
  if (nb < 16)      { W = Wq + (size_t)nb * 128 * HID;  bias = bq + nb * 128;
                      C = Qb + nb * 128; ldc = HID; }
  else if (nb < 20) { const int j = nb - 16;
                      W = Wk + (size_t)j * 128 * HID;   bias = bk + j * 128;
                      C = Kb + j * 128; ldc = KVW; }
  else              { const int j = nb - 20;
                      W = Wv + (size_t)j * 128 * HID;   bias = bv + j * 128;
                      C = Vb + j * 128; ldc = KVW; }
  gemm128_tile<float, bf16_t>(x + (size_t)mb * 128 * HID, HID, W, HID, bias,
                              C + (size_t)mb * 128 * ldc, ldc, HID);
}

__global__ __launch_bounds__(256) void oproj_kernel(
    const bf16_t* __restrict__ A, const float* __restrict__ Wo,
    const float* __restrict__ bo, float* out)
{
  const int nb = blockIdx.x, mb = blockIdx.y;
  gemm128_tile<bf16_t, float>(A + (size_t)mb * 128 * HID, HID,
                              Wo + (size_t)nb * 128 * HID, HID,
                              bo + nb * 128,
                              out + (size_t)mb * 128 * HID + nb * 128, HID, HID);
}

__global__ __launch_bounds__(256) void vtrans_kernel(
    const bf16_t* __restrict__ Vb, bf16_t* __restrict__ VbT)
{
  __shared__ bf16_t T[64][72];
  const int st = blockIdx.x, kvh = blockIdx.y, b = blockIdx.z;
  const int tid = threadIdx.x;
  {
    const int row = tid >> 2;
    const int c16 = (tid & 3) * 16;
    const bf16_t* src =
        Vb + ((size_t)b * SLEN + st * 64 + row) * KVW + kvh * HDIM + c16;
    *(bf16x8*)&T[row][c16]     = *(const bf16x8*)(src);
    *(bf16x8*)&T[row][c16 + 8] = *(const bf16x8*)(src + 8);
  }
  __syncthreads();
  {
    const int d  = tid >> 2;
    const int sc = (tid & 3) * 16;
    bf16_t tmp[16];
    for (int j = 0; j < 16; ++j) tmp[j] = T[sc + j][d];
    bf16_t* dst = VbT + ((size_t)(b * NKVH + kvh) * HDIM + d) * SLEN + st * 64 + sc;
    *(bf16x8*)dst       = *(bf16x8*)&tmp[0];
    *(bf16x8*)(dst + 8) = *(bf16x8*)&tmp[8];
  }
}

// ---------------- Flash attention: swapped QK^T, in-register P --------------
// 4 waves, QBLK=64, KVBLK=128. Flat grid 1024: xcd = blockIdx.x & 7 maps each
// XCD to ONE kvh (both batches) -> K+V working set 2MB fits per-XCD L2.
// KL/VtL layouts carry a (row>>1)&3 XOR on the 16B column-group so every
// aligned 8-lane subgroup of each ds_read_b128 hits 8 distinct bank groups.
__global__ __launch_bounds__(256, 4) void attn_kernel(
    const bf16_t* Q, const bf16_t* __restrict__ Kg,
    const bf16_t* __restrict__ VT, bf16_t* O)
{
  const int bid = blockIdx.x;            // 0..1023
  const int xcd = bid & 7;
  const int j   = bid >> 3;              // 0..127
  const int kvh = xcd;                   // one kvh per XCD
  const int b   = j >> 6;                // 0..1
  const int rem = j & 63;
  const int h   = kvh * 4 + (rem & 3);
  const int pid = rem >> 2;              // 0..15

  const int tid  = threadIdx.x;
  const int lane = tid & 63;
  const int w    = tid >> 6;         // 0..3
  const int fr   = lane & 15;
  const int quad = lane >> 4;

  __shared__ __align__(16) bf16_t KL[8192];    // [ks(2)][krow(128)][4 grp][8] swz
  __shared__ __align__(16) bf16_t VtL[8192];   // [kb(4)][d(64)][4 grp][8] swz

  const size_t qbase = (size_t)b * SLEN;
  const bf16_t* VTh = VT + (size_t)(b * NKVH + kvh) * HDIM * SLEN;

  // sigma: quad -> V k-slot (absorbs shfl_xor(16) pairing), as slot index
  const int sig = ((quad & 1) << 1) | ((quad >> 1) & 1);   // 0,2,1,3
  const int fsw = (fr >> 1) & 3;                            // read-side XOR
  const bool oddq = (quad & 1);

  bf16x8 ones8;
  {
    const bf16_t o1 = (bf16_t)(fr == 0 ? 1.0f : 0.0f);
#pragma unroll
    for (int j2 = 0; j2 < 8; ++j2) ones8[j2] = o1;
  }

  for (int half = 0; half < 2; ++half) {
    const int qt = half ? (31 - pid) : pid;
    const int q0 = qt * 64;

    bf16x8 qf[2];
#pragma unroll
    for (int ks = 0; ks < 2; ++ks)
      qf[ks] = *(const bf16x8*)&Q[(qbase + q0 + w * 16 + fr) * HID
                                  + h * HDIM + ks * 32 + quad * 8];

    const f32x4 z4 = {0.f, 0.f, 0.f, 0.f};
    f32x4 o_acc[4];
    f32x4 o_l = z4;
#pragma unroll
    for (int di = 0; di < 4; ++di) o_acc[di] = z4;

    const int ktmax = qt >> 1;
    const int qloc  = (qt & 1) * 64 + w * 16 + fr;   // q local to diag tile

    for (int kt = 0; kt <= ktmax; ++kt) {
      const size_t krow0 = qbase + (size_t)kt * 128;

      // stage K: dest slot s holds logical (ks, kr, g) with g = (s&3)^((kr>>1)&3)
#pragma unroll
      for (int jj = 0; jj < 4; ++jj) {
        const int s  = jj * 256 + tid;
        const int ks = s >> 9, kr = (s >> 2) & 127, c8 = (s & 3) ^ ((kr >> 1) & 3);
        gl2lds16(&Kg[(krow0 + kr) * KVW + kvh * HDIM + ks * 32 + c8 * 8],
                 &KL[s * 8]);
      }
      // stage V^T: dest slot idx holds logical (kb, d, g) with g = (idx&3)^((d>>1)&3)
#pragma unroll
      for (int jj = 0; jj < 4; ++jj) {
        const int idx = jj * 256 + tid;
        const int kb = idx >> 8, d = (idx >> 2) & 63, c8 = (idx & 3) ^ ((d >> 1) & 3);
        gl2lds16(&VTh[(size_t)d * SLEN + kt * 128 + kb * 32 + c8 * 8],
                 &VtL[idx * 8]);
      }
      __syncthreads();

      // QK^T swapped: s8[ki] rows = k (quad*4+r), cols = q (fr)
      f32x4 s8[8];
#pragma unroll
      for (int ki = 0; ki < 8; ++ki) s8[ki] = z4;
#pragma unroll
      for (int ks = 0; ks < 2; ++ks)
#pragma unroll
        for (int ki = 0; ki < 8; ++ki) {
          bf16x8 kf = *(const bf16x8*)&KL[ks * 4096 + (ki * 16 + fr) * 32
                                          + ((quad ^ fsw) << 3)];
          s8[ki] = mfma16(kf, qf[ks], s8[ki]);
        }

      const float C2 = 0.18033688f;   // log2(e)/8
      const bool diag = (kt == ktmax);

#pragma unroll
      for (int m = 0; m < 4; ++m) {
        float pe[8];
#pragma unroll
        for (int ki2 = 0; ki2 < 2; ++ki2) {
          const int ki = 2 * m + ki2;
#pragma unroll
          for (int r = 0; r < 4; ++r) {
            float p = fast_exp2(s8[ki][r] * C2);
            if (diag && (ki * 16 + quad * 4 + r > qloc)) p = 0.f;
            pe[ki2 * 4 + r] = p;
          }
        }
        uint32_t pw0 = pack2(pe[0], pe[1]);
        uint32_t pw1 = pack2(pe[2], pe[3]);
        uint32_t pw2 = pack2(pe[4], pe[5]);
        uint32_t pw3 = pack2(pe[6], pe[7]);
        uint32_t x0 = oddq ? pw0 : pw2;
        uint32_t x1 = oddq ? pw1 : pw3;
        uint32_t r0 = (uint32_t)__shfl_xor((int)x0, 16);
        uint32_t r1 = (uint32_t)__shfl_xor((int)x1, 16);
        union { uint32_t u[4]; bf16x8 v; } pb;
        pb.u[0] = oddq ? r0 : pw0;
        pb.u[1] = oddq ? r1 : pw1;
        pb.u[2] = oddq ? pw2 : r0;
        pb.u[3] = oddq ? pw3 : r1;

        o_l = mfma16(pb.v, ones8, o_l);
#pragma unroll
        for (int di = 0; di < 4; ++di) {
          bf16x8 vf = *(const bf16x8*)&VtL[m * 2048 + (di * 16 + fr) * 32
                                           + ((sig ^ fsw) << 3)];
          o_acc[di] = mfma16(pb.v, vf, o_acc[di]);
        }
      }
      __syncthreads();
    }

    // epilogue: o_acc rows = q (quad*4+r), cols = d (di*16+fr); l at fr==0
#pragma unroll
    for (int r = 0; r < 4; ++r) {
      const float l  = __shfl(o_l[r], lane & 48);
      const float rl = 1.f / l;
      const size_t qg = qbase + q0 + w * 16 + quad * 4 + r;
#pragma unroll
      for (int di = 0; di < 4; ++di)
        O[qg * HID + h * HDIM + di * 16 + fr] = (bf16_t)(o_acc[di][r] * rl);
    }
  }
}

extern "C" void kernel_launch(void* const* d_in, const int* in_sizes, int n_in,
                              void* d_out, int out_size, void* d_ws, size_t ws_size,
                              hipStream_t stream) {
  const float* x  = (const float*)d_in[0];
  // d_in[1] = causal mask (int32) -- recomputed inline, not read
  const float* Wq = (const float*)d_in[2];
  const float* bq = (const float*)d_in[3];
  const float* Wk = (const float*)d_in[4];
  const float* bk = (const float*)d_in[5];
  const float* Wv = (const float*)d_in[6];
  const float* bv = (const float*)d_in[7];
  const float* Wo = (const float*)d_in[8];
  const float* bo = (const float*)d_in[9];
  float* out = (float*)d_out;

  const size_t M = (size_t)NB * SLEN;          // 4096
  dim3 blk(256, 1, 1);

  const size_t needA = (M * HID
                        + (size_t)HID * HID
                        + (size_t)KVW * HID
                        + (size_t)KVW * HID
                        + (size_t)HID * HID
                        + M * HID
                        + M * KVW
                        + M * KVW) * 2
                       + (size_t)(HID + 2 * KVW) * sizeof(float);
  if (ws_size >= needA) {
    bf16_t* xb  = (bf16_t*)d_ws;
    bf16_t* Wqb = xb  + M * HID;              // Wq|Wk|Wv contiguous = Wcat
    bf16_t* Wkb = Wqb + (size_t)HID * HID;
    bf16_t* Wvb = Wkb + (size_t)KVW * HID;
    bf16_t* Wob = Wvb + (size_t)KVW * HID;
    bf16_t* Qb  = Wob + (size_t)HID * HID;
    bf16_t* Kb  = Qb  + M * HID;
    bf16_t* VbT = Kb  + M * KVW;
    float*  bcat = (float*)(VbT + M * KVW);   // [bq|bk|bv], 3072 floats

    cvt_kernel<<<dim3(1024, 8, 1), blk, 0, stream>>>(
        x, Wq, Wk, Wv, Wo, bq, bk, bv, xb, Wqb, Wkb, Wvb, Wob, bcat);
    qkv8_kernel<<<dim3(12, 16, 1), dim3(512, 1, 1), 0, stream>>>(
        xb, Wqb, bcat, Qb, Kb, VbT);
    attn_kernel<<<dim3(1024, 1, 1), blk, 0, stream>>>(Qb, Kb, VbT, Qb);
    oproj8_kernel<<<dim3(8, 16, 1), dim3(512, 1, 1), 0, stream>>>(
        Qb, Wob, bo, out);
  } else {
    bf16_t* Qb  = (bf16_t*)d_ws;
    bf16_t* Kb  = Qb + M * KVW * 0 + M * HID; // keep layout
    bf16_t* Vb  = Kb + M * KVW;
    bf16_t* VbT = Vb + M * KVW;

    qkv_kernel<<<dim3(24, 32, 1), blk, 0, stream>>>(x, Wq, bq, Wk, bk, Wv, bv, Qb, Kb, Vb);
    vtrans_kernel<<<dim3(32, 8, 2), blk, 0, stream>>>(Vb, VbT);
    attn_kernel<<<dim3(1024, 1, 1), blk, 0, stream>>>(Qb, Kb, VbT, Qb);
    oproj_kernel<<<dim3(16, 32, 1), blk, 0, stream>>>(Qb, Wo, bo, out);
  }
}

// Round 4
// 299.781 us; speedup vs baseline: 1.0694x; 1.0694x over previous
//
#include <hip/hip_runtime.h>
#include <hip/hip_bf16.h>
#include <stdint.h>

#define HID   2048
#define SLEN  2048
#define NB    2
#define NHEADS 32
#define NKVH   8
#define HDIM   64
#define KVW    512   // NKVH*HDIM

typedef __bf16 bf16_t;
typedef __bf16 bf16x2 __attribute__((ext_vector_type(2)));
typedef __bf16 bf16x4 __attribute__((ext_vector_type(4)));
typedef __bf16 bf16x8 __attribute__((ext_vector_type(8)));
typedef float  f32x4  __attribute__((ext_vector_type(4)));

__device__ __forceinline__ f32x4 mfma16(bf16x8 a, bf16x8 b, f32x4 c) {
  return __builtin_amdgcn_mfma_f32_16x16x32_bf16(a, b, c, 0, 0, 0);
}

__device__ __forceinline__ void gl2lds16(const bf16_t* g, bf16_t* l) {
  __builtin_amdgcn_global_load_lds(
      (const __attribute__((address_space(1))) void*)g,
      (__attribute__((address_space(3))) void*)l,
      16, 0, 0);
}

__device__ __forceinline__ float fast_exp2(float x) {
#if __has_builtin(__builtin_amdgcn_exp2f)
  return __builtin_amdgcn_exp2f(x);
#else
  return __expf(x * 0.69314718f);
#endif
}

__device__ __forceinline__ bf16x8 ld8(const bf16_t* p) {
  return *(const bf16x8*)p;
}
__device__ __forceinline__ bf16x8 ld8(const float* p) {
  f32x4 a = *(const f32x4*)p;
  f32x4 b = *(const f32x4*)(p + 4);
  bf16x8 r;
  r[0] = (bf16_t)a[0]; r[1] = (bf16_t)a[1]; r[2] = (bf16_t)a[2]; r[3] = (bf16_t)a[3];
  r[4] = (bf16_t)b[0]; r[5] = (bf16_t)b[1]; r[6] = (bf16_t)b[2]; r[7] = (bf16_t)b[3];
  return r;
}

__device__ __forceinline__ uint32_t pack2(float a, float b) {
  bf16x2 t; t[0] = (bf16_t)a; t[1] = (bf16_t)b;
  return __builtin_bit_cast(uint32_t, t);
}

__device__ __forceinline__ void st_c(bf16_t* p, float v) { *p = (bf16_t)v; }
__device__ __forceinline__ void st_c(float*  p, float v) { *p = v; }

// ---------------- fp32 -> bf16 convert pass + bias concat -------------------
__global__ __launch_bounds__(256) void cvt_kernel(
    const float* __restrict__ x,  const float* __restrict__ wq,
    const float* __restrict__ wk, const float* __restrict__ wv,
    const float* __restrict__ wo,
    const float* __restrict__ bq, const float* __restrict__ bk,
    const float* __restrict__ bv,
    bf16_t* xb, bf16_t* wqb, bf16_t* wkb, bf16_t* wvb, bf16_t* wob,
    float* bcat)
{
  if (blockIdx.y >= 5) {   // float->float bias concat
    const float* fs; float* fd; size_t n;
    if (blockIdx.y == 5)      { fs = bq; fd = bcat;        n = HID; }
    else if (blockIdx.y == 6) { fs = bk; fd = bcat + HID;  n = KVW; }
    else                      { fs = bv; fd = bcat + HID + KVW; n = KVW; }
    const size_t stride4 = (size_t)gridDim.x * 256 * 4;
    for (size_t i = ((size_t)blockIdx.x * 256 + threadIdx.x) * 4; i < n; i += stride4)
      *(f32x4*)(fd + i) = *(const f32x4*)(fs + i);
    return;
  }
  const float* s; bf16_t* d; size_t n;
  switch (blockIdx.y) {
    case 0:  s = x;  d = xb;  n = (size_t)NB * SLEN * HID; break;
    case 1:  s = wq; d = wqb; n = (size_t)HID * HID; break;
    case 2:  s = wk; d = wkb; n = (size_t)KVW * HID; break;
    case 3:  s = wv; d = wvb; n = (size_t)KVW * HID; break;
    default: s = wo; d = wob; n = (size_t)HID * HID; break;
  }
  const size_t stride = (size_t)gridDim.x * 256 * 8;
  for (size_t i = ((size_t)blockIdx.x * 256 + threadIdx.x) * 8; i < n; i += stride)
    *(bf16x8*)(d + i) = ld8(s + i);
}

// ====================== 256x256 8-phase GEMM (T2+T3+T4+T5) ==================
__device__ __forceinline__ bf16x8 ldfrag(const bf16_t* __restrict__ Lh, int r, int g) {
  return *(const bf16x8*)(Lh + r * 64 + ((g ^ (r & 7)) << 3));
}

template <int Q>
__device__ __forceinline__ void mfma_quad(const bf16x8 (&af)[2][2],
                                          const bf16x8 (&bfr)[4][2],
                                          f32x4 (&acc)[8][4]) {
#pragma unroll
  for (int ks = 0; ks < 2; ++ks)
#pragma unroll
    for (int i = 0; i < 2; ++i)
#pragma unroll
      for (int ni = 0; ni < 4; ++ni)
        acc[2 * Q + i][ni] = mfma16(af[i][ks], bfr[ni][ks], acc[2 * Q + i][ni]);
}

__device__ __forceinline__ void phase_barrier() {
  __builtin_amdgcn_s_barrier();
  asm volatile("" ::: "memory");
}

__device__ __forceinline__ void gemm256_core(
    const bf16_t* __restrict__ Ag,
    const bf16_t* __restrict__ Bg,
    bf16_t* __restrict__ lds, f32x4 (&acc)[8][4])
{
  const int tid  = threadIdx.x;
  const int lane = tid & 63;
  const int w    = tid >> 6;
  const int fr   = lane & 15;
  const int quad = lane >> 4;
  const int wr   = w >> 2;
  const int wc   = w & 3;
  const int rbB  = (wc & 1) * 64;

  bf16_t* A0 = lds;
  bf16_t* B0 = lds + 16384;
  bf16_t* A1 = lds + 32768;
  bf16_t* B1 = lds + 49152;
  const bf16_t* Ar0 = A0 + wr * 8192;
  const bf16_t* Br0 = B0 + (wc >> 1) * 8192;
  const bf16_t* Ar1 = A1 + wr * 8192;
  const bf16_t* Br1 = B1 + (wc >> 1) * 8192;

  const f32x4 z4 = {0.f, 0.f, 0.f, 0.f};
#pragma unroll
  for (int i = 0; i < 8; ++i)
#pragma unroll
    for (int j = 0; j < 4; ++j) acc[i][j] = z4;

  auto STAGE = [&](const bf16_t* __restrict__ Gp, bf16_t* __restrict__ Lh) {
#pragma unroll
    for (int j = 0; j < 2; ++j) {
      const int s = j * 512 + tid;
      const int r = s >> 3;
      const int g = (s & 7) ^ (r & 7);
      gl2lds16(Gp + (size_t)r * HID + g * 8, Lh + s * 8);
    }
  };

  STAGE(Bg,                  B0);
  STAGE(Bg + 128 * HID,      B0 + 8192);
  STAGE(Ag,                  A0);
  STAGE(Ag + 128 * HID,      A0 + 8192);
  STAGE(Bg + 64,             B1);
  STAGE(Bg + 128 * HID + 64, B1 + 8192);
  asm volatile("s_waitcnt vmcnt(4)" ::: "memory");
  phase_barrier();

  bf16x8 bfr[4][2], af[2][2];

#pragma unroll 1
  for (int it = 0; it < 16; ++it) {
    const bool more = (it < 15);
    const size_t k1 = (size_t)(2 * it + 1) * 64;
    const size_t k2 = (size_t)(2 * it + 2) * 64;
    const size_t k3 = (size_t)(2 * it + 3) * 64;

#pragma unroll
    for (int ni = 0; ni < 4; ++ni)
#pragma unroll
      for (int ks = 0; ks < 2; ++ks)
        bfr[ni][ks] = ldfrag(Br0, rbB + ni * 16 + fr, ks * 4 + quad);
#pragma unroll
    for (int i = 0; i < 2; ++i)
#pragma unroll
      for (int ks = 0; ks < 2; ++ks)
        af[i][ks] = ldfrag(Ar0, i * 16 + fr, ks * 4 + quad);
    STAGE(Ag + k1, A1);
    phase_barrier();
    asm volatile("s_waitcnt lgkmcnt(0)" ::: "memory");
    __builtin_amdgcn_s_setprio(1);
    mfma_quad<0>(af, bfr, acc);
    __builtin_amdgcn_s_setprio(0);
    phase_barrier();

#pragma unroll
    for (int i = 0; i < 2; ++i)
#pragma unroll
      for (int ks = 0; ks < 2; ++ks)
        af[i][ks] = ldfrag(Ar0, 32 + i * 16 + fr, ks * 4 + quad);
    STAGE(Ag + 128 * HID + k1, A1 + 8192);
    phase_barrier();
    asm volatile("s_waitcnt lgkmcnt(0)" ::: "memory");
    __builtin_amdgcn_s_setprio(1);
    mfma_quad<1>(af, bfr, acc);
    __builtin_amdgcn_s_setprio(0);
    phase_barrier();

#pragma unroll
    for (int i = 0; i < 2; ++i)
#pragma unroll
      for (int ks = 0; ks < 2; ++ks)
        af[i][ks] = ldfrag(Ar0, 64 + i * 16 + fr, ks * 4 + quad);
    if (more) STAGE(Bg + k2, B0);
    phase_barrier();
    asm volatile("s_waitcnt lgkmcnt(0)" ::: "memory");
    __builtin_amdgcn_s_setprio(1);
    mfma_quad<2>(af, bfr, acc);
    __builtin_amdgcn_s_setprio(0);
    phase_barrier();

#pragma unroll
    for (int i = 0; i < 2; ++i)
#pragma unroll
      for (int ks = 0; ks < 2; ++ks)
        af[i][ks] = ldfrag(Ar0, 96 + i * 16 + fr, ks * 4 + quad);
    if (more) STAGE(Bg + 128 * HID + k2, B0 + 8192);
    phase_barrier();
    asm volatile("s_waitcnt lgkmcnt(0)" ::: "memory");
    __builtin_amdgcn_s_setprio(1);
    mfma_quad<3>(af, bfr, acc);
    __builtin_amdgcn_s_setprio(0);
    if (more) { asm volatile("s_waitcnt vmcnt(4)" ::: "memory"); }
    else      { asm volatile("s_waitcnt vmcnt(0)" ::: "memory"); }
    phase_barrier();

#pragma unroll
    for (int ni = 0; ni < 4; ++ni)
#pragma unroll
      for (int ks = 0; ks < 2; ++ks)
        bfr[ni][ks] = ldfrag(Br1, rbB + ni * 16 + fr, ks * 4 + quad);
#pragma unroll
    for (int i = 0; i < 2; ++i)
#pragma unroll
      for (int ks = 0; ks < 2; ++ks)
        af[i][ks] = ldfrag(Ar1, i * 16 + fr, ks * 4 + quad);
    if (more) STAGE(Ag + k2, A0);
    phase_barrier();
    asm volatile("s_waitcnt lgkmcnt(0)" ::: "memory");
    __builtin_amdgcn_s_setprio(1);
    mfma_quad<0>(af, bfr, acc);
    __builtin_amdgcn_s_setprio(0);
    phase_barrier();

#pragma unroll
    for (int i = 0; i < 2; ++i)
#pragma unroll
      for (int ks = 0; ks < 2; ++ks)
        af[i][ks] = ldfrag(Ar1, 32 + i * 16 + fr, ks * 4 + quad);
    if (more) STAGE(Ag + 128 * HID + k2, A0 + 8192);
    phase_barrier();
    asm volatile("s_waitcnt lgkmcnt(0)" ::: "memory");
    __builtin_amdgcn_s_setprio(1);
    mfma_quad<1>(af, bfr, acc);
    __builtin_amdgcn_s_setprio(0);
    phase_barrier();

#pragma unroll
    for (int i = 0; i < 2; ++i)
#pragma unroll
      for (int ks = 0; ks < 2; ++ks)
        af[i][ks] = ldfrag(Ar1, 64 + i * 16 + fr, ks * 4 + quad);
    if (more) STAGE(Bg + k3, B1);
    phase_barrier();
    asm volatile("s_waitcnt lgkmcnt(0)" ::: "memory");
    __builtin_amdgcn_s_setprio(1);
    mfma_quad<2>(af, bfr, acc);
    __builtin_amdgcn_s_setprio(0);
    phase_barrier();

#pragma unroll
    for (int i = 0; i < 2; ++i)
#pragma unroll
      for (int ks = 0; ks < 2; ++ks)
        af[i][ks] = ldfrag(Ar1, 96 + i * 16 + fr, ks * 4 + quad);
    if (more) STAGE(Bg + 128 * HID + k3, B1 + 8192);
    phase_barrier();
    asm volatile("s_waitcnt lgkmcnt(0)" ::: "memory");
    __builtin_amdgcn_s_setprio(1);
    mfma_quad<3>(af, bfr, acc);
    __builtin_amdgcn_s_setprio(0);
    if (more) { asm volatile("s_waitcnt vmcnt(4)" ::: "memory"); }
    phase_barrier();
  }
}

__global__ __launch_bounds__(512, 2) void qkv8_kernel(
    const bf16_t* __restrict__ xb, const bf16_t* __restrict__ Wcat,
    const float* __restrict__ bcat,
    bf16_t* __restrict__ Qb, bf16_t* __restrict__ Kb, bf16_t* __restrict__ VbT)
{
  __shared__ __align__(16) bf16_t lds[65536];
  const int cb = blockIdx.x;   // 0..11
  const int mb = blockIdx.y;   // 0..15
  f32x4 acc[8][4];
  gemm256_core(xb + (size_t)mb * 256 * HID, Wcat + (size_t)cb * 256 * HID, lds, acc);

  const int tid = threadIdx.x, lane = tid & 63, w = tid >> 6;
  const int fr = lane & 15, quad = lane >> 4, wr = w >> 2, wc = w & 3;
#pragma unroll
  for (int ni = 0; ni < 4; ++ni) {
    const int gcol = cb * 256 + wc * 64 + ni * 16 + fr;
    const float bz = bcat[gcol];
#pragma unroll
    for (int mi = 0; mi < 8; ++mi) {
      const int grow = mb * 256 + wr * 128 + mi * 16 + quad * 4;
      if (cb < 8) {
#pragma unroll
        for (int r = 0; r < 4; ++r)
          Qb[(size_t)(grow + r) * HID + gcol] = (bf16_t)(acc[mi][ni][r] + bz);
      } else if (cb < 10) {
        const int kc = gcol - 2048;
#pragma unroll
        for (int r = 0; r < 4; ++r)
          Kb[(size_t)(grow + r) * KVW + kc] = (bf16_t)(acc[mi][ni][r] + bz);
      } else {
        const int vc = gcol - 2560;
        const int b = grow >> 11, s = grow & 2047;
        bf16x4 pk;
#pragma unroll
        for (int r = 0; r < 4; ++r) pk[r] = (bf16_t)(acc[mi][ni][r] + bz);
        *(bf16x4*)&VbT[((size_t)(b * NKVH + (vc >> 6)) * HDIM + (vc & 63)) * SLEN + s] = pk;
      }
    }
  }
}

__global__ __launch_bounds__(512, 2) void oproj8_kernel(
    const bf16_t* __restrict__ A, const bf16_t* __restrict__ Wob,
    const float* __restrict__ bo, float* __restrict__ out)
{
  __shared__ __align__(16) bf16_t lds[65536];
  const int cb = blockIdx.x;
  const int mb = blockIdx.y;
  f32x4 acc[8][4];
  gemm256_core(A + (size_t)mb * 256 * HID, Wob + (size_t)cb * 256 * HID, lds, acc);

  const int tid = threadIdx.x, lane = tid & 63, w = tid >> 6;
  const int fr = lane & 15, quad = lane >> 4, wr = w >> 2, wc = w & 3;
#pragma unroll
  for (int ni = 0; ni < 4; ++ni) {
    const int gcol = cb * 256 + wc * 64 + ni * 16 + fr;
    const float bz = bo[gcol];
#pragma unroll
    for (int mi = 0; mi < 8; ++mi) {
      const int grow = mb * 256 + wr * 128 + mi * 16 + quad * 4;
#pragma unroll
      for (int r = 0; r < 4; ++r)
        out[(size_t)(grow + r) * HID + gcol] = acc[mi][ni][r] + bz;
    }
  }
}

// ---------------- Path B (fallback): fp32-source GEMM -----------------------
template <typename AT, typename CT>
__device__ __forceinline__ void gemm128_tile(
    const AT* __restrict__ Ap, int lda,
    const float* __restrict__ Wp, int ldw,
    const float* __restrict__ biasp,
    CT* __restrict__ Cp, int ldc,
    int K)
{
  __shared__ __align__(16) bf16_t Al[128 * 32];
  __shared__ __align__(16) bf16_t Bl[128 * 32];

  const int tid  = threadIdx.x;
  const int lane = tid & 63;
  const int w    = tid >> 6;
  const int fr   = lane & 15;
  const int quad = lane >> 4;
  const int wm   = (w >> 1) * 64;
  const int wn   = (w & 1) * 64;

  const f32x4 z4 = {0.f, 0.f, 0.f, 0.f};
  f32x4 acc[4][4];
  for (int i = 0; i < 4; ++i)
    for (int j = 0; j < 4; ++j) acc[i][j] = z4;

  const int c0    = w * 2;
  const int srow0 = lane >> 2;
  const int skc   = (lane & 3) * 8;

  for (int k0 = 0; k0 < K; k0 += 32) {
    bf16x8 av[2], bv[2];
    for (int t = 0; t < 2; ++t) {
      const int r = (c0 + t) * 16 + srow0;
      av[t] = ld8(Ap + (size_t)r * lda + k0 + skc);
      bv[t] = ld8(Wp + (size_t)r * ldw + k0 + skc);
    }
    for (int t = 0; t < 2; ++t) {
      const int c = c0 + t;
      *(bf16x8*)&Al[c * 512 + lane * 8] = av[t];
      *(bf16x8*)&Bl[c * 512 + lane * 8] = bv[t];
    }
    __syncthreads();
    bf16x8 af[4], bfr[4];
    for (int mi = 0; mi < 4; ++mi)
      af[mi] = *(const bf16x8*)&Al[(wm + mi * 16 + fr) * 32 + quad * 8];
    for (int ni = 0; ni < 4; ++ni)
      bfr[ni] = *(const bf16x8*)&Bl[(wn + ni * 16 + fr) * 32 + quad * 8];
    for (int mi = 0; mi < 4; ++mi)
      for (int ni = 0; ni < 4; ++ni)
        acc[mi][ni] = mfma16(af[mi], bfr[ni], acc[mi][ni]);
    __syncthreads();
  }

  for (int ni = 0; ni < 4; ++ni) {
    const int col = wn + ni * 16 + fr;
    const float bz = biasp[col];
    for (int mi = 0; mi < 4; ++mi) {
      const int r0 = wm + mi * 16 + quad * 4;
      for (int r = 0; r < 4; ++r)
        st_c(Cp + (size_t)(r0 + r) * ldc + col, acc[mi][ni][r] + bz);
    }
  }
}

__global__ __launch_bounds__(256) void qkv_kernel(
    const float* __restrict__ x,
    const float* __restrict__ Wq, const float* __restrict__ bq,
    const float* __restrict__ Wk, const float* __restrict__ bk,
    const float* __restrict__ Wv, const float* __restrict__ bv,
    bf16_t* Qb, bf16_t* Kb, bf16_t* Vb)
{
  const int nb = blockIdx.x;
  const int mb = blockIdx.y;
  const float* W; const float* bias; bf16_t* C; int ldc;
  if (nb < 16)      { W = Wq + (size_t)nb * 128 * HID;  bias = bq + nb * 128;
                      C = Qb + nb * 128; ldc = HID; }
  else if (nb < 20) { const int j = nb - 16;
                      W = Wk + (size_t)j * 128 * HID;   bias = bk + j * 128;
                      C = Kb + j * 128; ldc = KVW; }
  else              { const int j = nb - 20;
                      W = Wv + (size_t)j * 128 * HID;   bias = bv + j * 128;
                      C = Vb + j * 128; ldc = KVW; }
  gemm128_tile<float, bf16_t>(x + (size_t)mb * 128 * HID, HID, W, HID, bias,
                              C + (size_t)mb * 128 * ldc, ldc, HID);
}

__global__ __launch_bounds__(256) void oproj_kernel(
    const bf16_t* __restrict__ A, const float* __restrict__ Wo,
    const float* __restrict__ bo, float* out)
{
  const int nb = blockIdx.x, mb = blockIdx.y;
  gemm128_tile<bf16_t, float>(A + (size_t)mb * 128 * HID, HID,
                              Wo + (size_t)nb * 128 * HID, HID,
                              bo + nb * 128,
                              out + (size_t)mb * 128 * HID + nb * 128, HID, HID);
}

__global__ __launch_bounds__(256) void vtrans_kernel(
    const bf16_t* __restrict__ Vb, bf16_t* __restrict__ VbT)
{
  __shared__ bf16_t T[64][72];
  const int st = blockIdx.x, kvh = blockIdx.y, b = blockIdx.z;
  const int tid = threadIdx.x;
  {
    const int row = tid >> 2;
    const int c16 = (tid & 3) * 16;
    const bf16_t* src =
        Vb + ((size_t)b * SLEN + st * 64 + row) * KVW + kvh * HDIM + c16;
    *(bf16x8*)&T[row][c16]     = *(const bf16x8*)(src);
    *(bf16x8*)&T[row][c16 + 8] = *(const bf16x8*)(src + 8);
  }
  __syncthreads();
  {
    const int d  = tid >> 2;
    const int sc = (tid & 3) * 16;
    bf16_t tmp[16];
    for (int j = 0; j < 16; ++j) tmp[j] = T[sc + j][d];
    bf16_t* dst = VbT + ((size_t)(b * NKVH + kvh) * HDIM + d) * SLEN + st * 64 + sc;
    *(bf16x8*)dst       = *(bf16x8*)&tmp[0];
    *(bf16x8*)(dst + 8) = *(bf16x8*)&tmp[8];
  }
}

// ---------------- Flash attention: dbuf K/V + in-register P -----------------
// 8 waves, QBLK=128, KVBLK=128, grid 512 (xcd = bid&7 -> one kvh per XCD).
// Double-buffered K/V LDS (2x32KB): stage(t+1) issued BEFORE compute(t), so
// HBM/L2 latency hides under 36 MFMAs + softmax; vmcnt(0) after compute ~free.
// O epilogue bounces through LDS for coalesced 32B/thread stores.
__global__ __launch_bounds__(512, 4) void attn_kernel(
    const bf16_t* Q, const bf16_t* __restrict__ Kg,
    const bf16_t* __restrict__ VT, bf16_t* O)
{
  const int bid = blockIdx.x;            // 0..511
  const int kvh = bid & 7;               // one kvh per XCD
  const int jb  = bid >> 3;              // 0..63
  const int b   = jb >> 5;
  const int rem = jb & 31;
  const int h   = kvh * 4 + (rem & 3);
  const int pid = rem >> 2;              // 0..7

  const int tid  = threadIdx.x;
  const int lane = tid & 63;
  const int w    = tid >> 6;             // 0..7
  const int fr   = lane & 15;
  const int quad = lane >> 4;

  __shared__ __align__(16) bf16_t lds[32768];  // 2 x (KL 8192 + VtL 8192)

  const size_t qbase = (size_t)b * SLEN;
  const bf16_t* VTh = VT + (size_t)(b * NKVH + kvh) * HDIM * SLEN;

  const int sig = ((quad & 1) << 1) | ((quad >> 1) & 1);   // 0,2,1,3
  const int fsw = (fr >> 1) & 3;
  const bool oddq = (quad & 1);

  bf16x8 ones8;
  {
    const bf16_t o1 = (bf16_t)(fr == 0 ? 1.0f : 0.0f);
#pragma unroll
    for (int j2 = 0; j2 < 8; ++j2) ones8[j2] = o1;
  }

  auto STAGE_KV = [&](int kt, bf16_t* KL) {
    const size_t krow0 = qbase + (size_t)kt * 128;
    bf16_t* VtL = KL + 8192;
#pragma unroll
    for (int jj = 0; jj < 2; ++jj) {
      const int s  = jj * 512 + tid;
      const int ks = s >> 9, kr = (s >> 2) & 127, c8 = (s & 3) ^ ((kr >> 1) & 3);
      gl2lds16(&Kg[(krow0 + kr) * KVW + kvh * HDIM + ks * 32 + c8 * 8],
               &KL[s * 8]);
    }
#pragma unroll
    for (int jj = 0; jj < 2; ++jj) {
      const int idx = jj * 512 + tid;
      const int kb = idx >> 8, d = (idx >> 2) & 63, c8 = (idx & 3) ^ ((d >> 1) & 3);
      gl2lds16(&VTh[(size_t)d * SLEN + kt * 128 + kb * 32 + c8 * 8],
               &VtL[idx * 8]);
    }
  };

  for (int half = 0; half < 2; ++half) {
    const int qt = half ? (15 - pid) : pid;
    const int q0 = qt * 128;

    bf16x8 qf[2];
#pragma unroll
    for (int ks = 0; ks < 2; ++ks)
      qf[ks] = *(const bf16x8*)&Q[(qbase + q0 + w * 16 + fr) * HID
                                  + h * HDIM + ks * 32 + quad * 8];

    const f32x4 z4 = {0.f, 0.f, 0.f, 0.f};
    f32x4 o_acc[4];
    f32x4 o_l = z4;
#pragma unroll
    for (int di = 0; di < 4; ++di) o_acc[di] = z4;

    const int ktmax = qt;
    const int qloc  = w * 16 + fr;       // q local to the 128-row diag tile

    // prologue: stage kt=0 into buf0
    STAGE_KV(0, lds);
    asm volatile("s_waitcnt vmcnt(0)" ::: "memory");
    phase_barrier();

    int cur = 0;
    for (int kt = 0; kt <= ktmax; ++kt) {
      bf16_t* KL  = lds + cur * 16384;
      bf16_t* VtL = KL + 8192;
      if (kt < ktmax) STAGE_KV(kt + 1, lds + (cur ^ 1) * 16384);

      // QK^T swapped: s8[ki] rows = k (quad*4+r), cols = q (fr)
      f32x4 s8[8];
#pragma unroll
      for (int ki = 0; ki < 8; ++ki) s8[ki] = z4;
      __builtin_amdgcn_s_setprio(1);
#pragma unroll
      for (int ks = 0; ks < 2; ++ks)
#pragma unroll
        for (int ki = 0; ki < 8; ++ki) {
          bf16x8 kf = *(const bf16x8*)&KL[ks * 4096 + (ki * 16 + fr) * 32
                                          + ((quad ^ fsw) << 3)];
          s8[ki] = mfma16(kf, qf[ks], s8[ki]);
        }
      __builtin_amdgcn_s_setprio(0);

      const float C2 = 0.18033688f;   // log2(e)/8
      const bool diag = (kt == ktmax);

#pragma unroll
      for (int m = 0; m < 4; ++m) {
        float pe[8];
#pragma unroll
        for (int ki2 = 0; ki2 < 2; ++ki2) {
          const int ki = 2 * m + ki2;
#pragma unroll
          for (int r = 0; r < 4; ++r) {
            float p = fast_exp2(s8[ki][r] * C2);
            if (diag && (ki * 16 + quad * 4 + r > qloc)) p = 0.f;
            pe[ki2 * 4 + r] = p;
          }
        }
        uint32_t pw0 = pack2(pe[0], pe[1]);
        uint32_t pw1 = pack2(pe[2], pe[3]);
        uint32_t pw2 = pack2(pe[4], pe[5]);
        uint32_t pw3 = pack2(pe[6], pe[7]);
        uint32_t x0 = oddq ? pw0 : pw2;
        uint32_t x1 = oddq ? pw1 : pw3;
        uint32_t r0 = (uint32_t)__shfl_xor((int)x0, 16);
        uint32_t r1 = (uint32_t)__shfl_xor((int)x1, 16);
        union { uint32_t u[4]; bf16x8 v; } pb;
        pb.u[0] = oddq ? r0 : pw0;
        pb.u[1] = oddq ? r1 : pw1;
        pb.u[2] = oddq ? pw2 : r0;
        pb.u[3] = oddq ? pw3 : r1;

        __builtin_amdgcn_s_setprio(1);
        o_l = mfma16(pb.v, ones8, o_l);
#pragma unroll
        for (int di = 0; di < 4; ++di) {
          bf16x8 vf = *(const bf16x8*)&VtL[m * 2048 + (di * 16 + fr) * 32
                                           + ((sig ^ fsw) << 3)];
          o_acc[di] = mfma16(pb.v, vf, o_acc[di]);
        }
        __builtin_amdgcn_s_setprio(0);
      }

      asm volatile("s_waitcnt vmcnt(0)" ::: "memory");
      phase_barrier();
      cur ^= 1;
    }

    // epilogue: scale, bounce through LDS (reuse buf0), coalesced stores
    bf16_t* OB = lds;   // 128 x 64 bf16 = 16KB
#pragma unroll
    for (int r = 0; r < 4; ++r) {
      const float l  = __shfl(o_l[r], lane & 48);
      const float rl = 1.f / l;
      const int q = w * 16 + quad * 4 + r;
#pragma unroll
      for (int di = 0; di < 4; ++di)
        OB[q * 64 + di * 16 + fr] = (bf16_t)(o_acc[di][r] * rl);
    }
    asm volatile("s_waitcnt lgkmcnt(0)" ::: "memory");
    phase_barrier();
    {
      const int row = tid >> 2;          // 0..127
      const int seg = tid & 3;           // 0..3 (16 bf16 each)
      bf16x8 v0 = *(const bf16x8*)&OB[row * 64 + seg * 16];
      bf16x8 v1 = *(const bf16x8*)&OB[row * 64 + seg * 16 + 8];
      bf16_t* dst = &O[(qbase + q0 + row) * HID + h * HDIM + seg * 16];
      *(bf16x8*)dst       = v0;
      *(bf16x8*)(dst + 8) = v1;
    }
    phase_barrier();   // protect OB before next half's staging
  }
}

extern "C" void kernel_launch(void* const* d_in, const int* in_sizes, int n_in,
                              void* d_out, int out_size, void* d_ws, size_t ws_size,
                              hipStream_t stream) {
  const float* x  = (const float*)d_in[0];
  // d_in[1] = causal mask (int32) -- recomputed inline, not read
  const float* Wq = (const float*)d_in[2];
  const float* bq = (const float*)d_in[3];
  const float* Wk = (const float*)d_in[4];
  const float* bk = (const float*)d_in[5];
  const float* Wv = (const float*)d_in[6];
  const float* bv = (const float*)d_in[7];
  const float* Wo = (const float*)d_in[8];
  const float* bo = (const float*)d_in[9];
  float* out = (float*)d_out;

  const size_t M = (size_t)NB * SLEN;          // 4096
  dim3 blk(256, 1, 1);

  const size_t needA = (M * HID
                        + (size_t)HID * HID
                        + (size_t)KVW * HID
                        + (size_t)KVW * HID
                        + (size_t)HID * HID
                        + M * HID
                        + M * KVW
                        + M * KVW) * 2
                       + (size_t)(HID + 2 * KVW) * sizeof(float);
  if (ws_size >= needA) {
    bf16_t* xb  = (bf16_t*)d_ws;
    bf16_t* Wqb = xb  + M * HID;              // Wq|Wk|Wv contiguous = Wcat
    bf16_t* Wkb = Wqb + (size_t)HID * HID;
    bf16_t* Wvb = Wkb + (size_t)KVW * HID;
    bf16_t* Wob = Wvb + (size_t)KVW * HID;
    bf16_t* Qb  = Wob + (size_t)HID * HID;
    bf16_t* Kb  = Qb  + M * HID;
    bf16_t* VbT = Kb  + M * KVW;
    float*  bcat = (float*)(VbT + M * KVW);   // [bq|bk|bv], 3072 floats

    cvt_kernel<<<dim3(1024, 8, 1), blk, 0, stream>>>(
        x, Wq, Wk, Wv, Wo, bq, bk, bv, xb, Wqb, Wkb, Wvb, Wob, bcat);
    qkv8_kernel<<<dim3(12, 16, 1), dim3(512, 1, 1), 0, stream>>>(
        xb, Wqb, bcat, Qb, Kb, VbT);
    attn_kernel<<<dim3(512, 1, 1), dim3(512, 1, 1), 0, stream>>>(Qb, Kb, VbT, Qb);
    oproj8_kernel<<<dim3(8, 16, 1), dim3(512, 1, 1), 0, stream>>>(
        Qb, Wob, bo, out);
  } else {
    bf16_t* Qb  = (bf16_t*)d_ws;
    bf16_t* Kb  = Qb + M * HID;
    bf16_t* Vb  = Kb + M * KVW;
    bf16_t* VbT = Vb + M * KVW;

    qkv_kernel<<<dim3(24, 32, 1), blk, 0, stream>>>(x, Wq, bq, Wk, bk, Wv, bv, Qb, Kb, Vb);
    vtrans_kernel<<<dim3(32, 8, 2), blk, 0, stream>>>(Vb, VbT);
    attn_kernel<<<dim3(512, 1, 1), dim3(512, 1, 1), 0, stream>>>(Qb, Kb, VbT, Qb);
    oproj_kernel<<<dim3(16, 32, 1), blk, 0, stream>>>(Qb, Wo, bo, out);
  }
}

// Round 5
// 285.767 us; speedup vs baseline: 1.1218x; 1.0490x over previous
//
#include <hip/hip_runtime.h>
#include <hip/hip_bf16.h>
#include <stdint.h>

#define HID   2048
#define SLEN  2048
#define NB    2
#define NHEADS 32
#define NKVH   8
#define HDIM   64
#define KVW    512   // NKVH*HDIM

typedef __bf16 bf16_t;
typedef __bf16 bf16x2 __attribute__((ext_vector_type(2)));
typedef __bf16 bf16x4 __attribute__((ext_vector_type(4)));
typedef __bf16 bf16x8 __attribute__((ext_vector_type(8)));
typedef float  f32x4  __attribute__((ext_vector_type(4)));

__device__ __forceinline__ f32x4 mfma16(bf16x8 a, bf16x8 b, f32x4 c) {
  return __builtin_amdgcn_mfma_f32_16x16x32_bf16(a, b, c, 0, 0, 0);
}

__device__ __forceinline__ void gl2lds16(const bf16_t* g, bf16_t* l) {
  __builtin_amdgcn_global_load_lds(
      (const __attribute__((address_space(1))) void*)g,
      (__attribute__((address_space(3))) void*)l,
      16, 0, 0);
}

__device__ __forceinline__ float fast_exp2(float x) {
#if __has_builtin(__builtin_amdgcn_exp2f)
  return __builtin_amdgcn_exp2f(x);
#else
  return __expf(x * 0.69314718f);
#endif
}

__device__ __forceinline__ bf16x8 ld8(const bf16_t* p) {
  return *(const bf16x8*)p;
}
__device__ __forceinline__ bf16x8 ld8(const float* p) {
  f32x4 a = *(const f32x4*)p;
  f32x4 b = *(const f32x4*)(p + 4);
  bf16x8 r;
  r[0] = (bf16_t)a[0]; r[1] = (bf16_t)a[1]; r[2] = (bf16_t)a[2]; r[3] = (bf16_t)a[3];
  r[4] = (bf16_t)b[0]; r[5] = (bf16_t)b[1]; r[6] = (bf16_t)b[2]; r[7] = (bf16_t)b[3];
  return r;
}

__device__ __forceinline__ uint32_t pack2(float a, float b) {
  bf16x2 t; t[0] = (bf16_t)a; t[1] = (bf16_t)b;
  return __builtin_bit_cast(uint32_t, t);
}

__device__ __forceinline__ void st_c(bf16_t* p, float v) { *p = (bf16_t)v; }
__device__ __forceinline__ void st_c(float*  p, float v) { *p = v; }

// ---------------- fp32 -> bf16 convert pass + bias concat -------------------
__global__ __launch_bounds__(256) void cvt_kernel(
    const float* __restrict__ x,  const float* __restrict__ wq,
    const float* __restrict__ wk, const float* __restrict__ wv,
    const float* __restrict__ wo,
    const float* __restrict__ bq, const float* __restrict__ bk,
    const float* __restrict__ bv,
    bf16_t* xb, bf16_t* wqb, bf16_t* wkb, bf16_t* wvb, bf16_t* wob,
    float* bcat)
{
  if (blockIdx.y >= 5) {   // float->float bias concat
    const float* fs; float* fd; size_t n;
    if (blockIdx.y == 5)      { fs = bq; fd = bcat;        n = HID; }
    else if (blockIdx.y == 6) { fs = bk; fd = bcat + HID;  n = KVW; }
    else                      { fs = bv; fd = bcat + HID + KVW; n = KVW; }
    const size_t stride4 = (size_t)gridDim.x * 256 * 4;
    for (size_t i = ((size_t)blockIdx.x * 256 + threadIdx.x) * 4; i < n; i += stride4)
      *(f32x4*)(fd + i) = *(const f32x4*)(fs + i);
    return;
  }
  const float* s; bf16_t* d; size_t n;
  switch (blockIdx.y) {
    case 0:  s = x;  d = xb;  n = (size_t)NB * SLEN * HID; break;
    case 1:  s = wq; d = wqb; n = (size_t)HID * HID; break;
    case 2:  s = wk; d = wkb; n = (size_t)KVW * HID; break;
    case 3:  s = wv; d = wvb; n = (size_t)KVW * HID; break;
    default: s = wo; d = wob; n = (size_t)HID * HID; break;
  }
  const size_t stride = (size_t)gridDim.x * 256 * 8;
  for (size_t i = ((size_t)blockIdx.x * 256 + threadIdx.x) * 8; i < n; i += stride)
    *(bf16x8*)(d + i) = ld8(s + i);
}

// =============== 256xBN 8-phase GEMM template (T1+T2+T3+T4+T5) ==============
// BM=256 rows, BK=64, BN = U*64 (U = 4, 3, or 2). 512 threads = 8 waves
// (2M x 4N); per-wave C = 128 x (U*16). LDS = 2 x (A 32KB + B U*8KB).
// Staging unit = 8KB = 64 rows x 64 k (1 gl2lds16/thread). A = 4 units,
// B = U units. vmcnt(U) at K-tile boundaries (B units of next-next tile
// stay in flight; in-order drain guarantees consumed buffers landed).
__device__ __forceinline__ bf16x8 ldfrag(const bf16_t* __restrict__ Lh, int r, int g) {
  return *(const bf16x8*)(Lh + r * 64 + ((g ^ (r & 7)) << 3));
}

template <int N>
__device__ __forceinline__ void vm_wait() {
  if constexpr (N == 0)      asm volatile("s_waitcnt vmcnt(0)" ::: "memory");
  else if constexpr (N == 2) asm volatile("s_waitcnt vmcnt(2)" ::: "memory");
  else if constexpr (N == 3) asm volatile("s_waitcnt vmcnt(3)" ::: "memory");
  else                       asm volatile("s_waitcnt vmcnt(4)" ::: "memory");
}

template <int Q, int U>
__device__ __forceinline__ void mfma_quadU(const bf16x8 (&af)[2][2],
                                           const bf16x8 (&bfr)[U][2],
                                           f32x4 (&acc)[8][U]) {
#pragma unroll
  for (int ks = 0; ks < 2; ++ks)
#pragma unroll
    for (int i = 0; i < 2; ++i)
#pragma unroll
      for (int ni = 0; ni < U; ++ni)
        acc[2 * Q + i][ni] = mfma16(af[i][ks], bfr[ni][ks], acc[2 * Q + i][ni]);
}

__device__ __forceinline__ void phase_barrier() {
  __builtin_amdgcn_s_barrier();
  asm volatile("" ::: "memory");
}

template <int U>
__device__ __forceinline__ void gemm_core_u(
    const bf16_t* __restrict__ Ag,
    const bf16_t* __restrict__ Bg,
    bf16_t* __restrict__ lds, f32x4 (&acc)[8][U])
{
  const int tid  = threadIdx.x;
  const int lane = tid & 63;
  const int w    = tid >> 6;
  const int fr   = lane & 15;
  const int quad = lane >> 4;
  const int wr   = w >> 2;
  const int wc   = w & 3;

  bf16_t* A0 = lds;
  bf16_t* B0 = lds + 16384;
  bf16_t* A1 = B0 + U * 4096;
  bf16_t* B1 = A1 + 16384;

  const f32x4 z4 = {0.f, 0.f, 0.f, 0.f};
#pragma unroll
  for (int i = 0; i < 8; ++i)
#pragma unroll
    for (int j = 0; j < U; ++j) acc[i][j] = z4;

  auto STAGEU = [&](const bf16_t* __restrict__ Gp, bf16_t* __restrict__ Lb, int u) {
    const int r = tid >> 3;
    const int g = (tid & 7) ^ (r & 7);
    gl2lds16(Gp + (size_t)(u * 64 + r) * HID + g * 8, Lb + u * 4096 + tid * 8);
  };
  auto LDB = [&](const bf16_t* __restrict__ Bb, bf16x8 (&bfr)[U][2]) {
#pragma unroll
    for (int ni = 0; ni < U; ++ni)
#pragma unroll
      for (int ks = 0; ks < 2; ++ks)
        bfr[ni][ks] = ldfrag(Bb, wc * (16 * U) + ni * 16 + fr, ks * 4 + quad);
  };
  auto LDA = [&](const bf16_t* __restrict__ Ab, int q, bf16x8 (&af)[2][2]) {
#pragma unroll
    for (int i = 0; i < 2; ++i)
#pragma unroll
      for (int ks = 0; ks < 2; ++ks)
        af[i][ks] = ldfrag(Ab, wr * 128 + q * 32 + i * 16 + fr, ks * 4 + quad);
  };

  // prologue: B(0), A(0), B(1)
#pragma unroll
  for (int u = 0; u < U; ++u) STAGEU(Bg, B0, u);
#pragma unroll
  for (int u = 0; u < 4; ++u) STAGEU(Ag, A0, u);
#pragma unroll
  for (int u = 0; u < U; ++u) STAGEU(Bg + 64, B1, u);
  vm_wait<U>();
  phase_barrier();

  bf16x8 bfr[U][2], af[2][2];

#pragma unroll 1
  for (int it = 0; it < 16; ++it) {
    const bool more = (it < 15);
    const size_t k1 = (size_t)(2 * it + 1) * 64;
    const size_t k2 = (size_t)(2 * it + 2) * 64;
    const size_t k3 = (size_t)(2 * it + 3) * 64;

    // ---- p0: tile t (buf0) q0; stage A(t+1) u0,u1 -> A1
    LDB(B0, bfr);
    LDA(A0, 0, af);
    STAGEU(Ag + k1, A1, 0); STAGEU(Ag + k1, A1, 1);
    phase_barrier();
    asm volatile("s_waitcnt lgkmcnt(0)" ::: "memory");
    __builtin_amdgcn_s_setprio(1);
    mfma_quadU<0>(af, bfr, acc);
    __builtin_amdgcn_s_setprio(0);
    phase_barrier();

    // ---- p1: q1; stage A(t+1) u2,u3
    LDA(A0, 1, af);
    STAGEU(Ag + k1, A1, 2); STAGEU(Ag + k1, A1, 3);
    phase_barrier();
    asm volatile("s_waitcnt lgkmcnt(0)" ::: "memory");
    __builtin_amdgcn_s_setprio(1);
    mfma_quadU<1>(af, bfr, acc);
    __builtin_amdgcn_s_setprio(0);
    phase_barrier();

    // ---- p2: q2; stage B(t+2) first units
    LDA(A0, 2, af);
    if (more) {
#pragma unroll
      for (int u = 0; u < (U + 1) / 2; ++u) STAGEU(Bg + k2, B0, u);
    }
    phase_barrier();
    asm volatile("s_waitcnt lgkmcnt(0)" ::: "memory");
    __builtin_amdgcn_s_setprio(1);
    mfma_quadU<2>(af, bfr, acc);
    __builtin_amdgcn_s_setprio(0);
    phase_barrier();

    // ---- p3: q3; stage B(t+2) rest; K-tile boundary vmcnt
    LDA(A0, 3, af);
    if (more) {
#pragma unroll
      for (int u = (U + 1) / 2; u < U; ++u) STAGEU(Bg + k2, B0, u);
    }
    phase_barrier();
    asm volatile("s_waitcnt lgkmcnt(0)" ::: "memory");
    __builtin_amdgcn_s_setprio(1);
    mfma_quadU<3>(af, bfr, acc);
    __builtin_amdgcn_s_setprio(0);
    if (more) vm_wait<U>(); else vm_wait<0>();
    phase_barrier();

    // ---- p4: tile t+1 (buf1) q0; stage A(t+2) u0,u1 -> A0
    LDB(B1, bfr);
    LDA(A1, 0, af);
    if (more) { STAGEU(Ag + k2, A0, 0); STAGEU(Ag + k2, A0, 1); }
    phase_barrier();
    asm volatile("s_waitcnt lgkmcnt(0)" ::: "memory");
    __builtin_amdgcn_s_setprio(1);
    mfma_quadU<0>(af, bfr, acc);
    __builtin_amdgcn_s_setprio(0);
    phase_barrier();

    // ---- p5: q1; stage A(t+2) u2,u3
    LDA(A1, 1, af);
    if (more) { STAGEU(Ag + k2, A0, 2); STAGEU(Ag + k2, A0, 3); }
    phase_barrier();
    asm volatile("s_waitcnt lgkmcnt(0)" ::: "memory");
    __builtin_amdgcn_s_setprio(1);
    mfma_quadU<1>(af, bfr, acc);
    __builtin_amdgcn_s_setprio(0);
    phase_barrier();

    // ---- p6: q2; stage B(t+3) first units
    LDA(A1, 2, af);
    if (more) {
#pragma unroll
      for (int u = 0; u < (U + 1) / 2; ++u) STAGEU(Bg + k3, B1, u);
    }
    phase_barrier();
    asm volatile("s_waitcnt lgkmcnt(0)" ::: "memory");
    __builtin_amdgcn_s_setprio(1);
    mfma_quadU<2>(af, bfr, acc);
    __builtin_amdgcn_s_setprio(0);
    phase_barrier();

    // ---- p7: q3; stage B(t+3) rest; iter boundary vmcnt
    LDA(A1, 3, af);
    if (more) {
#pragma unroll
      for (int u = (U + 1) / 2; u < U; ++u) STAGEU(Bg + k3, B1, u);
    }
    phase_barrier();
    asm volatile("s_waitcnt lgkmcnt(0)" ::: "memory");
    __builtin_amdgcn_s_setprio(1);
    mfma_quadU<3>(af, bfr, acc);
    __builtin_amdgcn_s_setprio(0);
    if (more) vm_wait<U>();
    phase_barrier();
  }
}

// Region-chunked XCD swizzle for a 16x16 (cb x mb) grid: each XCD owns an
// 8cb x 4mb region; its 32 co-resident blocks run in lockstep with a ~320KB
// per-K-step working set -> L2-resident panel reuse.
__device__ __forceinline__ void grid_map16(int orig, int& cb, int& mb) {
  const int xcd = orig & 7, wp = orig >> 3;
  cb = (xcd & 1) * 8 + (wp & 7);
  mb = (xcd >> 1) * 4 + (wp >> 3);
}

// QKV: BN=192, grid 256. Wcat = [Wq|Wk|Wv] rows; strip cb covers cols
// cb*192..cb*192+191 of the fused 3072-col output. Epilogue bounces through
// LDS [256][200] for coalesced stores; V columns read back transposed.
__global__ __launch_bounds__(512, 2) void qkv8_kernel(
    const bf16_t* __restrict__ xb, const bf16_t* __restrict__ Wcat,
    const float* __restrict__ bcat,
    bf16_t* __restrict__ Qb, bf16_t* __restrict__ Kb, bf16_t* __restrict__ VbT)
{
  __shared__ __align__(16) bf16_t lds[57344];   // 112 KB
  int cb, mb;
  grid_map16(blockIdx.x, cb, mb);

  f32x4 acc[8][3];
  gemm_core_u<3>(xb + (size_t)mb * 256 * HID, Wcat + (size_t)cb * 192 * HID,
                 lds, acc);

  const int tid = threadIdx.x, lane = tid & 63, w = tid >> 6;
  const int fr = lane & 15, quad = lane >> 4, wr = w >> 2, wc = w & 3;
  const int CP = 200;
  bf16_t* C = lds;
#pragma unroll
  for (int ni = 0; ni < 3; ++ni) {
    const int col = wc * 48 + ni * 16 + fr;
    const float bz = bcat[cb * 192 + col];
#pragma unroll
    for (int mi = 0; mi < 8; ++mi)
#pragma unroll
      for (int r = 0; r < 4; ++r)
        C[(wr * 128 + mi * 16 + quad * 4 + r) * CP + col] =
            (bf16_t)(acc[mi][ni][r] + bz);
  }
  asm volatile("s_waitcnt lgkmcnt(0)" ::: "memory");
  phase_barrier();

  // Q/K copy-out: 256 rows x 24 col-groups of 8 (16B chunks)
#pragma unroll
  for (int i = 0; i < 12; ++i) {
    const unsigned task = (unsigned)(i * 512 + tid);
    const unsigned row = task / 24u;
    const unsigned cg  = task - row * 24u;
    const int gcol0 = cb * 192 + (int)cg * 8;
    const int grow  = mb * 256 + (int)row;
    bf16x8 v = *(const bf16x8*)&C[row * CP + cg * 8];
    if (gcol0 < 2048)
      *(bf16x8*)&Qb[(size_t)grow * HID + gcol0] = v;
    else if (gcol0 < 2560)
      *(bf16x8*)&Kb[(size_t)grow * KVW + (gcol0 - 2048)] = v;
    // V chunks handled transposed below
  }
  // V copy-out (transposed): cb >= 13 carries V columns
  if (cb >= 13) {
    const int colbase = (cb == 13) ? 64 : 0;
    const int Nv = 192 - colbase;
    const int b = mb >> 3;
    const int s0 = (mb & 7) * 256;
#pragma unroll
    for (int i = 0; i < 12; ++i) {
      const int task = i * 512 + tid;
      const int vi = task >> 5, si = task & 31;
      if (vi < Nv) {
        const int col = colbase + vi;
        const int vc  = cb * 192 + col - 2560;       // 0..511
        bf16x8 pk;
#pragma unroll
        for (int j = 0; j < 8; ++j) pk[j] = C[(si * 8 + j) * CP + col];
        *(bf16x8*)&VbT[((size_t)(b * NKVH + (vc >> 6)) * HDIM + (vc & 63)) * SLEN
                       + s0 + si * 8] = pk;
      }
    }
  }
}

// O-proj: BN=128, grid 256, f32 out. Epilogue in two 128-row slabs through
// LDS [128][132] f32 for coalesced 16B stores.
__global__ __launch_bounds__(512, 2) void oproj8_kernel(
    const bf16_t* __restrict__ A, const bf16_t* __restrict__ Wob,
    const float* __restrict__ bo, float* __restrict__ out)
{
  __shared__ __align__(16) bf16_t lds[49152];   // 96 KB
  int cb, mb;
  grid_map16(blockIdx.x, cb, mb);

  f32x4 acc[8][2];
  gemm_core_u<2>(A + (size_t)mb * 256 * HID, Wob + (size_t)cb * 128 * HID,
                 lds, acc);

  const int tid = threadIdx.x, lane = tid & 63, w = tid >> 6;
  const int fr = lane & 15, quad = lane >> 4, wr = w >> 2, wc = w & 3;
  const int CPF = 132;
  float* Cf = (float*)lds;
#pragma unroll
  for (int s = 0; s < 2; ++s) {
    if (wr == s) {
#pragma unroll
      for (int ni = 0; ni < 2; ++ni) {
        const int col = wc * 32 + ni * 16 + fr;
        const float bz = bo[cb * 128 + col];
#pragma unroll
        for (int mi = 0; mi < 8; ++mi)
#pragma unroll
          for (int r = 0; r < 4; ++r)
            Cf[(mi * 16 + quad * 4 + r) * CPF + col] = acc[mi][ni][r] + bz;
      }
    }
    asm volatile("s_waitcnt lgkmcnt(0)" ::: "memory");
    phase_barrier();
#pragma unroll
    for (int i = 0; i < 8; ++i) {
      const int task = i * 512 + tid;
      const int row = task >> 5, cg = task & 31;
      f32x4 v = *(const f32x4*)&Cf[row * CPF + cg * 4];
      *(f32x4*)&out[(size_t)(mb * 256 + s * 128 + row) * HID + cb * 128 + cg * 4] = v;
    }
    phase_barrier();
  }
}

// ---------------- Path B (fallback): fp32-source GEMM -----------------------
template <typename AT, typename CT>
__device__ __forceinline__ void gemm128_tile(
    const AT* __restrict__ Ap, int lda,
    const float* __restrict__ Wp, int ldw,
    const float* __restrict__ biasp,
    CT* __restrict__ Cp, int ldc,
    int K)
{
  __shared__ __align__(16) bf16_t Al[128 * 32];
  __shared__ __align__(16) bf16_t Bl[128 * 32];

  const int tid  = threadIdx.x;
  const int lane = tid & 63;
  const int w    = tid >> 6;
  const int fr   = lane & 15;
  const int quad = lane >> 4;
  const int wm   = (w >> 1) * 64;
  const int wn   = (w & 1) * 64;

  const f32x4 z4 = {0.f, 0.f, 0.f, 0.f};
  f32x4 acc[4][4];
  for (int i = 0; i < 4; ++i)
    for (int j = 0; j < 4; ++j) acc[i][j] = z4;

  const int c0    = w * 2;
  const int srow0 = lane >> 2;
  const int skc   = (lane & 3) * 8;

  for (int k0 = 0; k0 < K; k0 += 32) {
    bf16x8 av[2], bv[2];
    for (int t = 0; t < 2; ++t) {
      const int r = (c0 + t) * 16 + srow0;
      av[t] = ld8(Ap + (size_t)r * lda + k0 + skc);
      bv[t] = ld8(Wp + (size_t)r * ldw + k0 + skc);
    }
    for (int t = 0; t < 2; ++t) {
      const int c = c0 + t;
      *(bf16x8*)&Al[c * 512 + lane * 8] = av[t];
      *(bf16x8*)&Bl[c * 512 + lane * 8] = bv[t];
    }
    __syncthreads();
    bf16x8 af[4], bfr[4];
    for (int mi = 0; mi < 4; ++mi)
      af[mi] = *(const bf16x8*)&Al[(wm + mi * 16 + fr) * 32 + quad * 8];
    for (int ni = 0; ni < 4; ++ni)
      bfr[ni] = *(const bf16x8*)&Bl[(wn + ni * 16 + fr) * 32 + quad * 8];
    for (int mi = 0; mi < 4; ++mi)
      for (int ni = 0; ni < 4; ++ni)
        acc[mi][ni] = mfma16(af[mi], bfr[ni], acc[mi][ni]);
    __syncthreads();
  }

  for (int ni = 0; ni < 4; ++ni) {
    const int col = wn + ni * 16 + fr;
    const float bz = biasp[col];
    for (int mi = 0; mi < 4; ++mi) {
      const int r0 = wm + mi * 16 + quad * 4;
      for (int r = 0; r < 4; ++r)
        st_c(Cp + (size_t)(r0 + r) * ldc + col, acc[mi][ni][r] + bz);
    }
  }
}

__global__ __launch_bounds__(256) void qkv_kernel(
    const float* __restrict__ x,
    const float* __restrict__ Wq, const float* __restrict__ bq,
    const float* __restrict__ Wk, const float* __restrict__ bk,
    const float* __restrict__ Wv, const float* __restrict__ bv,
    bf16_t* Qb, bf16_t* Kb, bf16_t* Vb)
{
  const int nb = blockIdx.x;
  const int mb = blockIdx.y;
  const float* W; const float* bias; bf16_t* C; int ldc;
  if (nb < 16)      { W = Wq + (size_t)nb * 128 * HID;  bias = bq + nb * 128;
                      C = Qb + nb * 128; ldc = HID; }
  else if (nb < 20) { const int j = nb - 16;
                      W = Wk + (size_t)j * 128 * HID;   bias = bk + j * 128;
                      C = Kb + j * 128; ldc = KVW; }
  else              { const int j = nb - 20;
                      W = Wv + (size_t)j * 128 * HID;   bias = bv + j * 128;
                      C = Vb + j * 128; ldc = KVW; }
  gemm128_tile<float, bf16_t>(x + (size_t)mb * 128 * HID, HID, W, HID, bias,
                              C + (size_t)mb * 128 * ldc, ldc, HID);
}

__global__ __launch_bounds__(256) void oproj_kernel(
    const bf16_t* __restrict__ A, const float* __restrict__ Wo,
    const float* __restrict__ bo, float* out)
{
  const int nb = blockIdx.x, mb = blockIdx.y;
  gemm128_tile<bf16_t, float>(A + (size_t)mb * 128 * HID, HID,
                              Wo + (size_t)nb * 128 * HID, HID,
                              bo + nb * 128,
                              out + (size_t)mb * 128 * HID + nb * 128, HID, HID);
}

__global__ __launch_bounds__(256) void vtrans_kernel(
    const bf16_t* __restrict__ Vb, bf16_t* __restrict__ VbT)
{
  __shared__ bf16_t T[64][72];
  const int st = blockIdx.x, kvh = blockIdx.y, b = blockIdx.z;
  const int tid = threadIdx.x;
  {
    const int row = tid >> 2;
    const int c16 = (tid & 3) * 16;
    const bf16_t* src =
        Vb + ((size_t)b * SLEN + st * 64 + row) * KVW + kvh * HDIM + c16;
    *(bf16x8*)&T[row][c16]     = *(const bf16x8*)(src);
    *(bf16x8*)&T[row][c16 + 8] = *(const bf16x8*)(src + 8);
  }
  __syncthreads();
  {
    const int d  = tid >> 2;
    const int sc = (tid & 3) * 16;
    bf16_t tmp[16];
    for (int j = 0; j < 16; ++j) tmp[j] = T[sc + j][d];
    bf16_t* dst = VbT + ((size_t)(b * NKVH + kvh) * HDIM + d) * SLEN + st * 64 + sc;
    *(bf16x8*)dst       = *(bf16x8*)&tmp[0];
    *(bf16x8*)(dst + 8) = *(bf16x8*)&tmp[8];
  }
}

// ---------------- Flash attention: dbuf K/V + in-register P -----------------
__global__ __launch_bounds__(512, 4) void attn_kernel(
    const bf16_t* Q, const bf16_t* __restrict__ Kg,
    const bf16_t* __restrict__ VT, bf16_t* O)
{
  const int bid = blockIdx.x;            // 0..511
  const int kvh = bid & 7;               // one kvh per XCD
  const int jb  = bid >> 3;              // 0..63
  const int b   = jb >> 5;
  const int rem = jb & 31;
  const int h   = kvh * 4 + (rem & 3);
  const int pid = rem >> 2;              // 0..7

  const int tid  = threadIdx.x;
  const int lane = tid & 63;
  const int w    = tid >> 6;             // 0..7
  const int fr   = lane & 15;
  const int quad = lane >> 4;

  __shared__ __align__(16) bf16_t lds[32768];  // 2 x (KL 8192 + VtL 8192)

  const size_t qbase = (size_t)b * SLEN;
  const bf16_t* VTh = VT + (size_t)(b * NKVH + kvh) * HDIM * SLEN;

  const int sig = ((quad & 1) << 1) | ((quad >> 1) & 1);   // 0,2,1,3
  const int fsw = (fr >> 1) & 3;
  const bool oddq = (quad & 1);

  bf16x8 ones8;
  {
    const bf16_t o1 = (bf16_t)(fr == 0 ? 1.0f : 0.0f);
#pragma unroll
    for (int j2 = 0; j2 < 8; ++j2) ones8[j2] = o1;
  }

  auto STAGE_KV = [&](int kt, bf16_t* KL) {
    const size_t krow0 = qbase + (size_t)kt * 128;
    bf16_t* VtL = KL + 8192;
#pragma unroll
    for (int jj = 0; jj < 2; ++jj) {
      const int s  = jj * 512 + tid;
      const int ks = s >> 9, kr = (s >> 2) & 127, c8 = (s & 3) ^ ((kr >> 1) & 3);
      gl2lds16(&Kg[(krow0 + kr) * KVW + kvh * HDIM + ks * 32 + c8 * 8],
               &KL[s * 8]);
    }
#pragma unroll
    for (int jj = 0; jj < 2; ++jj) {
      const int idx = jj * 512 + tid;
      const int kb = idx >> 8, d = (idx >> 2) & 63, c8 = (idx & 3) ^ ((d >> 1) & 3);
      gl2lds16(&VTh[(size_t)d * SLEN + kt * 128 + kb * 32 + c8 * 8],
               &VtL[idx * 8]);
    }
  };

  for (int half = 0; half < 2; ++half) {
    const int qt = half ? (15 - pid) : pid;
    const int q0 = qt * 128;

    bf16x8 qf[2];
#pragma unroll
    for (int ks = 0; ks < 2; ++ks)
      qf[ks] = *(const bf16x8*)&Q[(qbase + q0 + w * 16 + fr) * HID
                                  + h * HDIM + ks * 32 + quad * 8];

    const f32x4 z4 = {0.f, 0.f, 0.f, 0.f};
    f32x4 o_acc[4];
    f32x4 o_l = z4;
#pragma unroll
    for (int di = 0; di < 4; ++di) o_acc[di] = z4;

    const int ktmax = qt;
    const int qloc  = w * 16 + fr;       // q local to the 128-row diag tile

    STAGE_KV(0, lds);
    asm volatile("s_waitcnt vmcnt(0)" ::: "memory");
    phase_barrier();

    int cur = 0;
    for (int kt = 0; kt <= ktmax; ++kt) {
      bf16_t* KL  = lds + cur * 16384;
      bf16_t* VtL = KL + 8192;
      if (kt < ktmax) STAGE_KV(kt + 1, lds + (cur ^ 1) * 16384);

      f32x4 s8[8];
#pragma unroll
      for (int ki = 0; ki < 8; ++ki) s8[ki] = z4;
      __builtin_amdgcn_s_setprio(1);
#pragma unroll
      for (int ks = 0; ks < 2; ++ks)
#pragma unroll
        for (int ki = 0; ki < 8; ++ki) {
          bf16x8 kf = *(const bf16x8*)&KL[ks * 4096 + (ki * 16 + fr) * 32
                                          + ((quad ^ fsw) << 3)];
          s8[ki] = mfma16(kf, qf[ks], s8[ki]);
        }
      __builtin_amdgcn_s_setprio(0);

      const float C2 = 0.18033688f;   // log2(e)/8
      const bool diag = (kt == ktmax);

#pragma unroll
      for (int m = 0; m < 4; ++m) {
        float pe[8];
#pragma unroll
        for (int ki2 = 0; ki2 < 2; ++ki2) {
          const int ki = 2 * m + ki2;
#pragma unroll
          for (int r = 0; r < 4; ++r) {
            float p = fast_exp2(s8[ki][r] * C2);
            if (diag && (ki * 16 + quad * 4 + r > qloc)) p = 0.f;
            pe[ki2 * 4 + r] = p;
          }
        }
        uint32_t pw0 = pack2(pe[0], pe[1]);
        uint32_t pw1 = pack2(pe[2], pe[3]);
        uint32_t pw2 = pack2(pe[4], pe[5]);
        uint32_t pw3 = pack2(pe[6], pe[7]);
        uint32_t x0 = oddq ? pw0 : pw2;
        uint32_t x1 = oddq ? pw1 : pw3;
        uint32_t r0 = (uint32_t)__shfl_xor((int)x0, 16);
        uint32_t r1 = (uint32_t)__shfl_xor((int)x1, 16);
        union { uint32_t u[4]; bf16x8 v; } pb;
        pb.u[0] = oddq ? r0 : pw0;
        pb.u[1] = oddq ? r1 : pw1;
        pb.u[2] = oddq ? pw2 : r0;
        pb.u[3] = oddq ? pw3 : r1;

        __builtin_amdgcn_s_setprio(1);
        o_l = mfma16(pb.v, ones8, o_l);
#pragma unroll
        for (int di = 0; di < 4; ++di) {
          bf16x8 vf = *(const bf16x8*)&VtL[m * 2048 + (di * 16 + fr) * 32
                                           + ((sig ^ fsw) << 3)];
          o_acc[di] = mfma16(pb.v, vf, o_acc[di]);
        }
        __builtin_amdgcn_s_setprio(0);
      }

      asm volatile("s_waitcnt vmcnt(0)" ::: "memory");
      phase_barrier();
      cur ^= 1;
    }

    bf16_t* OB = lds;   // 128 x 64 bf16 = 16KB
#pragma unroll
    for (int r = 0; r < 4; ++r) {
      const float l  = __shfl(o_l[r], lane & 48);
      const float rl = 1.f / l;
      const int q = w * 16 + quad * 4 + r;
#pragma unroll
      for (int di = 0; di < 4; ++di)
        OB[q * 64 + di * 16 + fr] = (bf16_t)(o_acc[di][r] * rl);
    }
    asm volatile("s_waitcnt lgkmcnt(0)" ::: "memory");
    phase_barrier();
    {
      const int row = tid >> 2;          // 0..127
      const int seg = tid & 3;           // 0..3 (16 bf16 each)
      bf16x8 v0 = *(const bf16x8*)&OB[row * 64 + seg * 16];
      bf16x8 v1 = *(const bf16x8*)&OB[row * 64 + seg * 16 + 8];
      bf16_t* dst = &O[(qbase + q0 + row) * HID + h * HDIM + seg * 16];
      *(bf16x8*)dst       = v0;
      *(bf16x8*)(dst + 8) = v1;
    }
    phase_barrier();   // protect OB before next half's staging
  }
}

extern "C" void kernel_launch(void* const* d_in, const int* in_sizes, int n_in,
                              void* d_out, int out_size, void* d_ws, size_t ws_size,
                              hipStream_t stream) {
  const float* x  = (const float*)d_in[0];
  // d_in[1] = causal mask (int32) -- recomputed inline, not read
  const float* Wq = (const float*)d_in[2];
  const float* bq = (const float*)d_in[3];
  const float* Wk = (const float*)d_in[4];
  const float* bk = (const float*)d_in[5];
  const float* Wv = (const float*)d_in[6];
  const float* bv = (const float*)d_in[7];
  const float* Wo = (const float*)d_in[8];
  const float* bo = (const float*)d_in[9];
  float* out = (float*)d_out;

  const size_t M = (size_t)NB * SLEN;          // 4096
  dim3 blk(256, 1, 1);

  const size_t needA = (M * HID
                        + (size_t)HID * HID
                        + (size_t)KVW * HID
                        + (size_t)KVW * HID
                        + (size_t)HID * HID
                        + M * HID
                        + M * KVW
                        + M * KVW) * 2
                       + (size_t)(HID + 2 * KVW) * sizeof(float);
  if (ws_size >= needA) {
    bf16_t* xb  = (bf16_t*)d_ws;
    bf16_t* Wqb = xb  + M * HID;              // Wq|Wk|Wv contiguous = Wcat
    bf16_t* Wkb = Wqb + (size_t)HID * HID;
    bf16_t* Wvb = Wkb + (size_t)KVW * HID;
    bf16_t* Wob = Wvb + (size_t)KVW * HID;
    bf16_t* Qb  = Wob + (size_t)HID * HID;
    bf16_t* Kb  = Qb  + M * HID;
    bf16_t* VbT = Kb  + M * KVW;
    float*  bcat = (float*)(VbT + M * KVW);   // [bq|bk|bv], 3072 floats

    cvt_kernel<<<dim3(1024, 8, 1), blk, 0, stream>>>(
        x, Wq, Wk, Wv, Wo, bq, bk, bv, xb, Wqb, Wkb, Wvb, Wob, bcat);
    qkv8_kernel<<<dim3(256, 1, 1), dim3(512, 1, 1), 0, stream>>>(
        xb, Wqb, bcat, Qb, Kb, VbT);
    attn_kernel<<<dim3(512, 1, 1), dim3(512, 1, 1), 0, stream>>>(Qb, Kb, VbT, Qb);
    oproj8_kernel<<<dim3(256, 1, 1), dim3(512, 1, 1), 0, stream>>>(
        Qb, Wob, bo, out);
  } else {
    bf16_t* Qb  = (bf16_t*)d_ws;
    bf16_t* Kb  = Qb + M * HID;
    bf16_t* Vb  = Kb + M * KVW;
    bf16_t* VbT = Vb + M * KVW;

    qkv_kernel<<<dim3(24, 32, 1), blk, 0, stream>>>(x, Wq, bq, Wk, bk, Wv, bv, Qb, Kb, Vb);
    vtrans_kernel<<<dim3(32, 8, 2), blk, 0, stream>>>(Vb, VbT);
    attn_kernel<<<dim3(512, 1, 1), dim3(512, 1, 1), 0, stream>>>(Qb, Kb, VbT, Qb);
    oproj_kernel<<<dim3(16, 32, 1), blk, 0, stream>>>(Qb, Wo, bo, out);
  }
}

// Round 6
// 273.584 us; speedup vs baseline: 1.1718x; 1.0445x over previous
//
#include <hip/hip_runtime.h>
#include <hip/hip_bf16.h>
#include <stdint.h>

#define HID   2048
#define SLEN  2048
#define NB    2
#define NHEADS 32
#define NKVH   8
#define HDIM   64
#define KVW    512   // NKVH*HDIM

typedef __bf16 bf16_t;
typedef __bf16 bf16x2 __attribute__((ext_vector_type(2)));
typedef __bf16 bf16x4 __attribute__((ext_vector_type(4)));
typedef __bf16 bf16x8 __attribute__((ext_vector_type(8)));
typedef float  f32x4  __attribute__((ext_vector_type(4)));

__device__ __forceinline__ f32x4 mfma16(bf16x8 a, bf16x8 b, f32x4 c) {
  return __builtin_amdgcn_mfma_f32_16x16x32_bf16(a, b, c, 0, 0, 0);
}

__device__ __forceinline__ void gl2lds16(const bf16_t* g, bf16_t* l) {
  __builtin_amdgcn_global_load_lds(
      (const __attribute__((address_space(1))) void*)g,
      (__attribute__((address_space(3))) void*)l,
      16, 0, 0);
}

__device__ __forceinline__ float fast_exp2(float x) {
#if __has_builtin(__builtin_amdgcn_exp2f)
  return __builtin_amdgcn_exp2f(x);
#else
  return __expf(x * 0.69314718f);
#endif
}

__device__ __forceinline__ bf16x8 ld8(const bf16_t* p) {
  return *(const bf16x8*)p;
}
__device__ __forceinline__ bf16x8 ld8(const float* p) {
  f32x4 a = *(const f32x4*)p;
  f32x4 b = *(const f32x4*)(p + 4);
  bf16x8 r;
  r[0] = (bf16_t)a[0]; r[1] = (bf16_t)a[1]; r[2] = (bf16_t)a[2]; r[3] = (bf16_t)a[3];
  r[4] = (bf16_t)b[0]; r[5] = (bf16_t)b[1]; r[6] = (bf16_t)b[2]; r[7] = (bf16_t)b[3];
  return r;
}

__device__ __forceinline__ uint32_t pack2(float a, float b) {
  bf16x2 t; t[0] = (bf16_t)a; t[1] = (bf16_t)b;
  return __builtin_bit_cast(uint32_t, t);
}

__device__ __forceinline__ void st_c(bf16_t* p, float v) { *p = (bf16_t)v; }
__device__ __forceinline__ void st_c(float*  p, float v) { *p = v; }

// ---------------- fp32 -> bf16 convert pass + bias concat -------------------
__global__ __launch_bounds__(256) void cvt_kernel(
    const float* __restrict__ x,  const float* __restrict__ wq,
    const float* __restrict__ wk, const float* __restrict__ wv,
    const float* __restrict__ wo,
    const float* __restrict__ bq, const float* __restrict__ bk,
    const float* __restrict__ bv,
    bf16_t* xb, bf16_t* wqb, bf16_t* wkb, bf16_t* wvb, bf16_t* wob,
    float* bcat)
{
  if (blockIdx.y >= 5) {   // float->float bias concat
    const float* fs; float* fd; size_t n;
    if (blockIdx.y == 5)      { fs = bq; fd = bcat;        n = HID; }
    else if (blockIdx.y == 6) { fs = bk; fd = bcat + HID;  n = KVW; }
    else                      { fs = bv; fd = bcat + HID + KVW; n = KVW; }
    const size_t stride4 = (size_t)gridDim.x * 256 * 4;
    for (size_t i = ((size_t)blockIdx.x * 256 + threadIdx.x) * 4; i < n; i += stride4)
      *(f32x4*)(fd + i) = *(const f32x4*)(fs + i);
    return;
  }
  const float* s; bf16_t* d; size_t n;
  switch (blockIdx.y) {
    case 0:  s = x;  d = xb;  n = (size_t)NB * SLEN * HID; break;
    case 1:  s = wq; d = wqb; n = (size_t)HID * HID; break;
    case 2:  s = wk; d = wkb; n = (size_t)KVW * HID; break;
    case 3:  s = wv; d = wvb; n = (size_t)KVW * HID; break;
    default: s = wo; d = wob; n = (size_t)HID * HID; break;
  }
  const size_t stride = (size_t)gridDim.x * 256 * 8;
  for (size_t i = ((size_t)blockIdx.x * 256 + threadIdx.x) * 8; i < n; i += stride)
    *(bf16x8*)(d + i) = ld8(s + i);
}

// =============== 256xBN fat-phase GEMM template (T1+T2+T4+T5) ===============
// BM=256 rows, BK=64, BN = U*64. 512 threads = 8 waves (2M x 4N); per-wave
// C = 128 x (U*16). LDS = 2 x (A 32KB + B U*8KB). 4 FAT phases per 2-K-tile
// iteration: each phase = half the M-tile (2 quadrants, 8 ds_read_b128 +
// 2*8U MFMAs) -> 2 barriers per 16U MFMAs (half the barrier overhead of the
// 8-phase form; R5 counters showed phase overhead, not pipes, was the limit).
// Staging: p0 A(t+1)x4, p1 B(t+2)xU, p2 A(t+2)x4, p3 B(t+3)xU; vmcnt(U) at
// p1/p3 ends drains exactly what the next two phases consume (in-order).
__device__ __forceinline__ bf16x8 ldfrag(const bf16_t* __restrict__ Lh, int r, int g) {
  return *(const bf16x8*)(Lh + r * 64 + ((g ^ (r & 7)) << 3));
}

template <int N>
__device__ __forceinline__ void vm_wait() {
  if constexpr (N == 0)      asm volatile("s_waitcnt vmcnt(0)" ::: "memory");
  else if constexpr (N == 2) asm volatile("s_waitcnt vmcnt(2)" ::: "memory");
  else if constexpr (N == 3) asm volatile("s_waitcnt vmcnt(3)" ::: "memory");
  else                       asm volatile("s_waitcnt vmcnt(4)" ::: "memory");
}

template <int H, int U>
__device__ __forceinline__ void mfma_halfU(const bf16x8 (&af2)[2][2][2],
                                           const bf16x8 (&bfr)[U][2],
                                           f32x4 (&acc)[8][U]) {
#pragma unroll
  for (int q = 0; q < 2; ++q)
#pragma unroll
    for (int ks = 0; ks < 2; ++ks)
#pragma unroll
      for (int i = 0; i < 2; ++i)
#pragma unroll
        for (int ni = 0; ni < U; ++ni)
          acc[4 * H + 2 * q + i][ni] =
              mfma16(af2[q][i][ks], bfr[ni][ks], acc[4 * H + 2 * q + i][ni]);
}

__device__ __forceinline__ void phase_barrier() {
  __builtin_amdgcn_s_barrier();
  asm volatile("" ::: "memory");
}

template <int U>
__device__ __forceinline__ void gemm_core_u(
    const bf16_t* __restrict__ Ag,
    const bf16_t* __restrict__ Bg,
    bf16_t* __restrict__ lds, f32x4 (&acc)[8][U])
{
  const int tid  = threadIdx.x;
  const int lane = tid & 63;
  const int w    = tid >> 6;
  const int fr   = lane & 15;
  const int quad = lane >> 4;
  const int wr   = w >> 2;
  const int wc   = w & 3;

  bf16_t* A0 = lds;
  bf16_t* B0 = lds + 16384;
  bf16_t* A1 = B0 + U * 4096;
  bf16_t* B1 = A1 + 16384;

  const f32x4 z4 = {0.f, 0.f, 0.f, 0.f};
#pragma unroll
  for (int i = 0; i < 8; ++i)
#pragma unroll
    for (int j = 0; j < U; ++j) acc[i][j] = z4;

  auto STAGEU = [&](const bf16_t* __restrict__ Gp, bf16_t* __restrict__ Lb, int u) {
    const int r = tid >> 3;
    const int g = (tid & 7) ^ (r & 7);
    gl2lds16(Gp + (size_t)(u * 64 + r) * HID + g * 8, Lb + u * 4096 + tid * 8);
  };
  auto LDB = [&](const bf16_t* __restrict__ Bb, bf16x8 (&bfr)[U][2]) {
#pragma unroll
    for (int ni = 0; ni < U; ++ni)
#pragma unroll
      for (int ks = 0; ks < 2; ++ks)
        bfr[ni][ks] = ldfrag(Bb, wc * (16 * U) + ni * 16 + fr, ks * 4 + quad);
  };
  auto LDAH = [&](const bf16_t* __restrict__ Ab, int h, bf16x8 (&af2)[2][2][2]) {
#pragma unroll
    for (int q = 0; q < 2; ++q)
#pragma unroll
      for (int i = 0; i < 2; ++i)
#pragma unroll
        for (int ks = 0; ks < 2; ++ks)
          af2[q][i][ks] =
              ldfrag(Ab, wr * 128 + h * 64 + q * 32 + i * 16 + fr, ks * 4 + quad);
  };

  // prologue: B(0), A(0), B(1)
#pragma unroll
  for (int u = 0; u < U; ++u) STAGEU(Bg, B0, u);
#pragma unroll
  for (int u = 0; u < 4; ++u) STAGEU(Ag, A0, u);
#pragma unroll
  for (int u = 0; u < U; ++u) STAGEU(Bg + 64, B1, u);
  vm_wait<U>();
  phase_barrier();

  bf16x8 bfr[U][2], af2[2][2][2];

#pragma unroll 1
  for (int it = 0; it < 16; ++it) {
    const bool more = (it < 15);
    const size_t k1 = (size_t)(2 * it + 1) * 64;
    const size_t k2 = (size_t)(2 * it + 2) * 64;
    const size_t k3 = (size_t)(2 * it + 3) * 64;

    // ---- p0: tile t (buf0), M-half 0; stage A(t+1) x4 -> A1
    LDB(B0, bfr);
    LDAH(A0, 0, af2);
#pragma unroll
    for (int u = 0; u < 4; ++u) STAGEU(Ag + k1, A1, u);
    phase_barrier();
    asm volatile("s_waitcnt lgkmcnt(0)" ::: "memory");
    __builtin_amdgcn_s_setprio(1);
    mfma_halfU<0>(af2, bfr, acc);
    __builtin_amdgcn_s_setprio(0);
    phase_barrier();

    // ---- p1: M-half 1; stage B(t+2) xU -> B0; drain A(t+1)+B(t+1)
    LDAH(A0, 1, af2);
    if (more) {
#pragma unroll
      for (int u = 0; u < U; ++u) STAGEU(Bg + k2, B0, u);
    }
    phase_barrier();
    asm volatile("s_waitcnt lgkmcnt(0)" ::: "memory");
    __builtin_amdgcn_s_setprio(1);
    mfma_halfU<1>(af2, bfr, acc);
    __builtin_amdgcn_s_setprio(0);
    if (more) vm_wait<U>(); else vm_wait<0>();
    phase_barrier();

    // ---- p2: tile t+1 (buf1), M-half 0; stage A(t+2) x4 -> A0
    LDB(B1, bfr);
    LDAH(A1, 0, af2);
    if (more) {
#pragma unroll
      for (int u = 0; u < 4; ++u) STAGEU(Ag + k2, A0, u);
    }
    phase_barrier();
    asm volatile("s_waitcnt lgkmcnt(0)" ::: "memory");
    __builtin_amdgcn_s_setprio(1);
    mfma_halfU<0>(af2, bfr, acc);
    __builtin_amdgcn_s_setprio(0);
    phase_barrier();

    // ---- p3: M-half 1; stage B(t+3) xU -> B1; drain A(t+2)+B(t+2)
    LDAH(A1, 1, af2);
    if (more) {
#pragma unroll
      for (int u = 0; u < U; ++u) STAGEU(Bg + k3, B1, u);
    }
    phase_barrier();
    asm volatile("s_waitcnt lgkmcnt(0)" ::: "memory");
    __builtin_amdgcn_s_setprio(1);
    mfma_halfU<1>(af2, bfr, acc);
    __builtin_amdgcn_s_setprio(0);
    if (more) vm_wait<U>();
    phase_barrier();
  }
}

// Region-chunked XCD swizzle for a 16x16 (cb x mb) grid: each XCD owns an
// 8cb x 4mb region (32 lockstep blocks, ~320KB/K-step working set -> L2).
__device__ __forceinline__ void grid_map16(int orig, int& cb, int& mb) {
  const int xcd = orig & 7, wp = orig >> 3;
  cb = (xcd & 1) * 8 + (wp & 7);
  mb = (xcd >> 1) * 4 + (wp >> 3);
}

// Epilogue bounce-buffer index with XOR-octet swizzle: 16B group g of row r
// stored at octet-local g ^ ((r>>3)&7). Keeps 16B chunks contiguous (Q/K
// vector reads) while spreading the V transposed reads (8 lanes, row stride
// 8) across 8 distinct bank-groups.
__device__ __forceinline__ int cswz(int row, int col, int CP) {
  const int cg = col >> 3;
  const int g  = (cg & ~7) | ((cg ^ (row >> 3)) & 7);
  return row * CP + (g << 3) + (col & 7);
}

// QKV: BN=192 (U=3), grid 256 full-chip. Wcat = [Wq|Wk|Wv].
__global__ __launch_bounds__(512, 2) void qkv8_kernel(
    const bf16_t* __restrict__ xb, const bf16_t* __restrict__ Wcat,
    const float* __restrict__ bcat,
    bf16_t* __restrict__ Qb, bf16_t* __restrict__ Kb, bf16_t* __restrict__ VbT)
{
  __shared__ __align__(16) bf16_t lds[57344];   // 112 KB
  int cb, mb;
  grid_map16(blockIdx.x, cb, mb);

  f32x4 acc[8][3];
  gemm_core_u<3>(xb + (size_t)mb * 256 * HID, Wcat + (size_t)cb * 192 * HID,
                 lds, acc);

  const int tid = threadIdx.x, lane = tid & 63, w = tid >> 6;
  const int fr = lane & 15, quad = lane >> 4, wr = w >> 2, wc = w & 3;
  const int CP = 200;
  bf16_t* C = lds;
#pragma unroll
  for (int ni = 0; ni < 3; ++ni) {
    const int col = wc * 48 + ni * 16 + fr;
    const float bz = bcat[cb * 192 + col];
#pragma unroll
    for (int mi = 0; mi < 8; ++mi)
#pragma unroll
      for (int r = 0; r < 4; ++r)
        C[cswz(wr * 128 + mi * 16 + quad * 4 + r, col, CP)] =
            (bf16_t)(acc[mi][ni][r] + bz);
  }
  asm volatile("s_waitcnt lgkmcnt(0)" ::: "memory");
  phase_barrier();

  // Q/K copy-out: 256 rows x 24 col-groups of 8 (16B chunks)
#pragma unroll
  for (int i = 0; i < 12; ++i) {
    const unsigned task = (unsigned)(i * 512 + tid);
    const unsigned row = task / 24u;
    const unsigned cg  = task - row * 24u;
    const int gcol0 = cb * 192 + (int)cg * 8;
    const int grow  = mb * 256 + (int)row;
    const int g = ((int)cg & ~7) | (((int)cg ^ ((int)row >> 3)) & 7);
    bf16x8 v = *(const bf16x8*)&C[(int)row * CP + (g << 3)];
    if (gcol0 < 2048)
      *(bf16x8*)&Qb[(size_t)grow * HID + gcol0] = v;
    else if (gcol0 < 2560)
      *(bf16x8*)&Kb[(size_t)grow * KVW + (gcol0 - 2048)] = v;
    // V chunks handled transposed below
  }
  // V copy-out (transposed): cb >= 13 carries V columns
  if (cb >= 13) {
    const int colbase = (cb == 13) ? 64 : 0;
    const int Nv = 192 - colbase;
    const int b = mb >> 3;
    const int s0 = (mb & 7) * 256;
#pragma unroll
    for (int i = 0; i < 12; ++i) {
      const int task = i * 512 + tid;
      const int vi = task >> 5, si = task & 31;
      if (vi < Nv) {
        const int col = colbase + vi;
        const int vc  = cb * 192 + col - 2560;       // 0..511
        bf16x8 pk;
#pragma unroll
        for (int j = 0; j < 8; ++j) pk[j] = C[cswz(si * 8 + j, col, CP)];
        *(bf16x8*)&VbT[((size_t)(b * NKVH + (vc >> 6)) * HDIM + (vc & 63)) * SLEN
                       + s0 + si * 8] = pk;
      }
    }
  }
}

// O-proj: BN=128 (U=2), grid 256 full-chip, f32 out.
__global__ __launch_bounds__(512, 2) void oproj8_kernel(
    const bf16_t* __restrict__ A, const bf16_t* __restrict__ Wob,
    const float* __restrict__ bo, float* __restrict__ out)
{
  __shared__ __align__(16) bf16_t lds[49152];   // 96 KB
  int cb, mb;
  grid_map16(blockIdx.x, cb, mb);

  f32x4 acc[8][2];
  gemm_core_u<2>(A + (size_t)mb * 256 * HID, Wob + (size_t)cb * 128 * HID,
                 lds, acc);

  const int tid = threadIdx.x, lane = tid & 63, w = tid >> 6;
  const int fr = lane & 15, quad = lane >> 4, wr = w >> 2, wc = w & 3;
  const int CPF = 132;
  float* Cf = (float*)lds;
#pragma unroll
  for (int s = 0; s < 2; ++s) {
    if (wr == s) {
#pragma unroll
      for (int ni = 0; ni < 2; ++ni) {
        const int col = wc * 32 + ni * 16 + fr;
        const float bz = bo[cb * 128 + col];
#pragma unroll
        for (int mi = 0; mi < 8; ++mi)
#pragma unroll
          for (int r = 0; r < 4; ++r)
            Cf[(mi * 16 + quad * 4 + r) * CPF + col] = acc[mi][ni][r] + bz;
      }
    }
    asm volatile("s_waitcnt lgkmcnt(0)" ::: "memory");
    phase_barrier();
#pragma unroll
    for (int i = 0; i < 8; ++i) {
      const int task = i * 512 + tid;
      const int row = task >> 5, cg = task & 31;
      f32x4 v = *(const f32x4*)&Cf[row * CPF + cg * 4];
      *(f32x4*)&out[(size_t)(mb * 256 + s * 128 + row) * HID + cb * 128 + cg * 4] = v;
    }
    phase_barrier();
  }
}

// ---------------- Path B (fallback): fp32-source GEMM -----------------------
template <typename AT, typename CT>
__device__ __forceinline__ void gemm128_tile(
    const AT* __restrict__ Ap, int lda,
    const float* __restrict__ Wp, int ldw,
    const float* __restrict__ biasp,
    CT* __restrict__ Cp, int ldc,
    int K)
{
  __shared__ __align__(16) bf16_t Al[128 * 32];
  __shared__ __align__(16) bf16_t Bl[128 * 32];

  const int tid  = threadIdx.x;
  const int lane = tid & 63;
  const int w    = tid >> 6;
  const int fr   = lane & 15;
  const int quad = lane >> 4;
  const int wm   = (w >> 1) * 64;
  const int wn   = (w & 1) * 64;

  const f32x4 z4 = {0.f, 0.f, 0.f, 0.f};
  f32x4 acc[4][4];
  for (int i = 0; i < 4; ++i)
    for (int j = 0; j < 4; ++j) acc[i][j] = z4;

  const int c0    = w * 2;
  const int srow0 = lane >> 2;
  const int skc   = (lane & 3) * 8;

  for (int k0 = 0; k0 < K; k0 += 32) {
    bf16x8 av[2], bv[2];
    for (int t = 0; t < 2; ++t) {
      const int r = (c0 + t) * 16 + srow0;
      av[t] = ld8(Ap + (size_t)r * lda + k0 + skc);
      bv[t] = ld8(Wp + (size_t)r * ldw + k0 + skc);
    }
    for (int t = 0; t < 2; ++t) {
      const int c = c0 + t;
      *(bf16x8*)&Al[c * 512 + lane * 8] = av[t];
      *(bf16x8*)&Bl[c * 512 + lane * 8] = bv[t];
    }
    __syncthreads();
    bf16x8 af[4], bfr[4];
    for (int mi = 0; mi < 4; ++mi)
      af[mi] = *(const bf16x8*)&Al[(wm + mi * 16 + fr) * 32 + quad * 8];
    for (int ni = 0; ni < 4; ++ni)
      bfr[ni] = *(const bf16x8*)&Bl[(wn + ni * 16 + fr) * 32 + quad * 8];
    for (int mi = 0; mi < 4; ++mi)
      for (int ni = 0; ni < 4; ++ni)
        acc[mi][ni] = mfma16(af[mi], bfr[ni], acc[mi][ni]);
    __syncthreads();
  }

  for (int ni = 0; ni < 4; ++ni) {
    const int col = wn + ni * 16 + fr;
    const float bz = biasp[col];
    for (int mi = 0; mi < 4; ++mi) {
      const int r0 = wm + mi * 16 + quad * 4;
      for (int r = 0; r < 4; ++r)
        st_c(Cp + (size_t)(r0 + r) * ldc + col, acc[mi][ni][r] + bz);
    }
  }
}

__global__ __launch_bounds__(256) void qkv_kernel(
    const float* __restrict__ x,
    const float* __restrict__ Wq, const float* __restrict__ bq,
    const float* __restrict__ Wk, const float* __restrict__ bk,
    const float* __restrict__ Wv, const float* __restrict__ bv,
    bf16_t* Qb, bf16_t* Kb, bf16_t* Vb)
{
  const int nb = blockIdx.x;
  const int mb = blockIdx.y;
  const float* W; const float* bias; bf16_t* C; int ldc;
  if (nb < 16)      { W = Wq + (size_t)nb * 128 * HID;  bias = bq + nb * 128;
                      C = Qb + nb * 128; ldc = HID; }
  else if (nb < 20) { const int j = nb - 16;
                      W = Wk + (size_t)j * 128 * HID;   bias = bk + j * 128;
                      C = Kb + j * 128; ldc = KVW; }
  else              { const int j = nb - 20;
                      W = Wv + (size_t)j * 128 * HID;   bias = bv + j * 128;
                      C = Vb + j * 128; ldc = KVW; }
  gemm128_tile<float, bf16_t>(x + (size_t)mb * 128 * HID, HID, W, HID, bias,
                              C + (size_t)mb * 128 * ldc, ldc, HID);
}

__global__ __launch_bounds__(256) void oproj_kernel(
    const bf16_t* __restrict__ A, const float* __restrict__ Wo,
    const float* __restrict__ bo, float* out)
{
  const int nb = blockIdx.x, mb = blockIdx.y;
  gemm128_tile<bf16_t, float>(A + (size_t)mb * 128 * HID, HID,
                              Wo + (size_t)nb * 128 * HID, HID,
                              bo + nb * 128,
                              out + (size_t)mb * 128 * HID + nb * 128, HID, HID);
}

__global__ __launch_bounds__(256) void vtrans_kernel(
    const bf16_t* __restrict__ Vb, bf16_t* __restrict__ VbT)
{
  __shared__ bf16_t T[64][72];
  const int st = blockIdx.x, kvh = blockIdx.y, b = blockIdx.z;
  const int tid = threadIdx.x;
  {
    const int row = tid >> 2;
    const int c16 = (tid & 3) * 16;
    const bf16_t* src =
        Vb + ((size_t)b * SLEN + st * 64 + row) * KVW + kvh * HDIM + c16;
    *(bf16x8*)&T[row][c16]     = *(const bf16x8*)(src);
    *(bf16x8*)&T[row][c16 + 8] = *(const bf16x8*)(src + 8);
  }
  __syncthreads();
  {
    const int d  = tid >> 2;
    const int sc = (tid & 3) * 16;
    bf16_t tmp[16];
    for (int j = 0; j < 16; ++j) tmp[j] = T[sc + j][d];
    bf16_t* dst = VbT + ((size_t)(b * NKVH + kvh) * HDIM + d) * SLEN + st * 64 + sc;
    *(bf16x8*)dst       = *(bf16x8*)&tmp[0];
    *(bf16x8*)(dst + 8) = *(bf16x8*)&tmp[8];
  }
}

// ---------------- Flash attention: dbuf K/V + in-register P -----------------
__global__ __launch_bounds__(512, 4) void attn_kernel(
    const bf16_t* Q, const bf16_t* __restrict__ Kg,
    const bf16_t* __restrict__ VT, bf16_t* O)
{
  const int bid = blockIdx.x;            // 0..511
  const int kvh = bid & 7;               // one kvh per XCD
  const int jb  = bid >> 3;              // 0..63
  const int b   = jb >> 5;
  const int rem = jb & 31;
  const int h   = kvh * 4 + (rem & 3);
  const int pid = rem >> 2;              // 0..7

  const int tid  = threadIdx.x;
  const int lane = tid & 63;
  const int w    = tid >> 6;             // 0..7
  const int fr   = lane & 15;
  const int quad = lane >> 4;

  __shared__ __align__(16) bf16_t lds[32768];  // 2 x (KL 8192 + VtL 8192)

  const size_t qbase = (size_t)b * SLEN;
  const bf16_t* VTh = VT + (size_t)(b * NKVH + kvh) * HDIM * SLEN;

  const int sig = ((quad & 1) << 1) | ((quad >> 1) & 1);   // 0,2,1,3
  const int fsw = (fr >> 1) & 3;
  const bool oddq = (quad & 1);

  bf16x8 ones8;
  {
    const bf16_t o1 = (bf16_t)(fr == 0 ? 1.0f : 0.0f);
#pragma unroll
    for (int j2 = 0; j2 < 8; ++j2) ones8[j2] = o1;
  }

  auto STAGE_KV = [&](int kt, bf16_t* KL) {
    const size_t krow0 = qbase + (size_t)kt * 128;
    bf16_t* VtL = KL + 8192;
#pragma unroll
    for (int jj = 0; jj < 2; ++jj) {
      const int s  = jj * 512 + tid;
      const int ks = s >> 9, kr = (s >> 2) & 127, c8 = (s & 3) ^ ((kr >> 1) & 3);
      gl2lds16(&Kg[(krow0 + kr) * KVW + kvh * HDIM + ks * 32 + c8 * 8],
               &KL[s * 8]);
    }
#pragma unroll
    for (int jj = 0; jj < 2; ++jj) {
      const int idx = jj * 512 + tid;
      const int kb = idx >> 8, d = (idx >> 2) & 63, c8 = (idx & 3) ^ ((d >> 1) & 3);
      gl2lds16(&VTh[(size_t)d * SLEN + kt * 128 + kb * 32 + c8 * 8],
               &VtL[idx * 8]);
    }
  };

  for (int half = 0; half < 2; ++half) {
    const int qt = half ? (15 - pid) : pid;
    const int q0 = qt * 128;

    bf16x8 qf[2];
#pragma unroll
    for (int ks = 0; ks < 2; ++ks)
      qf[ks] = *(const bf16x8*)&Q[(qbase + q0 + w * 16 + fr) * HID
                                  + h * HDIM + ks * 32 + quad * 8];

    const f32x4 z4 = {0.f, 0.f, 0.f, 0.f};
    f32x4 o_acc[4];
    f32x4 o_l = z4;
#pragma unroll
    for (int di = 0; di < 4; ++di) o_acc[di] = z4;

    const int ktmax = qt;
    const int qloc  = w * 16 + fr;       // q local to the 128-row diag tile

    STAGE_KV(0, lds);
    asm volatile("s_waitcnt vmcnt(0)" ::: "memory");
    phase_barrier();

    int cur = 0;
    for (int kt = 0; kt <= ktmax; ++kt) {
      bf16_t* KL  = lds + cur * 16384;
      bf16_t* VtL = KL + 8192;
      if (kt < ktmax) STAGE_KV(kt + 1, lds + (cur ^ 1) * 16384);

      f32x4 s8[8];
#pragma unroll
      for (int ki = 0; ki < 8; ++ki) s8[ki] = z4;
      __builtin_amdgcn_s_setprio(1);
#pragma unroll
      for (int ks = 0; ks < 2; ++ks)
#pragma unroll
        for (int ki = 0; ki < 8; ++ki) {
          bf16x8 kf = *(const bf16x8*)&KL[ks * 4096 + (ki * 16 + fr) * 32
                                          + ((quad ^ fsw) << 3)];
          s8[ki] = mfma16(kf, qf[ks], s8[ki]);
        }
      __builtin_amdgcn_s_setprio(0);

      const float C2 = 0.18033688f;   // log2(e)/8
      const bool diag = (kt == ktmax);

#pragma unroll
      for (int m = 0; m < 4; ++m) {
        float pe[8];
#pragma unroll
        for (int ki2 = 0; ki2 < 2; ++ki2) {
          const int ki = 2 * m + ki2;
#pragma unroll
          for (int r = 0; r < 4; ++r) {
            float p = fast_exp2(s8[ki][r] * C2);
            if (diag && (ki * 16 + quad * 4 + r > qloc)) p = 0.f;
            pe[ki2 * 4 + r] = p;
          }
        }
        uint32_t pw0 = pack2(pe[0], pe[1]);
        uint32_t pw1 = pack2(pe[2], pe[3]);
        uint32_t pw2 = pack2(pe[4], pe[5]);
        uint32_t pw3 = pack2(pe[6], pe[7]);
        uint32_t x0 = oddq ? pw0 : pw2;
        uint32_t x1 = oddq ? pw1 : pw3;
        uint32_t r0 = (uint32_t)__shfl_xor((int)x0, 16);
        uint32_t r1 = (uint32_t)__shfl_xor((int)x1, 16);
        union { uint32_t u[4]; bf16x8 v; } pb;
        pb.u[0] = oddq ? r0 : pw0;
        pb.u[1] = oddq ? r1 : pw1;
        pb.u[2] = oddq ? pw2 : r0;
        pb.u[3] = oddq ? pw3 : r1;

        __builtin_amdgcn_s_setprio(1);
        o_l = mfma16(pb.v, ones8, o_l);
#pragma unroll
        for (int di = 0; di < 4; ++di) {
          bf16x8 vf = *(const bf16x8*)&VtL[m * 2048 + (di * 16 + fr) * 32
                                           + ((sig ^ fsw) << 3)];
          o_acc[di] = mfma16(pb.v, vf, o_acc[di]);
        }
        __builtin_amdgcn_s_setprio(0);
      }

      asm volatile("s_waitcnt vmcnt(0)" ::: "memory");
      phase_barrier();
      cur ^= 1;
    }

    bf16_t* OB = lds;   // 128 x 64 bf16 = 16KB
#pragma unroll
    for (int r = 0; r < 4; ++r) {
      const float l  = __shfl(o_l[r], lane & 48);
      const float rl = 1.f / l;
      const int q = w * 16 + quad * 4 + r;
#pragma unroll
      for (int di = 0; di < 4; ++di)
        OB[q * 64 + di * 16 + fr] = (bf16_t)(o_acc[di][r] * rl);
    }
    asm volatile("s_waitcnt lgkmcnt(0)" ::: "memory");
    phase_barrier();
    {
      const int row = tid >> 2;          // 0..127
      const int seg = tid & 3;           // 0..3 (16 bf16 each)
      bf16x8 v0 = *(const bf16x8*)&OB[row * 64 + seg * 16];
      bf16x8 v1 = *(const bf16x8*)&OB[row * 64 + seg * 16 + 8];
      bf16_t* dst = &O[(qbase + q0 + row) * HID + h * HDIM + seg * 16];
      *(bf16x8*)dst       = v0;
      *(bf16x8*)(dst + 8) = v1;
    }
    phase_barrier();   // protect OB before next half's staging
  }
}

extern "C" void kernel_launch(void* const* d_in, const int* in_sizes, int n_in,
                              void* d_out, int out_size, void* d_ws, size_t ws_size,
                              hipStream_t stream) {
  const float* x  = (const float*)d_in[0];
  // d_in[1] = causal mask (int32) -- recomputed inline, not read
  const float* Wq = (const float*)d_in[2];
  const float* bq = (const float*)d_in[3];
  const float* Wk = (const float*)d_in[4];
  const float* bk = (const float*)d_in[5];
  const float* Wv = (const float*)d_in[6];
  const float* bv = (const float*)d_in[7];
  const float* Wo = (const float*)d_in[8];
  const float* bo = (const float*)d_in[9];
  float* out = (float*)d_out;

  const size_t M = (size_t)NB * SLEN;          // 4096
  dim3 blk(256, 1, 1);

  const size_t needA = (M * HID
                        + (size_t)HID * HID
                        + (size_t)KVW * HID
                        + (size_t)KVW * HID
                        + (size_t)HID * HID
                        + M * HID
                        + M * KVW
                        + M * KVW) * 2
                       + (size_t)(HID + 2 * KVW) * sizeof(float);
  if (ws_size >= needA) {
    bf16_t* xb  = (bf16_t*)d_ws;
    bf16_t* Wqb = xb  + M * HID;              // Wq|Wk|Wv contiguous = Wcat
    bf16_t* Wkb = Wqb + (size_t)HID * HID;
    bf16_t* Wvb = Wkb + (size_t)KVW * HID;
    bf16_t* Wob = Wvb + (size_t)KVW * HID;
    bf16_t* Qb  = Wob + (size_t)HID * HID;
    bf16_t* Kb  = Qb  + M * HID;
    bf16_t* VbT = Kb  + M * KVW;
    float*  bcat = (float*)(VbT + M * KVW);   // [bq|bk|bv], 3072 floats

    cvt_kernel<<<dim3(1024, 8, 1), blk, 0, stream>>>(
        x, Wq, Wk, Wv, Wo, bq, bk, bv, xb, Wqb, Wkb, Wvb, Wob, bcat);
    qkv8_kernel<<<dim3(256, 1, 1), dim3(512, 1, 1), 0, stream>>>(
        xb, Wqb, bcat, Qb, Kb, VbT);
    attn_kernel<<<dim3(512, 1, 1), dim3(512, 1, 1), 0, stream>>>(Qb, Kb, VbT, Qb);
    oproj8_kernel<<<dim3(256, 1, 1), dim3(512, 1, 1), 0, stream>>>(
        Qb, Wob, bo, out);
  } else {
    bf16_t* Qb  = (bf16_t*)d_ws;
    bf16_t* Kb  = Qb + M * HID;
    bf16_t* Vb  = Kb + M * KVW;
    bf16_t* VbT = Vb + M * KVW;

    qkv_kernel<<<dim3(24, 32, 1), blk, 0, stream>>>(x, Wq, bq, Wk, bk, Wv, bv, Qb, Kb, Vb);
    vtrans_kernel<<<dim3(32, 8, 2), blk, 0, stream>>>(Vb, VbT);
    attn_kernel<<<dim3(512, 1, 1), dim3(512, 1, 1), 0, stream>>>(Qb, Kb, VbT, Qb);
    oproj_kernel<<<dim3(16, 32, 1), blk, 0, stream>>>(Qb, Wo, bo, out);
  }
}

// Round 7
// 269.281 us; speedup vs baseline: 1.1905x; 1.0160x over previous
//
#include <hip/hip_runtime.h>
#include <hip/hip_bf16.h>
#include <stdint.h>

#define HID   2048
#define SLEN  2048
#define NB    2
#define NHEADS 32
#define NKVH   8
#define HDIM   64
#define KVW    512   // NKVH*HDIM
#define QSCALE 0.18033688f   // log2(e)/8, folded into Wq/bq at cvt time

typedef __bf16 bf16_t;
typedef __bf16 bf16x2 __attribute__((ext_vector_type(2)));
typedef __bf16 bf16x4 __attribute__((ext_vector_type(4)));
typedef __bf16 bf16x8 __attribute__((ext_vector_type(8)));
typedef float  f32x4  __attribute__((ext_vector_type(4)));

__device__ __forceinline__ f32x4 mfma16(bf16x8 a, bf16x8 b, f32x4 c) {
  return __builtin_amdgcn_mfma_f32_16x16x32_bf16(a, b, c, 0, 0, 0);
}

__device__ __forceinline__ void gl2lds16(const bf16_t* g, bf16_t* l) {
  __builtin_amdgcn_global_load_lds(
      (const __attribute__((address_space(1))) void*)g,
      (__attribute__((address_space(3))) void*)l,
      16, 0, 0);
}

__device__ __forceinline__ float fast_exp2(float x) {
#if __has_builtin(__builtin_amdgcn_exp2f)
  return __builtin_amdgcn_exp2f(x);
#else
  return __expf(x * 0.69314718f);
#endif
}

__device__ __forceinline__ bf16x8 ld8(const bf16_t* p) {
  return *(const bf16x8*)p;
}
__device__ __forceinline__ bf16x8 ld8(const float* p) {
  f32x4 a = *(const f32x4*)p;
  f32x4 b = *(const f32x4*)(p + 4);
  bf16x8 r;
  r[0] = (bf16_t)a[0]; r[1] = (bf16_t)a[1]; r[2] = (bf16_t)a[2]; r[3] = (bf16_t)a[3];
  r[4] = (bf16_t)b[0]; r[5] = (bf16_t)b[1]; r[6] = (bf16_t)b[2]; r[7] = (bf16_t)b[3];
  return r;
}
__device__ __forceinline__ bf16x8 ld8s(const float* p, float s) {
  f32x4 a = *(const f32x4*)p;
  f32x4 b = *(const f32x4*)(p + 4);
  bf16x8 r;
  r[0] = (bf16_t)(a[0]*s); r[1] = (bf16_t)(a[1]*s);
  r[2] = (bf16_t)(a[2]*s); r[3] = (bf16_t)(a[3]*s);
  r[4] = (bf16_t)(b[0]*s); r[5] = (bf16_t)(b[1]*s);
  r[6] = (bf16_t)(b[2]*s); r[7] = (bf16_t)(b[3]*s);
  return r;
}

__device__ __forceinline__ uint32_t pack2(float a, float b) {
  bf16x2 t; t[0] = (bf16_t)a; t[1] = (bf16_t)b;
  return __builtin_bit_cast(uint32_t, t);
}

__device__ __forceinline__ void st_c(bf16_t* p, float v) { *p = (bf16_t)v; }
__device__ __forceinline__ void st_c(float*  p, float v) { *p = v; }

// ---------------- fp32 -> bf16 convert pass + bias concat -------------------
// Wq and bq are pre-scaled by QSCALE so attention can use exp2(s) directly.
__global__ __launch_bounds__(256) void cvt_kernel(
    const float* __restrict__ x,  const float* __restrict__ wq,
    const float* __restrict__ wk, const float* __restrict__ wv,
    const float* __restrict__ wo,
    const float* __restrict__ bq, const float* __restrict__ bk,
    const float* __restrict__ bv,
    bf16_t* xb, bf16_t* wqb, bf16_t* wkb, bf16_t* wvb, bf16_t* wob,
    float* bcat)
{
  if (blockIdx.y >= 5) {   // float->float bias concat
    const float* fs; float* fd; size_t n; float sc;
    if (blockIdx.y == 5)      { fs = bq; fd = bcat;        n = HID; sc = QSCALE; }
    else if (blockIdx.y == 6) { fs = bk; fd = bcat + HID;  n = KVW; sc = 1.f; }
    else                      { fs = bv; fd = bcat + HID + KVW; n = KVW; sc = 1.f; }
    const size_t stride4 = (size_t)gridDim.x * 256 * 4;
    for (size_t i = ((size_t)blockIdx.x * 256 + threadIdx.x) * 4; i < n; i += stride4) {
      f32x4 v = *(const f32x4*)(fs + i);
      v[0] *= sc; v[1] *= sc; v[2] *= sc; v[3] *= sc;
      *(f32x4*)(fd + i) = v;
    }
    return;
  }
  const float* s; bf16_t* d; size_t n;
  switch (blockIdx.y) {
    case 0:  s = x;  d = xb;  n = (size_t)NB * SLEN * HID; break;
    case 1:  s = wq; d = wqb; n = (size_t)HID * HID; break;
    case 2:  s = wk; d = wkb; n = (size_t)KVW * HID; break;
    case 3:  s = wv; d = wvb; n = (size_t)KVW * HID; break;
    default: s = wo; d = wob; n = (size_t)HID * HID; break;
  }
  const bool scq = (blockIdx.y == 1);
  const size_t stride = (size_t)gridDim.x * 256 * 8;
  for (size_t i = ((size_t)blockIdx.x * 256 + threadIdx.x) * 8; i < n; i += stride)
    *(bf16x8*)(d + i) = scq ? ld8s(s + i, QSCALE) : ld8(s + i);
}

// =============== 256xBN fat-phase GEMM template (T1+T2+T4+T5) ===============
__device__ __forceinline__ bf16x8 ldfrag(const bf16_t* __restrict__ Lh, int r, int g) {
  return *(const bf16x8*)(Lh + r * 64 + ((g ^ (r & 7)) << 3));
}

template <int N>
__device__ __forceinline__ void vm_wait() {
  if constexpr (N == 0)      asm volatile("s_waitcnt vmcnt(0)" ::: "memory");
  else if constexpr (N == 2) asm volatile("s_waitcnt vmcnt(2)" ::: "memory");
  else if constexpr (N == 3) asm volatile("s_waitcnt vmcnt(3)" ::: "memory");
  else                       asm volatile("s_waitcnt vmcnt(4)" ::: "memory");
}

template <int H, int U>
__device__ __forceinline__ void mfma_halfU(const bf16x8 (&af2)[2][2][2],
                                           const bf16x8 (&bfr)[U][2],
                                           f32x4 (&acc)[8][U]) {
#pragma unroll
  for (int q = 0; q < 2; ++q)
#pragma unroll
    for (int ks = 0; ks < 2; ++ks)
#pragma unroll
      for (int i = 0; i < 2; ++i)
#pragma unroll
        for (int ni = 0; ni < U; ++ni)
          acc[4 * H + 2 * q + i][ni] =
              mfma16(af2[q][i][ks], bfr[ni][ks], acc[4 * H + 2 * q + i][ni]);
}

__device__ __forceinline__ void phase_barrier() {
  __builtin_amdgcn_s_barrier();
  asm volatile("" ::: "memory");
}

template <int U>
__device__ __forceinline__ void gemm_core_u(
    const bf16_t* __restrict__ Ag,
    const bf16_t* __restrict__ Bg,
    bf16_t* __restrict__ lds, f32x4 (&acc)[8][U])
{
  const int tid  = threadIdx.x;
  const int lane = tid & 63;
  const int w    = tid >> 6;
  const int fr   = lane & 15;
  const int quad = lane >> 4;
  const int wr   = w >> 2;
  const int wc   = w & 3;

  bf16_t* A0 = lds;
  bf16_t* B0 = lds + 16384;
  bf16_t* A1 = B0 + U * 4096;
  bf16_t* B1 = A1 + 16384;

  const f32x4 z4 = {0.f, 0.f, 0.f, 0.f};
#pragma unroll
  for (int i = 0; i < 8; ++i)
#pragma unroll
    for (int j = 0; j < U; ++j) acc[i][j] = z4;

  auto STAGEU = [&](const bf16_t* __restrict__ Gp, bf16_t* __restrict__ Lb, int u) {
    const int r = tid >> 3;
    const int g = (tid & 7) ^ (r & 7);
    gl2lds16(Gp + (size_t)(u * 64 + r) * HID + g * 8, Lb + u * 4096 + tid * 8);
  };
  auto LDB = [&](const bf16_t* __restrict__ Bb, bf16x8 (&bfr)[U][2]) {
#pragma unroll
    for (int ni = 0; ni < U; ++ni)
#pragma unroll
      for (int ks = 0; ks < 2; ++ks)
        bfr[ni][ks] = ldfrag(Bb, wc * (16 * U) + ni * 16 + fr, ks * 4 + quad);
  };
  auto LDAH = [&](const bf16_t* __restrict__ Ab, int h, bf16x8 (&af2)[2][2][2]) {
#pragma unroll
    for (int q = 0; q < 2; ++q)
#pragma unroll
      for (int i = 0; i < 2; ++i)
#pragma unroll
        for (int ks = 0; ks < 2; ++ks)
          af2[q][i][ks] =
              ldfrag(Ab, wr * 128 + h * 64 + q * 32 + i * 16 + fr, ks * 4 + quad);
  };

  // prologue: B(0), A(0), B(1)
#pragma unroll
  for (int u = 0; u < U; ++u) STAGEU(Bg, B0, u);
#pragma unroll
  for (int u = 0; u < 4; ++u) STAGEU(Ag, A0, u);
#pragma unroll
  for (int u = 0; u < U; ++u) STAGEU(Bg + 64, B1, u);
  vm_wait<U>();
  phase_barrier();

  bf16x8 bfr[U][2], af2[2][2][2];

#pragma unroll 1
  for (int it = 0; it < 16; ++it) {
    const bool more = (it < 15);
    const size_t k1 = (size_t)(2 * it + 1) * 64;
    const size_t k2 = (size_t)(2 * it + 2) * 64;
    const size_t k3 = (size_t)(2 * it + 3) * 64;

    // ---- p0: tile t (buf0), M-half 0; stage A(t+1) x4 -> A1
    LDB(B0, bfr);
    LDAH(A0, 0, af2);
#pragma unroll
    for (int u = 0; u < 4; ++u) STAGEU(Ag + k1, A1, u);
    phase_barrier();
    asm volatile("s_waitcnt lgkmcnt(0)" ::: "memory");
    __builtin_amdgcn_s_setprio(1);
    mfma_halfU<0>(af2, bfr, acc);
    __builtin_amdgcn_s_setprio(0);
    phase_barrier();

    // ---- p1: M-half 1; stage B(t+2) xU -> B0; drain A(t+1)+B(t+1)
    LDAH(A0, 1, af2);
    if (more) {
#pragma unroll
      for (int u = 0; u < U; ++u) STAGEU(Bg + k2, B0, u);
    }
    phase_barrier();
    asm volatile("s_waitcnt lgkmcnt(0)" ::: "memory");
    __builtin_amdgcn_s_setprio(1);
    mfma_halfU<1>(af2, bfr, acc);
    __builtin_amdgcn_s_setprio(0);
    if (more) vm_wait<U>(); else vm_wait<0>();
    phase_barrier();

    // ---- p2: tile t+1 (buf1), M-half 0; stage A(t+2) x4 -> A0
    LDB(B1, bfr);
    LDAH(A1, 0, af2);
    if (more) {
#pragma unroll
      for (int u = 0; u < 4; ++u) STAGEU(Ag + k2, A0, u);
    }
    phase_barrier();
    asm volatile("s_waitcnt lgkmcnt(0)" ::: "memory");
    __builtin_amdgcn_s_setprio(1);
    mfma_halfU<0>(af2, bfr, acc);
    __builtin_amdgcn_s_setprio(0);
    phase_barrier();

    // ---- p3: M-half 1; stage B(t+3) xU -> B1; drain A(t+2)+B(t+2)
    LDAH(A1, 1, af2);
    if (more) {
#pragma unroll
      for (int u = 0; u < U; ++u) STAGEU(Bg + k3, B1, u);
    }
    phase_barrier();
    asm volatile("s_waitcnt lgkmcnt(0)" ::: "memory");
    __builtin_amdgcn_s_setprio(1);
    mfma_halfU<1>(af2, bfr, acc);
    __builtin_amdgcn_s_setprio(0);
    if (more) vm_wait<U>();
    phase_barrier();
  }
}

// Region-chunked XCD swizzle for a 16x16 (cb x mb) grid.
__device__ __forceinline__ void grid_map16(int orig, int& cb, int& mb) {
  const int xcd = orig & 7, wp = orig >> 3;
  cb = (xcd & 1) * 8 + (wp & 7);
  mb = (xcd >> 1) * 4 + (wp >> 3);
}

// Epilogue bounce-buffer index with XOR-octet swizzle.
__device__ __forceinline__ int cswz(int row, int col, int CP) {
  const int cg = col >> 3;
  const int g  = (cg & ~7) | ((cg ^ (row >> 3)) & 7);
  return row * CP + (g << 3) + (col & 7);
}

// QKV: BN=192 (U=3), grid 256 full-chip. Wcat = [Wq|Wk|Wv].
__global__ __launch_bounds__(512, 2) void qkv8_kernel(
    const bf16_t* __restrict__ xb, const bf16_t* __restrict__ Wcat,
    const float* __restrict__ bcat,
    bf16_t* __restrict__ Qb, bf16_t* __restrict__ Kb, bf16_t* __restrict__ VbT)
{
  __shared__ __align__(16) bf16_t lds[57344];   // 112 KB
  int cb, mb;
  grid_map16(blockIdx.x, cb, mb);

  f32x4 acc[8][3];
  gemm_core_u<3>(xb + (size_t)mb * 256 * HID, Wcat + (size_t)cb * 192 * HID,
                 lds, acc);

  const int tid = threadIdx.x, lane = tid & 63, w = tid >> 6;
  const int fr = lane & 15, quad = lane >> 4, wr = w >> 2, wc = w & 3;
  const int CP = 200;
  bf16_t* C = lds;
#pragma unroll
  for (int ni = 0; ni < 3; ++ni) {
    const int col = wc * 48 + ni * 16 + fr;
    const float bz = bcat[cb * 192 + col];
#pragma unroll
    for (int mi = 0; mi < 8; ++mi)
#pragma unroll
      for (int r = 0; r < 4; ++r)
        C[cswz(wr * 128 + mi * 16 + quad * 4 + r, col, CP)] =
            (bf16_t)(acc[mi][ni][r] + bz);
  }
  asm volatile("s_waitcnt lgkmcnt(0)" ::: "memory");
  phase_barrier();

  // Q/K copy-out: 256 rows x 24 col-groups of 8 (16B chunks)
#pragma unroll
  for (int i = 0; i < 12; ++i) {
    const unsigned task = (unsigned)(i * 512 + tid);
    const unsigned row = task / 24u;
    const unsigned cg  = task - row * 24u;
    const int gcol0 = cb * 192 + (int)cg * 8;
    const int grow  = mb * 256 + (int)row;
    const int g = ((int)cg & ~7) | (((int)cg ^ ((int)row >> 3)) & 7);
    bf16x8 v = *(const bf16x8*)&C[(int)row * CP + (g << 3)];
    if (gcol0 < 2048)
      *(bf16x8*)&Qb[(size_t)grow * HID + gcol0] = v;
    else if (gcol0 < 2560)
      *(bf16x8*)&Kb[(size_t)grow * KVW + (gcol0 - 2048)] = v;
    // V chunks handled transposed below
  }
  // V copy-out (transposed): cb >= 13 carries V columns
  if (cb >= 13) {
    const int colbase = (cb == 13) ? 64 : 0;
    const int Nv = 192 - colbase;
    const int b = mb >> 3;
    const int s0 = (mb & 7) * 256;
#pragma unroll
    for (int i = 0; i < 12; ++i) {
      const int task = i * 512 + tid;
      const int vi = task >> 5, si = task & 31;
      if (vi < Nv) {
        const int col = colbase + vi;
        const int vc  = cb * 192 + col - 2560;       // 0..511
        bf16x8 pk;
#pragma unroll
        for (int j = 0; j < 8; ++j) pk[j] = C[cswz(si * 8 + j, col, CP)];
        *(bf16x8*)&VbT[((size_t)(b * NKVH + (vc >> 6)) * HDIM + (vc & 63)) * SLEN
                       + s0 + si * 8] = pk;
      }
    }
  }
}

// O-proj: BN=128 (U=2), grid 256 full-chip, f32 out.
__global__ __launch_bounds__(512, 2) void oproj8_kernel(
    const bf16_t* __restrict__ A, const bf16_t* __restrict__ Wob,
    const float* __restrict__ bo, float* __restrict__ out)
{
  __shared__ __align__(16) bf16_t lds[49152];   // 96 KB
  int cb, mb;
  grid_map16(blockIdx.x, cb, mb);

  f32x4 acc[8][2];
  gemm_core_u<2>(A + (size_t)mb * 256 * HID, Wob + (size_t)cb * 128 * HID,
                 lds, acc);

  const int tid = threadIdx.x, lane = tid & 63, w = tid >> 6;
  const int fr = lane & 15, quad = lane >> 4, wr = w >> 2, wc = w & 3;
  const int CPF = 132;
  float* Cf = (float*)lds;
#pragma unroll
  for (int s = 0; s < 2; ++s) {
    if (wr == s) {
#pragma unroll
      for (int ni = 0; ni < 2; ++ni) {
        const int col = wc * 32 + ni * 16 + fr;
        const float bz = bo[cb * 128 + col];
#pragma unroll
        for (int mi = 0; mi < 8; ++mi)
#pragma unroll
          for (int r = 0; r < 4; ++r)
            Cf[(mi * 16 + quad * 4 + r) * CPF + col] = acc[mi][ni][r] + bz;
      }
    }
    asm volatile("s_waitcnt lgkmcnt(0)" ::: "memory");
    phase_barrier();
#pragma unroll
    for (int i = 0; i < 8; ++i) {
      const int task = i * 512 + tid;
      const int row = task >> 5, cg = task & 31;
      f32x4 v = *(const f32x4*)&Cf[row * CPF + cg * 4];
      *(f32x4*)&out[(size_t)(mb * 256 + s * 128 + row) * HID + cb * 128 + cg * 4] = v;
    }
    phase_barrier();
  }
}

// ---------------- Path B (fallback): fp32-source GEMM -----------------------
template <typename AT, typename CT>
__device__ __forceinline__ void gemm128_tile(
    const AT* __restrict__ Ap, int lda,
    const float* __restrict__ Wp, int ldw,
    const float* __restrict__ biasp,
    CT* __restrict__ Cp, int ldc,
    int K)
{
  __shared__ __align__(16) bf16_t Al[128 * 32];
  __shared__ __align__(16) bf16_t Bl[128 * 32];

  const int tid  = threadIdx.x;
  const int lane = tid & 63;
  const int w    = tid >> 6;
  const int fr   = lane & 15;
  const int quad = lane >> 4;
  const int wm   = (w >> 1) * 64;
  const int wn   = (w & 1) * 64;

  const f32x4 z4 = {0.f, 0.f, 0.f, 0.f};
  f32x4 acc[4][4];
  for (int i = 0; i < 4; ++i)
    for (int j = 0; j < 4; ++j) acc[i][j] = z4;

  const int c0    = w * 2;
  const int srow0 = lane >> 2;
  const int skc   = (lane & 3) * 8;

  for (int k0 = 0; k0 < K; k0 += 32) {
    bf16x8 av[2], bv[2];
    for (int t = 0; t < 2; ++t) {
      const int r = (c0 + t) * 16 + srow0;
      av[t] = ld8(Ap + (size_t)r * lda + k0 + skc);
      bv[t] = ld8(Wp + (size_t)r * ldw + k0 + skc);
    }
    for (int t = 0; t < 2; ++t) {
      const int c = c0 + t;
      *(bf16x8*)&Al[c * 512 + lane * 8] = av[t];
      *(bf16x8*)&Bl[c * 512 + lane * 8] = bv[t];
    }
    __syncthreads();
    bf16x8 af[4], bfr[4];
    for (int mi = 0; mi < 4; ++mi)
      af[mi] = *(const bf16x8*)&Al[(wm + mi * 16 + fr) * 32 + quad * 8];
    for (int ni = 0; ni < 4; ++ni)
      bfr[ni] = *(const bf16x8*)&Bl[(wn + ni * 16 + fr) * 32 + quad * 8];
    for (int mi = 0; mi < 4; ++mi)
      for (int ni = 0; ni < 4; ++ni)
        acc[mi][ni] = mfma16(af[mi], bfr[ni], acc[mi][ni]);
    __syncthreads();
  }

  for (int ni = 0; ni < 4; ++ni) {
    const int col = wn + ni * 16 + fr;
    const float bz = biasp[col];
    for (int mi = 0; mi < 4; ++mi) {
      const int r0 = wm + mi * 16 + quad * 4;
      for (int r = 0; r < 4; ++r)
        st_c(Cp + (size_t)(r0 + r) * ldc + col, acc[mi][ni][r] + bz);
    }
  }
}

__global__ __launch_bounds__(256) void qkv_kernel(
    const float* __restrict__ x,
    const float* __restrict__ Wq, const float* __restrict__ bq,
    const float* __restrict__ Wk, const float* __restrict__ bk,
    const float* __restrict__ Wv, const float* __restrict__ bv,
    bf16_t* Qb, bf16_t* Kb, bf16_t* Vb)
{
  const int nb = blockIdx.x;
  const int mb = blockIdx.y;
  const float* W; const float* bias; bf16_t* C; int ldc;
  if (nb < 16)      { W = Wq + (size_t)nb * 128 * HID;  bias = bq + nb * 128;
                      C = Qb + nb * 128; ldc = HID; }
  else if (nb < 20) { const int j = nb - 16;
                      W = Wk + (size_t)j * 128 * HID;   bias = bk + j * 128;
                      C = Kb + j * 128; ldc = KVW; }
  else              { const int j = nb - 20;
                      W = Wv + (size_t)j * 128 * HID;   bias = bv + j * 128;
                      C = Vb + j * 128; ldc = KVW; }
  gemm128_tile<float, bf16_t>(x + (size_t)mb * 128 * HID, HID, W, HID, bias,
                              C + (size_t)mb * 128 * ldc, ldc, HID);
}

__global__ __launch_bounds__(256) void oproj_kernel(
    const bf16_t* __restrict__ A, const float* __restrict__ Wo,
    const float* __restrict__ bo, float* out)
{
  const int nb = blockIdx.x, mb = blockIdx.y;
  gemm128_tile<bf16_t, float>(A + (size_t)mb * 128 * HID, HID,
                              Wo + (size_t)nb * 128 * HID, HID,
                              bo + nb * 128,
                              out + (size_t)mb * 128 * HID + nb * 128, HID, HID);
}

__global__ __launch_bounds__(256) void vtrans_kernel(
    const bf16_t* __restrict__ Vb, bf16_t* __restrict__ VbT)
{
  __shared__ bf16_t T[64][72];
  const int st = blockIdx.x, kvh = blockIdx.y, b = blockIdx.z;
  const int tid = threadIdx.x;
  {
    const int row = tid >> 2;
    const int c16 = (tid & 3) * 16;
    const bf16_t* src =
        Vb + ((size_t)b * SLEN + st * 64 + row) * KVW + kvh * HDIM + c16;
    *(bf16x8*)&T[row][c16]     = *(const bf16x8*)(src);
    *(bf16x8*)&T[row][c16 + 8] = *(const bf16x8*)(src + 8);
  }
  __syncthreads();
  {
    const int d  = tid >> 2;
    const int sc = (tid & 3) * 16;
    bf16_t tmp[16];
    for (int j = 0; j < 16; ++j) tmp[j] = T[sc + j][d];
    bf16_t* dst = VbT + ((size_t)(b * NKVH + kvh) * HDIM + d) * SLEN + st * 64 + sc;
    *(bf16x8*)dst       = *(bf16x8*)&tmp[0];
    *(bf16x8*)(dst + 8) = *(bf16x8*)&tmp[8];
  }
}

// ---------------- Flash attention: dbuf K/V, shuffle-free P -----------------
// 8 waves, QBLK=128, KVBLK=128, grid 512 (one kvh per XCD). Swapped QK^T
// leaves lane owning P[q=fr][k in {32m+4quad+r} u {32m+16+4quad+r}]. PV uses
// a k-relabel kappa (kappa(4q+r)=8q+r, kappa(16+4q+r)=8q+4+r) applied to BOTH
// P slot order and V rows -> lane's own packed values ARE the A-fragment; no
// cross-lane exchange. V read as 2x ds_read_b64 at k-chunks {quad, 4+quad}
// (16B-group XOR swizzle keeps them ~2-way = free). ones8 is kappa-invariant.
template <bool PRESCALED>
__global__ __launch_bounds__(512, 4) void attn_kernel(
    const bf16_t* Q, const bf16_t* __restrict__ Kg,
    const bf16_t* __restrict__ VT, bf16_t* O)
{
  const int bid = blockIdx.x;            // 0..511
  const int kvh = bid & 7;               // one kvh per XCD
  const int jb  = bid >> 3;              // 0..63
  const int b   = jb >> 5;
  const int rem = jb & 31;
  const int h   = kvh * 4 + (rem & 3);
  const int pid = rem >> 2;              // 0..7

  const int tid  = threadIdx.x;
  const int lane = tid & 63;
  const int w    = tid >> 6;             // 0..7
  const int fr   = lane & 15;
  const int quad = lane >> 4;

  __shared__ __align__(16) bf16_t lds[32768];  // 2 x (KL 8192 + VtL 8192)

  const size_t qbase = (size_t)b * SLEN;
  const bf16_t* VTh = VT + (size_t)(b * NKVH + kvh) * HDIM * SLEN;

  const int fsw = (fr >> 1) & 3;
  // V chunk addresses (elements): chunk c in {quad, 4+quad}; group g=c>>1
  // stored at g^fsw; 8B half = (c&1)*4.
  const int vco  = (quad & 1) * 4;
  const int vg0  = (((quad >> 1)) ^ fsw) << 3;
  const int vg1  = ((((quad >> 1)) + 2) ^ fsw) << 3;

  bf16x8 ones8;
  {
    const bf16_t o1 = (bf16_t)(fr == 0 ? 1.0f : 0.0f);
#pragma unroll
    for (int j2 = 0; j2 < 8; ++j2) ones8[j2] = o1;
  }

  auto STAGE_KV = [&](int kt, bf16_t* KL) {
    const size_t krow0 = qbase + (size_t)kt * 128;
    bf16_t* VtL = KL + 8192;
#pragma unroll
    for (int jj = 0; jj < 2; ++jj) {
      const int s  = jj * 512 + tid;
      const int ks = s >> 9, kr = (s >> 2) & 127, c8 = (s & 3) ^ ((kr >> 1) & 3);
      gl2lds16(&Kg[(krow0 + kr) * KVW + kvh * HDIM + ks * 32 + c8 * 8],
               &KL[s * 8]);
    }
#pragma unroll
    for (int jj = 0; jj < 2; ++jj) {
      const int idx = jj * 512 + tid;
      const int kb = idx >> 8, d = (idx >> 2) & 63, c8 = (idx & 3) ^ ((d >> 1) & 3);
      gl2lds16(&VTh[(size_t)d * SLEN + kt * 128 + kb * 32 + c8 * 8],
               &VtL[idx * 8]);
    }
  };

  for (int half = 0; half < 2; ++half) {
    const int qt = half ? (15 - pid) : pid;
    const int q0 = qt * 128;

    bf16x8 qf[2];
#pragma unroll
    for (int ks = 0; ks < 2; ++ks)
      qf[ks] = *(const bf16x8*)&Q[(qbase + q0 + w * 16 + fr) * HID
                                  + h * HDIM + ks * 32 + quad * 8];

    const f32x4 z4 = {0.f, 0.f, 0.f, 0.f};
    f32x4 o_acc[4];
    f32x4 o_l = z4;
#pragma unroll
    for (int di = 0; di < 4; ++di) o_acc[di] = z4;

    const int ktmax = qt;
    const int qloc  = w * 16 + fr;       // q local to the 128-row diag tile

    STAGE_KV(0, lds);
    asm volatile("s_waitcnt vmcnt(0)" ::: "memory");
    phase_barrier();

    int cur = 0;
    for (int kt = 0; kt <= ktmax; ++kt) {
      bf16_t* KL  = lds + cur * 16384;
      bf16_t* VtL = KL + 8192;
      if (kt < ktmax) STAGE_KV(kt + 1, lds + (cur ^ 1) * 16384);

      f32x4 s8[8];
#pragma unroll
      for (int ki = 0; ki < 8; ++ki) s8[ki] = z4;
      __builtin_amdgcn_s_setprio(1);
#pragma unroll
      for (int ks = 0; ks < 2; ++ks)
#pragma unroll
        for (int ki = 0; ki < 8; ++ki) {
          bf16x8 kf = *(const bf16x8*)&KL[ks * 4096 + (ki * 16 + fr) * 32
                                          + ((quad ^ fsw) << 3)];
          s8[ki] = mfma16(kf, qf[ks], s8[ki]);
        }
      __builtin_amdgcn_s_setprio(0);

      const float C2 = 0.18033688f;   // log2(e)/8 (only if !PRESCALED)
      const bool diag = (kt == ktmax);

#pragma unroll
      for (int m = 0; m < 4; ++m) {
        float pe[8];
#pragma unroll
        for (int ki2 = 0; ki2 < 2; ++ki2) {
          const int ki = 2 * m + ki2;
#pragma unroll
          for (int r = 0; r < 4; ++r) {
            const float sv = PRESCALED ? s8[ki][r] : s8[ki][r] * C2;
            float p = fast_exp2(sv);
            if (diag && (ki * 16 + quad * 4 + r > qloc)) p = 0.f;
            pe[ki2 * 4 + r] = p;
          }
        }
        // lane's own 8 values, packed in kappa order = PV A-fragment
        union { uint32_t u[4]; bf16x8 v; } pb;
        pb.u[0] = pack2(pe[0], pe[1]);
        pb.u[1] = pack2(pe[2], pe[3]);
        pb.u[2] = pack2(pe[4], pe[5]);
        pb.u[3] = pack2(pe[6], pe[7]);

        __builtin_amdgcn_s_setprio(1);
        o_l = mfma16(pb.v, ones8, o_l);
#pragma unroll
        for (int di = 0; di < 4; ++di) {
          const int rowoff = m * 2048 + (di * 16 + fr) * 32;
          union { bf16x4 h[2]; bf16x8 v; } vf;
          vf.h[0] = *(const bf16x4*)&VtL[rowoff + vg0 + vco];
          vf.h[1] = *(const bf16x4*)&VtL[rowoff + vg1 + vco];
          o_acc[di] = mfma16(pb.v, vf.v, o_acc[di]);
        }
        __builtin_amdgcn_s_setprio(0);
      }

      asm volatile("s_waitcnt vmcnt(0)" ::: "memory");
      phase_barrier();
      cur ^= 1;
    }

    bf16_t* OB = lds;   // 128 x 72 bf16 = 18KB (stride 72 kills 8-way writes)
#pragma unroll
    for (int r = 0; r < 4; ++r) {
      const float l  = __shfl(o_l[r], lane & 48);
      const float rl = 1.f / l;
      const int q = w * 16 + quad * 4 + r;
#pragma unroll
      for (int di = 0; di < 4; ++di)
        OB[q * 72 + di * 16 + fr] = (bf16_t)(o_acc[di][r] * rl);
    }
    asm volatile("s_waitcnt lgkmcnt(0)" ::: "memory");
    phase_barrier();
    {
      const int row = tid >> 2;          // 0..127
      const int seg = tid & 3;           // 0..3 (16 bf16 each)
      bf16x8 v0 = *(const bf16x8*)&OB[row * 72 + seg * 16];
      bf16x8 v1 = *(const bf16x8*)&OB[row * 72 + seg * 16 + 8];
      bf16_t* dst = &O[(qbase + q0 + row) * HID + h * HDIM + seg * 16];
      *(bf16x8*)dst       = v0;
      *(bf16x8*)(dst + 8) = v1;
    }
    phase_barrier();   // protect OB before next half's staging
  }
}

extern "C" void kernel_launch(void* const* d_in, const int* in_sizes, int n_in,
                              void* d_out, int out_size, void* d_ws, size_t ws_size,
                              hipStream_t stream) {
  const float* x  = (const float*)d_in[0];
  // d_in[1] = causal mask (int32) -- recomputed inline, not read
  const float* Wq = (const float*)d_in[2];
  const float* bq = (const float*)d_in[3];
  const float* Wk = (const float*)d_in[4];
  const float* bk = (const float*)d_in[5];
  const float* Wv = (const float*)d_in[6];
  const float* bv = (const float*)d_in[7];
  const float* Wo = (const float*)d_in[8];
  const float* bo = (const float*)d_in[9];
  float* out = (float*)d_out;

  const size_t M = (size_t)NB * SLEN;          // 4096
  dim3 blk(256, 1, 1);

  const size_t needA = (M * HID
                        + (size_t)HID * HID
                        + (size_t)KVW * HID
                        + (size_t)KVW * HID
                        + (size_t)HID * HID
                        + M * HID
                        + M * KVW
                        + M * KVW) * 2
                       + (size_t)(HID + 2 * KVW) * sizeof(float);
  if (ws_size >= needA) {
    bf16_t* xb  = (bf16_t*)d_ws;
    bf16_t* Wqb = xb  + M * HID;              // Wq|Wk|Wv contiguous = Wcat
    bf16_t* Wkb = Wqb + (size_t)HID * HID;
    bf16_t* Wvb = Wkb + (size_t)KVW * HID;
    bf16_t* Wob = Wvb + (size_t)KVW * HID;
    bf16_t* Qb  = Wob + (size_t)HID * HID;
    bf16_t* Kb  = Qb  + M * HID;
    bf16_t* VbT = Kb  + M * KVW;
    float*  bcat = (float*)(VbT + M * KVW);   // [bq|bk|bv], 3072 floats

    cvt_kernel<<<dim3(1024, 8, 1), blk, 0, stream>>>(
        x, Wq, Wk, Wv, Wo, bq, bk, bv, xb, Wqb, Wkb, Wvb, Wob, bcat);
    qkv8_kernel<<<dim3(256, 1, 1), dim3(512, 1, 1), 0, stream>>>(
        xb, Wqb, bcat, Qb, Kb, VbT);
    attn_kernel<true><<<dim3(512, 1, 1), dim3(512, 1, 1), 0, stream>>>(
        Qb, Kb, VbT, Qb);
    oproj8_kernel<<<dim3(256, 1, 1), dim3(512, 1, 1), 0, stream>>>(
        Qb, Wob, bo, out);
  } else {
    bf16_t* Qb  = (bf16_t*)d_ws;
    bf16_t* Kb  = Qb + M * HID;
    bf16_t* Vb  = Kb + M * KVW;
    bf16_t* VbT = Vb + M * KVW;

    qkv_kernel<<<dim3(24, 32, 1), blk, 0, stream>>>(x, Wq, bq, Wk, bk, Wv, bv, Qb, Kb, Vb);
    vtrans_kernel<<<dim3(32, 8, 2), blk, 0, stream>>>(Vb, VbT);
    attn_kernel<false><<<dim3(512, 1, 1), dim3(512, 1, 1), 0, stream>>>(
        Qb, Kb, VbT, Qb);
    oproj_kernel<<<dim3(16, 32, 1), blk, 0, stream>>>(Qb, Wo, bo, out);
  }
}

// Round 8
// 269.060 us; speedup vs baseline: 1.1915x; 1.0008x over previous
//
#include <hip/hip_runtime.h>
#include <hip/hip_bf16.h>
#include <stdint.h>

#define HID   2048
#define SLEN  2048
#define NB    2
#define NHEADS 32
#define NKVH   8
#define HDIM   64
#define KVW    512   // NKVH*HDIM
#define QSCALE 0.18033688f   // log2(e)/8, folded into Wq/bq at cvt time

typedef __bf16 bf16_t;
typedef __bf16 bf16x2 __attribute__((ext_vector_type(2)));
typedef __bf16 bf16x4 __attribute__((ext_vector_type(4)));
typedef __bf16 bf16x8 __attribute__((ext_vector_type(8)));
typedef float  f32x4  __attribute__((ext_vector_type(4)));

__device__ __forceinline__ f32x4 mfma16(bf16x8 a, bf16x8 b, f32x4 c) {
  return __builtin_amdgcn_mfma_f32_16x16x32_bf16(a, b, c, 0, 0, 0);
}

__device__ __forceinline__ void gl2lds16(const bf16_t* g, bf16_t* l) {
  __builtin_amdgcn_global_load_lds(
      (const __attribute__((address_space(1))) void*)g,
      (__attribute__((address_space(3))) void*)l,
      16, 0, 0);
}

__device__ __forceinline__ float fast_exp2(float x) {
#if __has_builtin(__builtin_amdgcn_exp2f)
  return __builtin_amdgcn_exp2f(x);
#else
  return __expf(x * 0.69314718f);
#endif
}

__device__ __forceinline__ bf16x8 ld8(const bf16_t* p) {
  return *(const bf16x8*)p;
}
__device__ __forceinline__ bf16x8 ld8(const float* p) {
  f32x4 a = *(const f32x4*)p;
  f32x4 b = *(const f32x4*)(p + 4);
  bf16x8 r;
  r[0] = (bf16_t)a[0]; r[1] = (bf16_t)a[1]; r[2] = (bf16_t)a[2]; r[3] = (bf16_t)a[3];
  r[4] = (bf16_t)b[0]; r[5] = (bf16_t)b[1]; r[6] = (bf16_t)b[2]; r[7] = (bf16_t)b[3];
  return r;
}
__device__ __forceinline__ bf16x8 ld8s(const float* p, float s) {
  f32x4 a = *(const f32x4*)p;
  f32x4 b = *(const f32x4*)(p + 4);
  bf16x8 r;
  r[0] = (bf16_t)(a[0]*s); r[1] = (bf16_t)(a[1]*s);
  r[2] = (bf16_t)(a[2]*s); r[3] = (bf16_t)(a[3]*s);
  r[4] = (bf16_t)(b[0]*s); r[5] = (bf16_t)(b[1]*s);
  r[6] = (bf16_t)(b[2]*s); r[7] = (bf16_t)(b[7-7]*0.f + b[3]*s);
  return r;
}

__device__ __forceinline__ uint32_t pack2(float a, float b) {
  bf16x2 t; t[0] = (bf16_t)a; t[1] = (bf16_t)b;
  return __builtin_bit_cast(uint32_t, t);
}

__device__ __forceinline__ void st_c(bf16_t* p, float v) { *p = (bf16_t)v; }
__device__ __forceinline__ void st_c(float*  p, float v) { *p = v; }

// ---------------- fp32 -> bf16 convert pass + bias concat -------------------
// Wq and bq are pre-scaled by QSCALE so attention can use exp2(s) directly.
__global__ __launch_bounds__(256) void cvt_kernel(
    const float* __restrict__ x,  const float* __restrict__ wq,
    const float* __restrict__ wk, const float* __restrict__ wv,
    const float* __restrict__ wo,
    const float* __restrict__ bq, const float* __restrict__ bk,
    const float* __restrict__ bv,
    bf16_t* xb, bf16_t* wqb, bf16_t* wkb, bf16_t* wvb, bf16_t* wob,
    float* bcat)
{
  if (blockIdx.y >= 5) {   // float->float bias concat
    const float* fs; float* fd; size_t n; float sc;
    if (blockIdx.y == 5)      { fs = bq; fd = bcat;        n = HID; sc = QSCALE; }
    else if (blockIdx.y == 6) { fs = bk; fd = bcat + HID;  n = KVW; sc = 1.f; }
    else                      { fs = bv; fd = bcat + HID + KVW; n = KVW; sc = 1.f; }
    const size_t stride4 = (size_t)gridDim.x * 256 * 4;
    for (size_t i = ((size_t)blockIdx.x * 256 + threadIdx.x) * 4; i < n; i += stride4) {
      f32x4 v = *(const f32x4*)(fs + i);
      v[0] *= sc; v[1] *= sc; v[2] *= sc; v[3] *= sc;
      *(f32x4*)(fd + i) = v;
    }
    return;
  }
  const float* s; bf16_t* d; size_t n;
  switch (blockIdx.y) {
    case 0:  s = x;  d = xb;  n = (size_t)NB * SLEN * HID; break;
    case 1:  s = wq; d = wqb; n = (size_t)HID * HID; break;
    case 2:  s = wk; d = wkb; n = (size_t)KVW * HID; break;
    case 3:  s = wv; d = wvb; n = (size_t)KVW * HID; break;
    default: s = wo; d = wob; n = (size_t)HID * HID; break;
  }
  const bool scq = (blockIdx.y == 1);
  const size_t stride = (size_t)gridDim.x * 256 * 8;
  for (size_t i = ((size_t)blockIdx.x * 256 + threadIdx.x) * 8; i < n; i += stride)
    *(bf16x8*)(d + i) = scq ? ld8s(s + i, QSCALE) : ld8(s + i);
}

// ========== 256xBN fat-phase GEMM, A TRI-BUFFERED (T1+T2+T4+T5) ============
// BM=256 rows, BK=64, BN = U*64. 512 threads = 8 waves (2M x 4N).
// LDS = 3 x A(32KB) + 2 x B(U*8KB): A triple-buffered so the issue->wait
// distance for every staged unit is >= 2 full fat-phases (covers ~900cyc HBM
// first-touch latency even at target phase times). Issue order per iter
// (tiles t,t+1): p0 A(t+2), p1 B(t+2), p2 A(t+3), p3 B(t+3). Counted waits
// vmcnt(4+U) at p1/p3 ends drain exactly the units the next two phases read
// (in-order queue: steady-state outstanding = 2*(4+U), drain half).
__device__ __forceinline__ bf16x8 ldfrag(const bf16_t* __restrict__ Lh, int r, int g) {
  return *(const bf16x8*)(Lh + r * 64 + ((g ^ (r & 7)) << 3));
}

template <int N>
__device__ __forceinline__ void vm_wait() {
  if constexpr (N == 0)      asm volatile("s_waitcnt vmcnt(0)" ::: "memory");
  else if constexpr (N == 2) asm volatile("s_waitcnt vmcnt(2)" ::: "memory");
  else if constexpr (N == 3) asm volatile("s_waitcnt vmcnt(3)" ::: "memory");
  else if constexpr (N == 4) asm volatile("s_waitcnt vmcnt(4)" ::: "memory");
  else if constexpr (N == 5) asm volatile("s_waitcnt vmcnt(5)" ::: "memory");
  else if constexpr (N == 6) asm volatile("s_waitcnt vmcnt(6)" ::: "memory");
  else                       asm volatile("s_waitcnt vmcnt(7)" ::: "memory");
}

template <int H, int U>
__device__ __forceinline__ void mfma_halfU(const bf16x8 (&af2)[2][2][2],
                                           const bf16x8 (&bfr)[U][2],
                                           f32x4 (&acc)[8][U]) {
#pragma unroll
  for (int q = 0; q < 2; ++q)
#pragma unroll
    for (int ks = 0; ks < 2; ++ks)
#pragma unroll
      for (int i = 0; i < 2; ++i)
#pragma unroll
        for (int ni = 0; ni < U; ++ni)
          acc[4 * H + 2 * q + i][ni] =
              mfma16(af2[q][i][ks], bfr[ni][ks], acc[4 * H + 2 * q + i][ni]);
}

__device__ __forceinline__ void phase_barrier() {
  __builtin_amdgcn_s_barrier();
  asm volatile("" ::: "memory");
}

template <int U>
__device__ __forceinline__ void gemm_core_u(
    const bf16_t* __restrict__ Ag,
    const bf16_t* __restrict__ Bg,
    bf16_t* __restrict__ lds, f32x4 (&acc)[8][U])
{
  const int tid  = threadIdx.x;
  const int lane = tid & 63;
  const int w    = tid >> 6;
  const int fr   = lane & 15;
  const int quad = lane >> 4;
  const int wr   = w >> 2;
  const int wc   = w & 3;

  bf16_t* Aa = lds;                 // holds A(t)
  bf16_t* Ab = lds + 16384;         // holds A(t+1)
  bf16_t* Ac = lds + 32768;         // stage target for A(t+2)
  bf16_t* B0 = lds + 49152;
  bf16_t* B1 = B0 + U * 4096;

  const f32x4 z4 = {0.f, 0.f, 0.f, 0.f};
#pragma unroll
  for (int i = 0; i < 8; ++i)
#pragma unroll
    for (int j = 0; j < U; ++j) acc[i][j] = z4;

  auto STAGEU = [&](const bf16_t* __restrict__ Gp, bf16_t* __restrict__ Lb, int u) {
    const int r = tid >> 3;
    const int g = (tid & 7) ^ (r & 7);
    gl2lds16(Gp + (size_t)(u * 64 + r) * HID + g * 8, Lb + u * 4096 + tid * 8);
  };
  auto LDB = [&](const bf16_t* __restrict__ Bb, bf16x8 (&bfr)[U][2]) {
#pragma unroll
    for (int ni = 0; ni < U; ++ni)
#pragma unroll
      for (int ks = 0; ks < 2; ++ks)
        bfr[ni][ks] = ldfrag(Bb, wc * (16 * U) + ni * 16 + fr, ks * 4 + quad);
  };
  auto LDAH = [&](const bf16_t* __restrict__ Ab_, int h, bf16x8 (&af2)[2][2][2]) {
#pragma unroll
    for (int q = 0; q < 2; ++q)
#pragma unroll
      for (int i = 0; i < 2; ++i)
#pragma unroll
        for (int ks = 0; ks < 2; ++ks)
          af2[q][i][ks] =
              ldfrag(Ab_, wr * 128 + h * 64 + q * 32 + i * 16 + fr, ks * 4 + quad);
  };

  // prologue: A(0)->Aa, B(0)->B0, A(1)->Ab, B(1)->B1
#pragma unroll
  for (int u = 0; u < 4; ++u) STAGEU(Ag, Aa, u);
#pragma unroll
  for (int u = 0; u < U; ++u) STAGEU(Bg, B0, u);
#pragma unroll
  for (int u = 0; u < 4; ++u) STAGEU(Ag + 64, Ab, u);
#pragma unroll
  for (int u = 0; u < U; ++u) STAGEU(Bg + 64, B1, u);
  vm_wait<4 + U>();     // A(0),B(0) landed; A(1),B(1) = steady-state backlog
  phase_barrier();

  bf16x8 bfr[U][2], af2[2][2][2];

#pragma unroll 1
  for (int it = 0; it < 16; ++it) {
    const bool more = (it < 15);
    const size_t k2 = (size_t)(2 * it + 2) * 64;
    const size_t k3 = (size_t)(2 * it + 3) * 64;

    // ---- p0: tile t (Aa,B0), M-half 0; stage A(t+2) -> Ac
    LDB(B0, bfr);
    LDAH(Aa, 0, af2);
    if (more) {
#pragma unroll
      for (int u = 0; u < 4; ++u) STAGEU(Ag + k2, Ac, u);
    }
    phase_barrier();
    asm volatile("s_waitcnt lgkmcnt(0)" ::: "memory");
    __builtin_amdgcn_s_setprio(1);
    mfma_halfU<0>(af2, bfr, acc);
    __builtin_amdgcn_s_setprio(0);
    phase_barrier();

    // ---- p1: M-half 1; stage B(t+2) -> B0; drain A(t+1)+B(t+1)
    LDAH(Aa, 1, af2);
    if (more) {
#pragma unroll
      for (int u = 0; u < U; ++u) STAGEU(Bg + k2, B0, u);
    }
    phase_barrier();
    asm volatile("s_waitcnt lgkmcnt(0)" ::: "memory");
    __builtin_amdgcn_s_setprio(1);
    mfma_halfU<1>(af2, bfr, acc);
    __builtin_amdgcn_s_setprio(0);
    if (more) vm_wait<4 + U>(); else vm_wait<0>();
    phase_barrier();

    // ---- p2: tile t+1 (Ab,B1), M-half 0; stage A(t+3) -> Aa
    LDB(B1, bfr);
    LDAH(Ab, 0, af2);
    if (more) {
#pragma unroll
      for (int u = 0; u < 4; ++u) STAGEU(Ag + k3, Aa, u);
    }
    phase_barrier();
    asm volatile("s_waitcnt lgkmcnt(0)" ::: "memory");
    __builtin_amdgcn_s_setprio(1);
    mfma_halfU<0>(af2, bfr, acc);
    __builtin_amdgcn_s_setprio(0);
    phase_barrier();

    // ---- p3: M-half 1; stage B(t+3) -> B1; drain A(t+2)+B(t+2)
    LDAH(Ab, 1, af2);
    if (more) {
#pragma unroll
      for (int u = 0; u < U; ++u) STAGEU(Bg + k3, B1, u);
    }
    phase_barrier();
    asm volatile("s_waitcnt lgkmcnt(0)" ::: "memory");
    __builtin_amdgcn_s_setprio(1);
    mfma_halfU<1>(af2, bfr, acc);
    __builtin_amdgcn_s_setprio(0);
    if (more) vm_wait<4 + U>();
    phase_barrier();

    // rotate A buffers: next iter's (t,t+1) live in Ac, Aa
    bf16_t* t0 = Aa; Aa = Ac; Ac = Ab; Ab = t0;
  }
}

// Region-chunked XCD swizzle for a 16x16 (cb x mb) grid.
__device__ __forceinline__ void grid_map16(int orig, int& cb, int& mb) {
  const int xcd = orig & 7, wp = orig >> 3;
  cb = (xcd & 1) * 8 + (wp & 7);
  mb = (xcd >> 1) * 4 + (wp >> 3);
}

// Epilogue bounce-buffer index with XOR-octet swizzle.
__device__ __forceinline__ int cswz(int row, int col, int CP) {
  const int cg = col >> 3;
  const int g  = (cg & ~7) | ((cg ^ (row >> 3)) & 7);
  return row * CP + (g << 3) + (col & 7);
}

// QKV: BN=192 (U=3), grid 256 full-chip. Wcat = [Wq|Wk|Wv]. LDS 144KB.
__global__ __launch_bounds__(512, 2) void qkv8_kernel(
    const bf16_t* __restrict__ xb, const bf16_t* __restrict__ Wcat,
    const float* __restrict__ bcat,
    bf16_t* __restrict__ Qb, bf16_t* __restrict__ Kb, bf16_t* __restrict__ VbT)
{
  __shared__ __align__(16) bf16_t lds[73728];   // 144 KB: 3xA(32K) + 2xB(24K)
  int cb, mb;
  grid_map16(blockIdx.x, cb, mb);

  f32x4 acc[8][3];
  gemm_core_u<3>(xb + (size_t)mb * 256 * HID, Wcat + (size_t)cb * 192 * HID,
                 lds, acc);

  const int tid = threadIdx.x, lane = tid & 63, w = tid >> 6;
  const int fr = lane & 15, quad = lane >> 4, wr = w >> 2, wc = w & 3;
  const int CP = 200;
  bf16_t* C = lds;
#pragma unroll
  for (int ni = 0; ni < 3; ++ni) {
    const int col = wc * 48 + ni * 16 + fr;
    const float bz = bcat[cb * 192 + col];
#pragma unroll
    for (int mi = 0; mi < 8; ++mi)
#pragma unroll
      for (int r = 0; r < 4; ++r)
        C[cswz(wr * 128 + mi * 16 + quad * 4 + r, col, CP)] =
            (bf16_t)(acc[mi][ni][r] + bz);
  }
  asm volatile("s_waitcnt lgkmcnt(0)" ::: "memory");
  phase_barrier();

  // Q/K copy-out: 256 rows x 24 col-groups of 8 (16B chunks)
#pragma unroll
  for (int i = 0; i < 12; ++i) {
    const unsigned task = (unsigned)(i * 512 + tid);
    const unsigned row = task / 24u;
    const unsigned cg  = task - row * 24u;
    const int gcol0 = cb * 192 + (int)cg * 8;
    const int grow  = mb * 256 + (int)row;
    const int g = ((int)cg & ~7) | (((int)cg ^ ((int)row >> 3)) & 7);
    bf16x8 v = *(const bf16x8*)&C[(int)row * CP + (g << 3)];
    if (gcol0 < 2048)
      *(bf16x8*)&Qb[(size_t)grow * HID + gcol0] = v;
    else if (gcol0 < 2560)
      *(bf16x8*)&Kb[(size_t)grow * KVW + (gcol0 - 2048)] = v;
    // V chunks handled transposed below
  }
  // V copy-out (transposed): cb >= 13 carries V columns
  if (cb >= 13) {
    const int colbase = (cb == 13) ? 64 : 0;
    const int Nv = 192 - colbase;
    const int b = mb >> 3;
    const int s0 = (mb & 7) * 256;
#pragma unroll
    for (int i = 0; i < 12; ++i) {
      const int task = i * 512 + tid;
      const int vi = task >> 5, si = task & 31;
      if (vi < Nv) {
        const int col = colbase + vi;
        const int vc  = cb * 192 + col - 2560;       // 0..511
        bf16x8 pk;
#pragma unroll
        for (int j = 0; j < 8; ++j) pk[j] = C[cswz(si * 8 + j, col, CP)];
        *(bf16x8*)&VbT[((size_t)(b * NKVH + (vc >> 6)) * HDIM + (vc & 63)) * SLEN
                       + s0 + si * 8] = pk;
      }
    }
  }
}

// O-proj: BN=128 (U=2), grid 256 full-chip, f32 out. LDS 128KB.
__global__ __launch_bounds__(512, 2) void oproj8_kernel(
    const bf16_t* __restrict__ A, const bf16_t* __restrict__ Wob,
    const float* __restrict__ bo, float* __restrict__ out)
{
  __shared__ __align__(16) bf16_t lds[65536];   // 128 KB: 3xA(32K) + 2xB(16K)
  int cb, mb;
  grid_map16(blockIdx.x, cb, mb);

  f32x4 acc[8][2];
  gemm_core_u<2>(A + (size_t)mb * 256 * HID, Wob + (size_t)cb * 128 * HID,
                 lds, acc);

  const int tid = threadIdx.x, lane = tid & 63, w = tid >> 6;
  const int fr = lane & 15, quad = lane >> 4, wr = w >> 2, wc = w & 3;
  const int CPF = 132;
  float* Cf = (float*)lds;
#pragma unroll
  for (int s = 0; s < 2; ++s) {
    if (wr == s) {
#pragma unroll
      for (int ni = 0; ni < 2; ++ni) {
        const int col = wc * 32 + ni * 16 + fr;
        const float bz = bo[cb * 128 + col];
#pragma unroll
        for (int mi = 0; mi < 8; ++mi)
#pragma unroll
          for (int r = 0; r < 4; ++r)
            Cf[(mi * 16 + quad * 4 + r) * CPF + col] = acc[mi][ni][r] + bz;
      }
    }
    asm volatile("s_waitcnt lgkmcnt(0)" ::: "memory");
    phase_barrier();
#pragma unroll
    for (int i = 0; i < 8; ++i) {
      const int task = i * 512 + tid;
      const int row = task >> 5, cg = task & 31;
      f32x4 v = *(const f32x4*)&Cf[row * CPF + cg * 4];
      *(f32x4*)&out[(size_t)(mb * 256 + s * 128 + row) * HID + cb * 128 + cg * 4] = v;
    }
    phase_barrier();
  }
}

// ---------------- Path B (fallback): fp32-source GEMM -----------------------
template <typename AT, typename CT>
__device__ __forceinline__ void gemm128_tile(
    const AT* __restrict__ Ap, int lda,
    const float* __restrict__ Wp, int ldw,
    const float* __restrict__ biasp,
    CT* __restrict__ Cp, int ldc,
    int K)
{
  __shared__ __align__(16) bf16_t Al[128 * 32];
  __shared__ __align__(16) bf16_t Bl[128 * 32];

  const int tid  = threadIdx.x;
  const int lane = tid & 63;
  const int w    = tid >> 6;
  const int fr   = lane & 15;
  const int quad = lane >> 4;
  const int wm   = (w >> 1) * 64;
  const int wn   = (w & 1) * 64;

  const f32x4 z4 = {0.f, 0.f, 0.f, 0.f};
  f32x4 acc[4][4];
  for (int i = 0; i < 4; ++i)
    for (int j = 0; j < 4; ++j) acc[i][j] = z4;

  const int c0    = w * 2;
  const int srow0 = lane >> 2;
  const int skc   = (lane & 3) * 8;

  for (int k0 = 0; k0 < K; k0 += 32) {
    bf16x8 av[2], bv[2];
    for (int t = 0; t < 2; ++t) {
      const int r = (c0 + t) * 16 + srow0;
      av[t] = ld8(Ap + (size_t)r * lda + k0 + skc);
      bv[t] = ld8(Wp + (size_t)r * ldw + k0 + skc);
    }
    for (int t = 0; t < 2; ++t) {
      const int c = c0 + t;
      *(bf16x8*)&Al[c * 512 + lane * 8] = av[t];
      *(bf16x8*)&Bl[c * 512 + lane * 8] = bv[t];
    }
    __syncthreads();
    bf16x8 af[4], bfr[4];
    for (int mi = 0; mi < 4; ++mi)
      af[mi] = *(const bf16x8*)&Al[(wm + mi * 16 + fr) * 32 + quad * 8];
    for (int ni = 0; ni < 4; ++ni)
      bfr[ni] = *(const bf16x8*)&Bl[(wn + ni * 16 + fr) * 32 + quad * 8];
    for (int mi = 0; mi < 4; ++mi)
      for (int ni = 0; ni < 4; ++ni)
        acc[mi][ni] = mfma16(af[mi], bfr[ni], acc[mi][ni]);
    __syncthreads();
  }

  for (int ni = 0; ni < 4; ++ni) {
    const int col = wn + ni * 16 + fr;
    const float bz = biasp[col];
    for (int mi = 0; mi < 4; ++mi) {
      const int r0 = wm + mi * 16 + quad * 4;
      for (int r = 0; r < 4; ++r)
        st_c(Cp + (size_t)(r0 + r) * ldc + col, acc[mi][ni][r] + bz);
    }
  }
}

__global__ __launch_bounds__(256) void qkv_kernel(
    const float* __restrict__ x,
    const float* __restrict__ Wq, const float* __restrict__ bq,
    const float* __restrict__ Wk, const float* __restrict__ bk,
    const float* __restrict__ Wv, const float* __restrict__ bv,
    bf16_t* Qb, bf16_t* Kb, bf16_t* Vb)
{
  const int nb = blockIdx.x;
  const int mb = blockIdx.y;
  const float* W; const float* bias; bf16_t* C; int ldc;
  if (nb < 16)      { W = Wq + (size_t)nb * 128 * HID;  bias = bq + nb * 128;
                      C = Qb + nb * 128; ldc = HID; }
  else if (nb < 20) { const int j = nb - 16;
                      W = Wk + (size_t)j * 128 * HID;   bias = bk + j * 128;
                      C = Kb + j * 128; ldc = KVW; }
  else              { const int j = nb - 20;
                      W = Wv + (size_t)j * 128 * HID;   bias = bv + j * 128;
                      C = Vb + j * 128; ldc = KVW; }
  gemm128_tile<float, bf16_t>(x + (size_t)mb * 128 * HID, HID, W, HID, bias,
                              C + (size_t)mb * 128 * ldc, ldc, HID);
}

__global__ __launch_bounds__(256) void oproj_kernel(
    const bf16_t* __restrict__ A, const float* __restrict__ Wo,
    const float* __restrict__ bo, float* out)
{
  const int nb = blockIdx.x, mb = blockIdx.y;
  gemm128_tile<bf16_t, float>(A + (size_t)mb * 128 * HID, HID,
                              Wo + (size_t)nb * 128 * HID, HID,
                              bo + nb * 128,
                              out + (size_t)mb * 128 * HID + nb * 128, HID, HID);
}

__global__ __launch_bounds__(256) void vtrans_kernel(
    const bf16_t* __restrict__ Vb, bf16_t* __restrict__ VbT)
{
  __shared__ bf16_t T[64][72];
  const int st = blockIdx.x, kvh = blockIdx.y, b = blockIdx.z;
  const int tid = threadIdx.x;
  {
    const int row = tid >> 2;
    const int c16 = (tid & 3) * 16;
    const bf16_t* src =
        Vb + ((size_t)b * SLEN + st * 64 + row) * KVW + kvh * HDIM + c16;
    *(bf16x8*)&T[row][c16]     = *(const bf16x8*)(src);
    *(bf16x8*)&T[row][c16 + 8] = *(const bf16x8*)(src + 8);
  }
  __syncthreads();
  {
    const int d  = tid >> 2;
    const int sc = (tid & 3) * 16;
    bf16_t tmp[16];
    for (int j = 0; j < 16; ++j) tmp[j] = T[sc + j][d];
    bf16_t* dst = VbT + ((size_t)(b * NKVH + kvh) * HDIM + d) * SLEN + st * 64 + sc;
    *(bf16x8*)dst       = *(bf16x8*)&tmp[0];
    *(bf16x8*)(dst + 8) = *(bf16x8*)&tmp[8];
  }
}

// ---------------- Flash attention: dbuf K/V, shuffle-free P -----------------
template <bool PRESCALED>
__global__ __launch_bounds__(512, 4) void attn_kernel(
    const bf16_t* Q, const bf16_t* __restrict__ Kg,
    const bf16_t* __restrict__ VT, bf16_t* O)
{
  const int bid = blockIdx.x;            // 0..511
  const int kvh = bid & 7;               // one kvh per XCD
  const int jb  = bid >> 3;              // 0..63
  const int b   = jb >> 5;
  const int rem = jb & 31;
  const int h   = kvh * 4 + (rem & 3);
  const int pid = rem >> 2;              // 0..7

  const int tid  = threadIdx.x;
  const int lane = tid & 63;
  const int w    = tid >> 6;             // 0..7
  const int fr   = lane & 15;
  const int quad = lane >> 4;

  __shared__ __align__(16) bf16_t lds[32768];  // 2 x (KL 8192 + VtL 8192)

  const size_t qbase = (size_t)b * SLEN;
  const bf16_t* VTh = VT + (size_t)(b * NKVH + kvh) * HDIM * SLEN;

  const int fsw = (fr >> 1) & 3;
  const int vco  = (quad & 1) * 4;
  const int vg0  = (((quad >> 1)) ^ fsw) << 3;
  const int vg1  = ((((quad >> 1)) + 2) ^ fsw) << 3;

  bf16x8 ones8;
  {
    const bf16_t o1 = (bf16_t)(fr == 0 ? 1.0f : 0.0f);
#pragma unroll
    for (int j2 = 0; j2 < 8; ++j2) ones8[j2] = o1;
  }

  auto STAGE_KV = [&](int kt, bf16_t* KL) {
    const size_t krow0 = qbase + (size_t)kt * 128;
    bf16_t* VtL = KL + 8192;
#pragma unroll
    for (int jj = 0; jj < 2; ++jj) {
      const int s  = jj * 512 + tid;
      const int ks = s >> 9, kr = (s >> 2) & 127, c8 = (s & 3) ^ ((kr >> 1) & 3);
      gl2lds16(&Kg[(krow0 + kr) * KVW + kvh * HDIM + ks * 32 + c8 * 8],
               &KL[s * 8]);
    }
#pragma unroll
    for (int jj = 0; jj < 2; ++jj) {
      const int idx = jj * 512 + tid;
      const int kb = idx >> 8, d = (idx >> 2) & 63, c8 = (idx & 3) ^ ((d >> 1) & 3);
      gl2lds16(&VTh[(size_t)d * SLEN + kt * 128 + kb * 32 + c8 * 8],
               &VtL[idx * 8]);
    }
  };

  for (int half = 0; half < 2; ++half) {
    const int qt = half ? (15 - pid) : pid;
    const int q0 = qt * 128;

    bf16x8 qf[2];
#pragma unroll
    for (int ks = 0; ks < 2; ++ks)
      qf[ks] = *(const bf16x8*)&Q[(qbase + q0 + w * 16 + fr) * HID
                                  + h * HDIM + ks * 32 + quad * 8];

    const f32x4 z4 = {0.f, 0.f, 0.f, 0.f};
    f32x4 o_acc[4];
    f32x4 o_l = z4;
#pragma unroll
    for (int di = 0; di < 4; ++di) o_acc[di] = z4;

    const int ktmax = qt;
    const int qloc  = w * 16 + fr;       // q local to the 128-row diag tile

    STAGE_KV(0, lds);
    asm volatile("s_waitcnt vmcnt(0)" ::: "memory");
    phase_barrier();

    int cur = 0;
    for (int kt = 0; kt <= ktmax; ++kt) {
      bf16_t* KL  = lds + cur * 16384;
      bf16_t* VtL = KL + 8192;
      if (kt < ktmax) STAGE_KV(kt + 1, lds + (cur ^ 1) * 16384);

      f32x4 s8[8];
#pragma unroll
      for (int ki = 0; ki < 8; ++ki) s8[ki] = z4;
      __builtin_amdgcn_s_setprio(1);
#pragma unroll
      for (int ks = 0; ks < 2; ++ks)
#pragma unroll
        for (int ki = 0; ki < 8; ++ki) {
          bf16x8 kf = *(const bf16x8*)&KL[ks * 4096 + (ki * 16 + fr) * 32
                                          + ((quad ^ fsw) << 3)];
          s8[ki] = mfma16(kf, qf[ks], s8[ki]);
        }
      __builtin_amdgcn_s_setprio(0);

      const float C2 = 0.18033688f;   // log2(e)/8 (only if !PRESCALED)
      const bool diag = (kt == ktmax);

#pragma unroll
      for (int m = 0; m < 4; ++m) {
        float pe[8];
#pragma unroll
        for (int ki2 = 0; ki2 < 2; ++ki2) {
          const int ki = 2 * m + ki2;
#pragma unroll
          for (int r = 0; r < 4; ++r) {
            const float sv = PRESCALED ? s8[ki][r] : s8[ki][r] * C2;
            float p = fast_exp2(sv);
            if (diag && (ki * 16 + quad * 4 + r > qloc)) p = 0.f;
            pe[ki2 * 4 + r] = p;
          }
        }
        union { uint32_t u[4]; bf16x8 v; } pb;
        pb.u[0] = pack2(pe[0], pe[1]);
        pb.u[1] = pack2(pe[2], pe[3]);
        pb.u[2] = pack2(pe[4], pe[5]);
        pb.u[3] = pack2(pe[6], pe[7]);

        __builtin_amdgcn_s_setprio(1);
        o_l = mfma16(pb.v, ones8, o_l);
#pragma unroll
        for (int di = 0; di < 4; ++di) {
          const int rowoff = m * 2048 + (di * 16 + fr) * 32;
          union { bf16x4 h[2]; bf16x8 v; } vf;
          vf.h[0] = *(const bf16x4*)&VtL[rowoff + vg0 + vco];
          vf.h[1] = *(const bf16x4*)&VtL[rowoff + vg1 + vco];
          o_acc[di] = mfma16(pb.v, vf.v, o_acc[di]);
        }
        __builtin_amdgcn_s_setprio(0);
      }

      asm volatile("s_waitcnt vmcnt(0)" ::: "memory");
      phase_barrier();
      cur ^= 1;
    }

    bf16_t* OB = lds;   // 128 x 72 bf16 = 18KB (stride 72 kills 8-way writes)
#pragma unroll
    for (int r = 0; r < 4; ++r) {
      const float l  = __shfl(o_l[r], lane & 48);
      const float rl = 1.f / l;
      const int q = w * 16 + quad * 4 + r;
#pragma unroll
      for (int di = 0; di < 4; ++di)
        OB[q * 72 + di * 16 + fr] = (bf16_t)(o_acc[di][r] * rl);
    }
    asm volatile("s_waitcnt lgkmcnt(0)" ::: "memory");
    phase_barrier();
    {
      const int row = tid >> 2;          // 0..127
      const int seg = tid & 3;           // 0..3 (16 bf16 each)
      bf16x8 v0 = *(const bf16x8*)&OB[row * 72 + seg * 16];
      bf16x8 v1 = *(const bf16x8*)&OB[row * 72 + seg * 16 + 8];
      bf16_t* dst = &O[(qbase + q0 + row) * HID + h * HDIM + seg * 16];
      *(bf16x8*)dst       = v0;
      *(bf16x8*)(dst + 8) = v1;
    }
    phase_barrier();   // protect OB before next half's staging
  }
}

extern "C" void kernel_launch(void* const* d_in, const int* in_sizes, int n_in,
                              void* d_out, int out_size, void* d_ws, size_t ws_size,
                              hipStream_t stream) {
  const float* x  = (const float*)d_in[0];
  // d_in[1] = causal mask (int32) -- recomputed inline, not read
  const float* Wq = (const float*)d_in[2];
  const float* bq = (const float*)d_in[3];
  const float* Wk = (const float*)d_in[4];
  const float* bk = (const float*)d_in[5];
  const float* Wv = (const float*)d_in[6];
  const float* bv = (const float*)d_in[7];
  const float* Wo = (const float*)d_in[8];
  const float* bo = (const float*)d_in[9];
  float* out = (float*)d_out;

  const size_t M = (size_t)NB * SLEN;          // 4096
  dim3 blk(256, 1, 1);

  const size_t needA = (M * HID
                        + (size_t)HID * HID
                        + (size_t)KVW * HID
                        + (size_t)KVW * HID
                        + (size_t)HID * HID
                        + M * HID
                        + M * KVW
                        + M * KVW) * 2
                       + (size_t)(HID + 2 * KVW) * sizeof(float);
  if (ws_size >= needA) {
    bf16_t* xb  = (bf16_t*)d_ws;
    bf16_t* Wqb = xb  + M * HID;              // Wq|Wk|Wv contiguous = Wcat
    bf16_t* Wkb = Wqb + (size_t)HID * HID;
    bf16_t* Wvb = Wkb + (size_t)KVW * HID;
    bf16_t* Wob = Wvb + (size_t)KVW * HID;
    bf16_t* Qb  = Wob + (size_t)HID * HID;
    bf16_t* Kb  = Qb  + M * HID;
    bf16_t* VbT = Kb  + M * KVW;
    float*  bcat = (float*)(VbT + M * KVW);   // [bq|bk|bv], 3072 floats

    cvt_kernel<<<dim3(1024, 8, 1), blk, 0, stream>>>(
        x, Wq, Wk, Wv, Wo, bq, bk, bv, xb, Wqb, Wkb, Wvb, Wob, bcat);
    qkv8_kernel<<<dim3(256, 1, 1), dim3(512, 1, 1), 0, stream>>>(
        xb, Wqb, bcat, Qb, Kb, VbT);
    attn_kernel<true><<<dim3(512, 1, 1), dim3(512, 1, 1), 0, stream>>>(
        Qb, Kb, VbT, Qb);
    oproj8_kernel<<<dim3(256, 1, 1), dim3(512, 1, 1), 0, stream>>>(
        Qb, Wob, bo, out);
  } else {
    bf16_t* Qb  = (bf16_t*)d_ws;
    bf16_t* Kb  = Qb + M * HID;
    bf16_t* Vb  = Kb + M * KVW;
    bf16_t* VbT = Vb + M * KVW;

    qkv_kernel<<<dim3(24, 32, 1), blk, 0, stream>>>(x, Wq, bq, Wk, bk, Wv, bv, Qb, Kb, Vb);
    vtrans_kernel<<<dim3(32, 8, 2), blk, 0, stream>>>(Vb, VbT);
    attn_kernel<false><<<dim3(512, 1, 1), dim3(512, 1, 1), 0, stream>>>(
        Qb, Kb, VbT, Qb);
    oproj_kernel<<<dim3(16, 32, 1), blk, 0, stream>>>(Qb, Wo, bo, out);
  }
}